// Round 3
// 5593.450 us; speedup vs baseline: 1.2130x; 1.2130x over previous
//
#include <hip/hip_runtime.h>
#include <hip/hip_bf16.h>

// DETR-style transformer forward, round 6 (second resubmit — rounds 7 and 8
// both died with the infra-level "MI355X container failed twice" error, no
// profile/verdict. Kernel re-audited: no OOB, no race, no divergent barrier,
// layouts re-derived. Resubmitting unchanged.)
// Round-5 profile: fattn_kernel (fp32 vector flash attn, MfmaUtil=0, 60 TF
// effective) was 6x288us = 25% of total. Replaced with bf16 MFMA flash
// attention (16x16x32): K staged in natural B-layout (pure bf16 copies),
// V transposed into B-layout at stage time, P re-enters A-layout via a
// per-wave 2KB LDS buffer. Online softmax in registers via C-layout row
// mapping + 16-lane shfl_xor butterflies. LDS 54KB -> 24KB.
//
// Shapes: D=512 H=8 dh=64 DFF=2048 S=1024 B=8 Q=256 LE=LD=6
// ws layout (~96.5 MB): x fp32 | tgt fp32 | QKVb bf16 | Fb bf16 | E1b | E2b

#define DMODEL 512
#define SEQ    1024
#define BT     8
#define NQ     256

using bf16 = __hip_bfloat16;
typedef short short8 __attribute__((ext_vector_type(8)));
typedef float floatx4 __attribute__((ext_vector_type(4)));

__device__ __forceinline__ float us2f(unsigned short u) {
    return __uint_as_float(((unsigned int)u) << 16);
}
__device__ __forceinline__ float b2f(bf16 x) { return __bfloat162float(x); }
__device__ __forceinline__ bf16  f2b(float x) { return __float2bfloat16(x); }
__device__ __forceinline__ short f2bs(float f) {  // RNE fp32->bf16 bits
    unsigned u = __float_as_uint(f);
    return (short)((u + 0x7fffu + ((u >> 16) & 1u)) >> 16);
}

__global__ void copy_kernel(const float* __restrict__ in, float* __restrict__ out, long n) {
    long i = (long)blockIdx.x * 256 + threadIdx.x;
    if (i < n) out[i] = in[i];
}

// ---------------- MFMA GEMM: C[m][n] = alpha*sum_k (A[m][k](+A2))*Bt[n][k] + bias[n] ----------------
// A fp32 or bf16, k-contiguous, row stride a_rs. A2 fp32 (stride DMODEL):
// mode 0=none, 1=A2[row], 2=A2[row>>3]. Bt fp32 dense [N][K]. C bf16/fp32.
// grid (N/128, M/128), block 256. K%32==0.
__global__ __launch_bounds__(256) void gemm_mfma_kernel(
    const void* __restrict__ A, int a_bf16,
    const float* __restrict__ A2, int a2_mode,
    const float* __restrict__ Bt,
    const float* __restrict__ bias,
    void* __restrict__ C, int c_bf16,
    int K, long a_rs, long c_rs,
    float alpha, int relu)
{
    const int m0 = blockIdx.y * 128;
    const int n0 = blockIdx.x * 128;
    const int t = threadIdx.x;
    const int lane = t & 63;
    const int wave = t >> 6;
    const int wmf = (wave >> 1) * 4;   // wave's first m-frag (of 8)
    const int wnf = (wave & 1) * 4;    // wave's first n-frag

    // fragment-major LDS: frag f occupies halves [f*512, f*512+512);
    // element (r in 0..15, k in 0..31) at f*512 + ((r&15) + (k>>3)*16)*8 + (k&7)
    __shared__ __align__(16) short Asl[4096];
    __shared__ __align__(16) short Bsl[4096];

    const int sr = t >> 1;          // staging row 0..127
    const int kh = t & 1;           // which 16-k half
    const int wbase = (sr >> 4) * 512 + (sr & 15) * 8;
    const int wslot0 = wbase + (2 * kh) * 128;      // kgrp 2*kh
    const int wslot1 = wbase + (2 * kh + 1) * 128;  // kgrp 2*kh+1

    floatx4 acc[4][4];
    #pragma unroll
    for (int i = 0; i < 4; i++)
        #pragma unroll
        for (int j = 0; j < 4; j++)
            acc[i][j] = (floatx4){0.f, 0.f, 0.f, 0.f};

    for (int k0 = 0; k0 < K; k0 += 32) {
        // ---- stage A (16 k-contiguous elems / thread) ----
        {
            float f[16];
            const long base = (long)(m0 + sr) * a_rs + k0 + kh * 16;
            if (a_bf16) {
                const unsigned short* p = (const unsigned short*)A + base;
                #pragma unroll
                for (int j = 0; j < 16; j += 4) {
                    ushort4 u = *(const ushort4*)(p + j);
                    f[j] = us2f(u.x); f[j+1] = us2f(u.y);
                    f[j+2] = us2f(u.z); f[j+3] = us2f(u.w);
                }
            } else {
                const float* p = (const float*)A + base;
                #pragma unroll
                for (int j = 0; j < 16; j += 4) {
                    float4 v = *(const float4*)(p + j);
                    f[j] = v.x; f[j+1] = v.y; f[j+2] = v.z; f[j+3] = v.w;
                }
            }
            if (a2_mode) {
                const long r2 = (a2_mode == 2) ? ((long)(m0 + sr) >> 3) : (long)(m0 + sr);
                const float* p = A2 + r2 * DMODEL + k0 + kh * 16;
                #pragma unroll
                for (int j = 0; j < 16; j += 4) {
                    float4 v = *(const float4*)(p + j);
                    f[j] += v.x; f[j+1] += v.y; f[j+2] += v.z; f[j+3] += v.w;
                }
            }
            short8 s0, s1;
            #pragma unroll
            for (int j = 0; j < 8; j++) { s0[j] = f2bs(f[j]); s1[j] = f2bs(f[8 + j]); }
            *(short8*)&Asl[wslot0] = s0;
            *(short8*)&Asl[wslot1] = s1;
        }
        // ---- stage B (fp32 weights) ----
        {
            const float* p = Bt + (long)(n0 + sr) * K + k0 + kh * 16;
            float f[16];
            #pragma unroll
            for (int j = 0; j < 16; j += 4) {
                float4 v = *(const float4*)(p + j);
                f[j] = v.x; f[j+1] = v.y; f[j+2] = v.z; f[j+3] = v.w;
            }
            short8 s0, s1;
            #pragma unroll
            for (int j = 0; j < 8; j++) { s0[j] = f2bs(f[j]); s1[j] = f2bs(f[8 + j]); }
            *(short8*)&Bsl[wslot0] = s0;
            *(short8*)&Bsl[wslot1] = s1;
        }
        __syncthreads();

        short8 af[4], bfr[4];
        #pragma unroll
        for (int i = 0; i < 4; i++)
            af[i] = *(short8*)&Asl[(wmf + i) * 512 + lane * 8];
        #pragma unroll
        for (int j = 0; j < 4; j++)
            bfr[j] = *(short8*)&Bsl[(wnf + j) * 512 + lane * 8];
        #pragma unroll
        for (int i = 0; i < 4; i++)
            #pragma unroll
            for (int j = 0; j < 4; j++)
                acc[i][j] = __builtin_amdgcn_mfma_f32_16x16x32_bf16(
                    af[i], bfr[j], acc[i][j], 0, 0, 0);
        __syncthreads();
    }

    // epilogue: D mapping col=lane&15, row=(lane>>4)*4+reg  [m89-verified]
    const int cl = lane & 15;
    const int rl = (lane >> 4) * 4;
    #pragma unroll
    for (int j = 0; j < 4; j++) {
        const int col = n0 + wnf * 16 + j * 16 + cl;
        const float bv = bias ? bias[col] : 0.f;
        #pragma unroll
        for (int i = 0; i < 4; i++) {
            const int rowb = m0 + wmf * 16 + i * 16 + rl;
            #pragma unroll
            for (int r = 0; r < 4; r++) {
                float v = acc[i][j][r] * alpha + bv;
                if (relu) v = fmaxf(v, 0.f);
                const long ci = (long)(rowb + r) * c_rs + col;
                if (c_bf16) ((bf16*)C)[ci] = f2b(v);
                else        ((float*)C)[ci] = v;
            }
        }
    }
}

// ---------------- generic strided/batched GEMM (kept for score/PV batched) ----------------
__global__ __launch_bounds__(256) void gemm_kernel(
    const void* __restrict__ A, int a_bf16,
    const float* __restrict__ A2, int a2_mode,
    const void* __restrict__ Bt, int bt_bf16, long bt_rs, long bt_cs,
    const float* __restrict__ bias,
    void* __restrict__ C, int c_bf16,
    int M, int N, int K,
    long a_rs, long a_bo, long b_bo, long c_rs, long c_bo,
    float alpha, int relu)
{
    const int bh = blockIdx.z;
    const int m0 = blockIdx.y * 64;
    const int n0 = blockIdx.x * 64;
    const int t  = threadIdx.x;

    __shared__ float As[16][64];
    __shared__ float Bs[16][64];

    const int am = t >> 2;
    const int ak = (t & 3) * 4;
    const int tm = (t >> 4) * 4;
    const int tn = (t & 15) * 4;

    float acc[4][4] = {};

    for (int k0 = 0; k0 < K; k0 += 16) {
        {
            const long arow = m0 + am;
            const long aidx = (long)bh * a_bo + arow * a_rs + (k0 + ak);
            float v0, v1, v2, v3;
            if (a_bf16) {
                ushort4 u = *(const ushort4*)((const unsigned short*)A + aidx);
                v0 = us2f(u.x); v1 = us2f(u.y); v2 = us2f(u.z); v3 = us2f(u.w);
            } else {
                float4 f = *(const float4*)((const float*)A + aidx);
                v0 = f.x; v1 = f.y; v2 = f.z; v3 = f.w;
            }
            if (a2_mode) {
                const long r2 = (a2_mode == 2) ? (arow >> 3) : arow;
                float4 f = *(const float4*)(A2 + r2 * DMODEL + (k0 + ak));
                v0 += f.x; v1 += f.y; v2 += f.z; v3 += f.w;
            }
            As[ak + 0][am] = v0; As[ak + 1][am] = v1;
            As[ak + 2][am] = v2; As[ak + 3][am] = v3;
        }
        if (bt_cs == 1) {
            const long bidx = (long)bh * b_bo + (long)(n0 + am) * bt_rs + (k0 + ak);
            if (bt_bf16) {
                ushort4 u = *(const ushort4*)((const unsigned short*)Bt + bidx);
                Bs[ak + 0][am] = us2f(u.x); Bs[ak + 1][am] = us2f(u.y);
                Bs[ak + 2][am] = us2f(u.z); Bs[ak + 3][am] = us2f(u.w);
            } else {
                float4 f = *(const float4*)((const float*)Bt + bidx);
                Bs[ak + 0][am] = f.x; Bs[ak + 1][am] = f.y;
                Bs[ak + 2][am] = f.z; Bs[ak + 3][am] = f.w;
            }
        } else {
            const int bn = t & 63;
            const int bk = t >> 6;
            const long base = (long)bh * b_bo + (long)(n0 + bn) * bt_rs;
            #pragma unroll
            for (int ii = 0; ii < 4; ii++) {
                int kk = bk * 4 + ii;
                long idx = base + (long)(k0 + kk) * bt_cs;
                Bs[kk][bn] = bt_bf16 ? b2f(((const bf16*)Bt)[idx])
                                     : ((const float*)Bt)[idx];
            }
        }
        __syncthreads();
        #pragma unroll
        for (int k = 0; k < 16; k++) {
            float a0 = As[k][tm], a1 = As[k][tm + 1], a2 = As[k][tm + 2], a3 = As[k][tm + 3];
            float b0 = Bs[k][tn], b1 = Bs[k][tn + 1], b2 = Bs[k][tn + 2], b3 = Bs[k][tn + 3];
            acc[0][0] += a0 * b0; acc[0][1] += a0 * b1; acc[0][2] += a0 * b2; acc[0][3] += a0 * b3;
            acc[1][0] += a1 * b0; acc[1][1] += a1 * b1; acc[1][2] += a1 * b2; acc[1][3] += a1 * b3;
            acc[2][0] += a2 * b0; acc[2][1] += a2 * b1; acc[2][2] += a2 * b2; acc[2][3] += a2 * b3;
            acc[3][0] += a3 * b0; acc[3][1] += a3 * b1; acc[3][2] += a3 * b2; acc[3][3] += a3 * b3;
        }
        __syncthreads();
    }

    #pragma unroll
    for (int i = 0; i < 4; i++) {
        #pragma unroll
        for (int j = 0; j < 4; j++) {
            int n = n0 + tn + j;
            float v = acc[i][j] * alpha;
            if (bias) v += bias[n];
            if (relu) v = fmaxf(v, 0.f);
            long cidx = (long)bh * c_bo + (long)(m0 + tm + i) * c_rs + n;
            if (c_bf16) ((bf16*)C)[cidx] = f2b(v);
            else        ((float*)C)[cidx] = v;
        }
    }
}

// ---------------- MFMA flash self-attention ----------------
// One block = one (b,h) x 64-query tile. 4 waves; wave w owns q rows
// [w*16, w*16+16). Per 64-key tile: K staged in B-layout (pure bf16 copy),
// V transposed into B-layout (n=dh, k=key); QK^T = 8 MFMA/wave; online
// softmax in registers (C layout: col=lane&15, row=(lane>>4)*4+reg);
// P -> per-wave LDS buffer in A-layout; PV = 8 MFMA/wave.
// Fragment-major layout for a 64x64 (rows x k) tile:
//   elem (r,k) at ((r>>4)*2 + (k>>5))*512 + ((r&15) + ((k&31)>>3)*16)*8 + (k&7)
__global__ __launch_bounds__(256) void fattn_mfma_kernel(
    const bf16* __restrict__ qkv, bf16* __restrict__ out, int nk)
{
    const int q0 = blockIdx.x * 64;
    const int bh = blockIdx.y;
    const int b = bh >> 3, h = bh & 7;
    const int t = threadIdx.x;
    const int lane = t & 63;
    const int wave = t >> 6;

    __shared__ __align__(16) short Ks[4096];     // K tile, B-layout (n=key, k=dh)
    __shared__ __align__(16) short Vs[4096];     // V^T tile, B-layout (n=dh, k=key)
    __shared__ __align__(16) short Ps[4][1024];  // per-wave P, A-layout (16 q x 64 key)

    // staging: thread -> row sr (0..63), 16-elem k chunk kh (0..3)
    const int sr = t >> 2;
    const int kh = t & 3;
    const int slot0 = ((sr >> 4) * 2 + (kh >> 1)) * 512
                    + ((sr & 15) + ((kh & 1) * 2) * 16) * 8;
    const int slot1 = slot0 + 128;
    // V^T write base: n = kh*16 + j (j=0..15), k = sr
    const int vbase = (kh * 2 + (sr >> 5)) * 512 + ((sr & 31) >> 3) * 128 + (sr & 7);

    // ---- stage Q via Ks, pull A-frags to regs (bf16 passthrough, no cvt) ----
    {
        const short* p = (const short*)qkv
            + ((long)(q0 + sr) * BT + b) * 1536 + h * 64 + kh * 16;
        *(short8*)&Ks[slot0] = *(const short8*)p;
        *(short8*)&Ks[slot1] = *(const short8*)(p + 8);
    }
    __syncthreads();
    short8 qf0 = *(short8*)&Ks[(wave * 2 + 0) * 512 + lane * 8];
    short8 qf1 = *(short8*)&Ks[(wave * 2 + 1) * 512 + lane * 8];
    __syncthreads();

    const int g = lane >> 4, c = lane & 15;

    float mrow[4], lrow[4];
    #pragma unroll
    for (int r = 0; r < 4; r++) { mrow[r] = -1e30f; lrow[r] = 0.f; }
    floatx4 accO[4];
    #pragma unroll
    for (int of = 0; of < 4; of++) accO[of] = (floatx4){0.f, 0.f, 0.f, 0.f};

    for (int kt = 0; kt < nk; kt += 64) {
        // ---- stage K (copy) + V (transpose) ----
        const short* kp = (const short*)qkv
            + ((long)(kt + sr) * BT + b) * 1536 + 512 + h * 64 + kh * 16;
        *(short8*)&Ks[slot0] = *(const short8*)kp;
        *(short8*)&Ks[slot1] = *(const short8*)(kp + 8);
        short8 v0 = *(const short8*)(kp + 512);
        short8 v1 = *(const short8*)(kp + 520);
        #pragma unroll
        for (int j = 0; j < 8; j++) {
            Vs[vbase + j * 8]       = v0[j];
            Vs[vbase + (8 + j) * 8] = v1[j];
        }
        __syncthreads();

        // ---- QK^T: S[16 q][64 key] per wave ----
        floatx4 sacc[4];
        #pragma unroll
        for (int nf = 0; nf < 4; nf++) {
            sacc[nf] = (floatx4){0.f, 0.f, 0.f, 0.f};
            short8 bk0 = *(short8*)&Ks[(nf * 2 + 0) * 512 + lane * 8];
            short8 bk1 = *(short8*)&Ks[(nf * 2 + 1) * 512 + lane * 8];
            sacc[nf] = __builtin_amdgcn_mfma_f32_16x16x32_bf16(qf0, bk0, sacc[nf], 0, 0, 0);
            sacc[nf] = __builtin_amdgcn_mfma_f32_16x16x32_bf16(qf1, bk1, sacc[nf], 0, 0, 0);
        }

        // ---- online softmax; q row = wave*16 + g*4 + r, key = nf*16 + c ----
        #pragma unroll
        for (int r = 0; r < 4; r++) {
            float mx = fmaxf(fmaxf(sacc[0][r], sacc[1][r]),
                             fmaxf(sacc[2][r], sacc[3][r]));
            mx = fmaxf(mx, __shfl_xor(mx, 1));
            mx = fmaxf(mx, __shfl_xor(mx, 2));
            mx = fmaxf(mx, __shfl_xor(mx, 4));
            mx = fmaxf(mx, __shfl_xor(mx, 8));
            mx *= 0.125f;  // scale = 1/sqrt(64); positive, commutes with max
            float mn = fmaxf(mrow[r], mx);
            float al = __expf(mrow[r] - mn);
            mrow[r] = mn;
            float ps = 0.f;
            #pragma unroll
            for (int nf = 0; nf < 4; nf++) {
                float p = __expf(fmaf(sacc[nf][r], 0.125f, -mn));
                ps += p;
                // A-layout slot for (row=g*4+r, key=nf*16+c)
                Ps[wave][(nf >> 1) * 512
                         + ((g * 4 + r) + ((nf & 1) * 2 + (c >> 3)) * 16) * 8
                         + (c & 7)] = f2bs(p);
            }
            ps += __shfl_xor(ps, 1);
            ps += __shfl_xor(ps, 2);
            ps += __shfl_xor(ps, 4);
            ps += __shfl_xor(ps, 8);
            lrow[r] = lrow[r] * al + ps;
            #pragma unroll
            for (int of = 0; of < 4; of++) accO[of][r] *= al;
        }

        // ---- PV: O[16 q][64 dh] += P[16][64] * V[64][64] ----
        short8 pf0 = *(short8*)&Ps[wave][lane * 8];
        short8 pf1 = *(short8*)&Ps[wave][512 + lane * 8];
        #pragma unroll
        for (int of = 0; of < 4; of++) {
            short8 vf0 = *(short8*)&Vs[(of * 2 + 0) * 512 + lane * 8];
            short8 vf1 = *(short8*)&Vs[(of * 2 + 1) * 512 + lane * 8];
            accO[of] = __builtin_amdgcn_mfma_f32_16x16x32_bf16(pf0, vf0, accO[of], 0, 0, 0);
            accO[of] = __builtin_amdgcn_mfma_f32_16x16x32_bf16(pf1, vf1, accO[of], 0, 0, 0);
        }
        __syncthreads();
    }

    // ---- epilogue: normalize, write bf16 out[q*B+b][h*64 + dh] ----
    #pragma unroll
    for (int r = 0; r < 4; r++) {
        const float inv = 1.f / lrow[r];
        const long off = ((long)(q0 + wave * 16 + g * 4 + r) * BT + b) * DMODEL
                       + h * 64 + c;
        #pragma unroll
        for (int of = 0; of < 4; of++)
            out[off + of * 16] = f2b(accO[of][r] * inv);
    }
}

// ---------------- layer norm: y = LN(x + res) * w + b ----------------
__global__ __launch_bounds__(256) void ln_kernel(
    const float* __restrict__ x, const bf16* __restrict__ res,
    const float* __restrict__ w, const float* __restrict__ b,
    float* __restrict__ y)
{
    const long row = blockIdx.x;
    const int t = threadIdx.x;
    const float* xr = x + row * DMODEL;
    float v0 = xr[t], v1 = xr[t + 256];
    if (res) {
        v0 += b2f(res[row * DMODEL + t]);
        v1 += b2f(res[row * DMODEL + t + 256]);
    }

    __shared__ float red[256];
    red[t] = v0 + v1; __syncthreads();
    for (int s = 128; s > 0; s >>= 1) { if (t < s) red[t] += red[t + s]; __syncthreads(); }
    float mean = red[0] * (1.f / DMODEL);
    __syncthreads();
    float d0 = v0 - mean, d1 = v1 - mean;
    red[t] = d0 * d0 + d1 * d1; __syncthreads();
    for (int s = 128; s > 0; s >>= 1) { if (t < s) red[t] += red[t + s]; __syncthreads(); }
    float inv = rsqrtf(red[0] * (1.f / DMODEL) + 1e-5f);

    y[row * DMODEL + t]       = d0 * inv * w[t] + b[t];
    y[row * DMODEL + t + 256] = d1 * inv * w[t + 256] + b[t + 256];
}

// ---------------- column softmax over q (assign-attn) ----------------
__global__ __launch_bounds__(256) void col_softmax_kernel(bf16* __restrict__ s) {
    const int bh = blockIdx.y;
    const int n = blockIdx.x * 256 + threadIdx.x;
    bf16* base = s + (long)bh * (NQ * SEQ) + n;
    float mx = -1e30f;
    for (int q = 0; q < NQ; q++) mx = fmaxf(mx, b2f(base[(long)q * SEQ]));
    float sum = 0.f;
    for (int q = 0; q < NQ; q++) {
        float v = __expf(b2f(base[(long)q * SEQ]) - mx);
        base[(long)q * SEQ] = f2b(v);
        sum += v;
    }
    float inv = 1.f / sum;
    for (int q = 0; q < NQ; q++)
        base[(long)q * SEQ] = f2b(b2f(base[(long)q * SEQ]) * inv);
}

// mean over heads: o[b,q,n] = (1/8) sum_h s[b,h,q,n], fp32 out.
__global__ __launch_bounds__(256) void mean_h_kernel(
    const bf16* __restrict__ s, float* __restrict__ o)
{
    long i = (long)blockIdx.x * 256 + threadIdx.x;
    int n = (int)(i & (SEQ - 1));
    long r = i >> 10;
    int q = (int)(r & (NQ - 1));
    int b = (int)(r >> 8);
    float acc = 0.f;
    #pragma unroll
    for (int h = 0; h < 8; h++)
        acc += b2f(s[(((long)b * 8 + h) * NQ + q) * SEQ + n]);
    o[i] = acc * 0.125f;
}

// ---------------- host launch ----------------
extern "C" void kernel_launch(void* const* d_in, const int* in_sizes, int n_in,
                              void* d_out, int out_size, void* d_ws, size_t ws_size,
                              hipStream_t stream) {
    const float* src         = (const float*)d_in[0];
    const float* query_embed = (const float*)d_in[2];
    const float* pos_embed   = (const float*)d_in[3];
    const float* enc_in_w    = (const float*)d_in[4];
    const float* enc_in_b    = (const float*)d_in[5];
    const float* enc_out_w   = (const float*)d_in[6];
    const float* enc_out_b   = (const float*)d_in[7];
    const float* enc_ffn_w1  = (const float*)d_in[8];
    const float* enc_ffn_b1  = (const float*)d_in[9];
    const float* enc_ffn_w2  = (const float*)d_in[10];
    const float* enc_ffn_b2  = (const float*)d_in[11];
    const float* enc_ln_w    = (const float*)d_in[12];
    const float* enc_ln_b    = (const float*)d_in[13];
    const float* dec_in_w    = (const float*)d_in[14];
    const float* dec_in_b    = (const float*)d_in[15];
    const float* dec_out_w   = (const float*)d_in[16];
    const float* dec_out_b   = (const float*)d_in[17];
    const float* dec_ca_w    = (const float*)d_in[18];
    const float* dec_ca_b    = (const float*)d_in[19];
    const float* dec_ffn_w1  = (const float*)d_in[20];
    const float* dec_ffn_b1  = (const float*)d_in[21];
    const float* dec_ffn_w2  = (const float*)d_in[22];
    const float* dec_ffn_b2  = (const float*)d_in[23];
    const float* dec_ln_w    = (const float*)d_in[24];
    const float* dec_ln_b    = (const float*)d_in[25];
    const float* final_ln_w  = (const float*)d_in[26];
    const float* final_ln_b  = (const float*)d_in[27];

    float* wsf = (float*)d_ws;
    float* x   = wsf;                     // 4,194,304 f
    float* tgt = wsf + 4194304;           // 1,048,576 f
    bf16* QKVb = (bf16*)(wsf + 5242880);  // 12,582,912 bf16
    bf16* Fb   = QKVb + 12582912;         // 16,777,216
    bf16* E1b  = Fb + 16777216;           //  4,194,304
    bf16* E2b  = E1b + 4194304;           //  4,194,304
    bf16* kca  = QKVb + 3145728;          // decoder carve (after 2048*1536)
    bf16* vca  = kca + 4194304;

    float* out0 = (float*)d_out;          // (1,Q,B,D) 1,048,576
    float* outP = out0 + 1048576;         // (B,Q,S)   2,097,152
    float* outS = outP + 2097152;         // (B,Q,S)   2,097,152

    // dense MFMA gemm: C[M][N] = (A(+A2)) @ Bt^T + bias
    auto mgemm = [&](const void* A, int a_bf16, const float* A2, int a2_mode,
                     const float* Bt, const float* bias, void* C, int c_bf16,
                     int M, int N, int K, long a_rs, long c_rs, int relu) {
        dim3 g(N / 128, M / 128, 1);
        gemm_mfma_kernel<<<g, 256, 0, stream>>>(A, a_bf16, A2, a2_mode, Bt, bias,
                                                C, c_bf16, K, a_rs, c_rs, 1.f, relu);
    };
    auto gemm = [&](const void* A, int a_bf16, const float* A2, int a2_mode,
                    const void* Bt, int bt_bf16, long bt_rs, long bt_cs,
                    const float* bias, void* C, int c_bf16,
                    int M, int N, int K,
                    long a_rs, long a_bo, long b_bo, long c_rs, long c_bo,
                    float alpha, int relu, int batch) {
        dim3 g(N / 64, M / 64, batch);
        gemm_kernel<<<g, 256, 0, stream>>>(A, a_bf16, A2, a2_mode, Bt, bt_bf16, bt_rs, bt_cs,
                                           bias, C, c_bf16, M, N, K,
                                           a_rs, a_bo, b_bo, c_rs, c_bo, alpha, relu);
    };

    copy_kernel<<<16384, 256, 0, stream>>>(src, x, 4194304);
    hipMemsetAsync(tgt, 0, 1048576 * sizeof(float), stream);

    // ---------------- encoder ----------------
    for (int i = 0; i < 6; i++) {
        const float* iw = enc_in_w + (long)i * 786432;
        const float* ib = enc_in_b + (long)i * 1536;
        mgemm(x, 0, pos_embed, 1, iw, ib, QKVb, 1, 8192, 1024, 512, 512, 1536, 0);
        mgemm(x, 0, nullptr, 0, iw + 524288, ib + 1024, QKVb + 1024, 1,
              8192, 512, 512, 512, 1536, 0);
        fattn_mfma_kernel<<<dim3(16, 64), 256, 0, stream>>>(QKVb, E1b, 1024);
        mgemm(E1b, 1, nullptr, 0, enc_out_w + (long)i * 262144, enc_out_b + (long)i * 512,
              E2b, 1, 8192, 512, 512, 512, 512, 0);
        ln_kernel<<<8192, 256, 0, stream>>>(x, E2b, enc_ln_w + (long)i * 1024,
                                            enc_ln_b + (long)i * 1024, x);
        mgemm(x, 0, nullptr, 0, enc_ffn_w1 + (long)i * 1048576, enc_ffn_b1 + (long)i * 2048,
              Fb, 1, 8192, 2048, 512, 512, 2048, 1);
        mgemm(Fb, 1, nullptr, 0, enc_ffn_w2 + (long)i * 1048576, enc_ffn_b2 + (long)i * 512,
              E1b, 1, 8192, 512, 2048, 2048, 512, 0);
        ln_kernel<<<8192, 256, 0, stream>>>(x, E1b, enc_ln_w + (long)i * 1024 + 512,
                                            enc_ln_b + (long)i * 1024 + 512, x);
    }
    // x = memory

    // ---------------- decoder ----------------
    for (int i = 0; i < 6; i++) {
        const float* iw = dec_in_w + (long)i * 786432;
        const float* ib = dec_in_b + (long)i * 1536;
        mgemm(tgt, 0, query_embed, 2, iw, ib, QKVb, 1, 2048, 1024, 512, 512, 1536, 0);
        mgemm(tgt, 0, nullptr, 0, iw + 524288, ib + 1024, QKVb + 1024, 1,
              2048, 512, 512, 512, 1536, 0);
        fattn_mfma_kernel<<<dim3(4, 64), 256, 0, stream>>>(QKVb, E1b, 256);
        mgemm(E1b, 1, nullptr, 0, dec_out_w + (long)i * 262144, dec_out_b + (long)i * 512,
              E2b, 1, 2048, 512, 512, 512, 512, 0);  // E2b = sa (keep)
        ln_kernel<<<2048, 256, 0, stream>>>(tgt, E2b, dec_ln_w + (long)i * 1536,
                                            dec_ln_b + (long)i * 1536, tgt);

        // assign (cross) attention: q = sa + qpos, k = memory + pos, v = memory
        const float* cw = dec_ca_w + (long)i * 1048576;
        const float* cb = dec_ca_b + (long)i * 2048;
        mgemm(E2b, 1, query_embed, 2, cw, cb, E1b, 1, 2048, 512, 512, 512, 512, 0);   // qca
        mgemm(x, 0, pos_embed, 1, cw + 262144, cb + 512, kca, 1,
              8192, 512, 512, 512, 512, 0);                                           // kca
        mgemm(x, 0, nullptr, 0, cw + 524288, cb + 1024, vca, 1,
              8192, 512, 512, 512, 512, 0);                                           // vca
        // scores[bh][q][n] = 0.125 * qca . kca   (batched over bh = b*8+h)
        gemm(E1b, 1, nullptr, 0, kca, 1, 4096, 1, nullptr, Fb, 1,
             256, 1024, 64, 4096, 64, 64, 1024, 262144, 0.125f, 0, 64);
        if (i == 5) mean_h_kernel<<<8192, 256, 0, stream>>>(Fb, outS);
        col_softmax_kernel<<<dim3(4, 64), 256, 0, stream>>>(Fb);
        if (i == 5) mean_h_kernel<<<8192, 256, 0, stream>>>(Fb, outP);
        // ca[q,(b,h),d] = P @ v  -> E2b
        gemm(Fb, 1, nullptr, 0, vca, 1, 1, 4096, nullptr, E2b, 1,
             256, 64, 1024, 1024, 262144, 64, 4096, 64, 1.f, 0, 64);
        mgemm(E2b, 1, nullptr, 0, cw + 786432, cb + 1536, E1b, 1,
              2048, 512, 512, 512, 512, 0);
        ln_kernel<<<2048, 256, 0, stream>>>(tgt, E1b, dec_ln_w + (long)i * 1536 + 512,
                                            dec_ln_b + (long)i * 1536 + 512, tgt);

        // FFN
        mgemm(tgt, 0, nullptr, 0, dec_ffn_w1 + (long)i * 1048576, dec_ffn_b1 + (long)i * 2048,
              Fb, 1, 2048, 2048, 512, 512, 2048, 1);
        mgemm(Fb, 1, nullptr, 0, dec_ffn_w2 + (long)i * 1048576, dec_ffn_b2 + (long)i * 512,
              E1b, 1, 2048, 512, 2048, 2048, 512, 0);
        ln_kernel<<<2048, 256, 0, stream>>>(tgt, E1b, dec_ln_w + (long)i * 1536 + 1024,
                                            dec_ln_b + (long)i * 1536 + 1024, tgt);
    }

    // final LN -> fp32 output 0
    ln_kernel<<<2048, 256, 0, stream>>>(tgt, nullptr, final_ln_w, final_ln_b, out0);
}

// Round 4
// 4856.892 us; speedup vs baseline: 1.3970x; 1.1517x over previous
//
#include <hip/hip_runtime.h>
#include <hip/hip_bf16.h>

// DETR-style transformer forward, round 9.
// Round-6 result: 5593us (fattn MFMA worked). Top-5 now: batched fp32
// gemm_kernel (cross-attn scores/PV), 12 x 125us = 1500us, MfmaUtil=0,
// VALUBusy 14%, occupancy 11% -- latency-bound fp32 vector GEMM on
// bf16-resident data. Replaced with bf16 MFMA kernels:
//   bgemm_mfma_kernel: scores, 128x128 tile, K=64, pure short8 staging.
//   pv_mfma_kernel: PV, fattn-style V-transpose staging, 64x64 tile, K=1024.
// fp32 gemm_kernel removed (unused).
//
// Shapes: D=512 H=8 dh=64 DFF=2048 S=1024 B=8 Q=256 LE=LD=6
// ws layout (~96.5 MB): x fp32 | tgt fp32 | QKVb bf16 | Fb bf16 | E1b | E2b

#define DMODEL 512
#define SEQ    1024
#define BT     8
#define NQ     256

using bf16 = __hip_bfloat16;
typedef short short8 __attribute__((ext_vector_type(8)));
typedef float floatx4 __attribute__((ext_vector_type(4)));

__device__ __forceinline__ float us2f(unsigned short u) {
    return __uint_as_float(((unsigned int)u) << 16);
}
__device__ __forceinline__ float b2f(bf16 x) { return __bfloat162float(x); }
__device__ __forceinline__ bf16  f2b(float x) { return __float2bfloat16(x); }
__device__ __forceinline__ short f2bs(float f) {  // RNE fp32->bf16 bits
    unsigned u = __float_as_uint(f);
    return (short)((u + 0x7fffu + ((u >> 16) & 1u)) >> 16);
}

__global__ void copy_kernel(const float* __restrict__ in, float* __restrict__ out, long n) {
    long i = (long)blockIdx.x * 256 + threadIdx.x;
    if (i < n) out[i] = in[i];
}

// ---------------- MFMA GEMM: C[m][n] = alpha*sum_k (A[m][k](+A2))*Bt[n][k] + bias[n] ----------------
// A fp32 or bf16, k-contiguous, row stride a_rs. A2 fp32 (stride DMODEL):
// mode 0=none, 1=A2[row], 2=A2[row>>3]. Bt fp32 dense [N][K]. C bf16/fp32.
// grid (N/128, M/128), block 256. K%32==0.
__global__ __launch_bounds__(256) void gemm_mfma_kernel(
    const void* __restrict__ A, int a_bf16,
    const float* __restrict__ A2, int a2_mode,
    const float* __restrict__ Bt,
    const float* __restrict__ bias,
    void* __restrict__ C, int c_bf16,
    int K, long a_rs, long c_rs,
    float alpha, int relu)
{
    const int m0 = blockIdx.y * 128;
    const int n0 = blockIdx.x * 128;
    const int t = threadIdx.x;
    const int lane = t & 63;
    const int wave = t >> 6;
    const int wmf = (wave >> 1) * 4;   // wave's first m-frag (of 8)
    const int wnf = (wave & 1) * 4;    // wave's first n-frag

    // fragment-major LDS: frag f occupies halves [f*512, f*512+512);
    // element (r in 0..15, k in 0..31) at f*512 + ((r&15) + (k>>3)*16)*8 + (k&7)
    __shared__ __align__(16) short Asl[4096];
    __shared__ __align__(16) short Bsl[4096];

    const int sr = t >> 1;          // staging row 0..127
    const int kh = t & 1;           // which 16-k half
    const int wbase = (sr >> 4) * 512 + (sr & 15) * 8;
    const int wslot0 = wbase + (2 * kh) * 128;      // kgrp 2*kh
    const int wslot1 = wbase + (2 * kh + 1) * 128;  // kgrp 2*kh+1

    floatx4 acc[4][4];
    #pragma unroll
    for (int i = 0; i < 4; i++)
        #pragma unroll
        for (int j = 0; j < 4; j++)
            acc[i][j] = (floatx4){0.f, 0.f, 0.f, 0.f};

    for (int k0 = 0; k0 < K; k0 += 32) {
        // ---- stage A (16 k-contiguous elems / thread) ----
        {
            float f[16];
            const long base = (long)(m0 + sr) * a_rs + k0 + kh * 16;
            if (a_bf16) {
                const unsigned short* p = (const unsigned short*)A + base;
                #pragma unroll
                for (int j = 0; j < 16; j += 4) {
                    ushort4 u = *(const ushort4*)(p + j);
                    f[j] = us2f(u.x); f[j+1] = us2f(u.y);
                    f[j+2] = us2f(u.z); f[j+3] = us2f(u.w);
                }
            } else {
                const float* p = (const float*)A + base;
                #pragma unroll
                for (int j = 0; j < 16; j += 4) {
                    float4 v = *(const float4*)(p + j);
                    f[j] = v.x; f[j+1] = v.y; f[j+2] = v.z; f[j+3] = v.w;
                }
            }
            if (a2_mode) {
                const long r2 = (a2_mode == 2) ? ((long)(m0 + sr) >> 3) : (long)(m0 + sr);
                const float* p = A2 + r2 * DMODEL + k0 + kh * 16;
                #pragma unroll
                for (int j = 0; j < 16; j += 4) {
                    float4 v = *(const float4*)(p + j);
                    f[j] += v.x; f[j+1] += v.y; f[j+2] += v.z; f[j+3] += v.w;
                }
            }
            short8 s0, s1;
            #pragma unroll
            for (int j = 0; j < 8; j++) { s0[j] = f2bs(f[j]); s1[j] = f2bs(f[8 + j]); }
            *(short8*)&Asl[wslot0] = s0;
            *(short8*)&Asl[wslot1] = s1;
        }
        // ---- stage B (fp32 weights) ----
        {
            const float* p = Bt + (long)(n0 + sr) * K + k0 + kh * 16;
            float f[16];
            #pragma unroll
            for (int j = 0; j < 16; j += 4) {
                float4 v = *(const float4*)(p + j);
                f[j] = v.x; f[j+1] = v.y; f[j+2] = v.z; f[j+3] = v.w;
            }
            short8 s0, s1;
            #pragma unroll
            for (int j = 0; j < 8; j++) { s0[j] = f2bs(f[j]); s1[j] = f2bs(f[8 + j]); }
            *(short8*)&Bsl[wslot0] = s0;
            *(short8*)&Bsl[wslot1] = s1;
        }
        __syncthreads();

        short8 af[4], bfr[4];
        #pragma unroll
        for (int i = 0; i < 4; i++)
            af[i] = *(short8*)&Asl[(wmf + i) * 512 + lane * 8];
        #pragma unroll
        for (int j = 0; j < 4; j++)
            bfr[j] = *(short8*)&Bsl[(wnf + j) * 512 + lane * 8];
        #pragma unroll
        for (int i = 0; i < 4; i++)
            #pragma unroll
            for (int j = 0; j < 4; j++)
                acc[i][j] = __builtin_amdgcn_mfma_f32_16x16x32_bf16(
                    af[i], bfr[j], acc[i][j], 0, 0, 0);
        __syncthreads();
    }

    // epilogue: D mapping col=lane&15, row=(lane>>4)*4+reg  [m89-verified]
    const int cl = lane & 15;
    const int rl = (lane >> 4) * 4;
    #pragma unroll
    for (int j = 0; j < 4; j++) {
        const int col = n0 + wnf * 16 + j * 16 + cl;
        const float bv = bias ? bias[col] : 0.f;
        #pragma unroll
        for (int i = 0; i < 4; i++) {
            const int rowb = m0 + wmf * 16 + i * 16 + rl;
            #pragma unroll
            for (int r = 0; r < 4; r++) {
                float v = acc[i][j][r] * alpha + bv;
                if (relu) v = fmaxf(v, 0.f);
                const long ci = (long)(rowb + r) * c_rs + col;
                if (c_bf16) ((bf16*)C)[ci] = f2b(v);
                else        ((float*)C)[ci] = v;
            }
        }
    }
}

// ---------------- batched bf16 MFMA GEMM (cross-attn scores) ----------------
// C[bh*c_bo + m*c_rs + n] = alpha * sum_k A[bh*a_bo + m*a_rs + k] * B[bh*b_bo + n*b_rs + k]
// All bf16, k-contiguous. grid (N/128, M/128, batch), block 256. K%32==0.
__global__ __launch_bounds__(256) void bgemm_mfma_kernel(
    const bf16* __restrict__ A, long a_rs, long a_bo,
    const bf16* __restrict__ B, long b_rs, long b_bo,
    bf16* __restrict__ C, long c_rs, long c_bo,
    int K, float alpha)
{
    const int bh = blockIdx.z;
    const int m0 = blockIdx.y * 128;
    const int n0 = blockIdx.x * 128;
    const int t = threadIdx.x;
    const int lane = t & 63;
    const int wave = t >> 6;
    const int wmf = (wave >> 1) * 4;
    const int wnf = (wave & 1) * 4;

    __shared__ __align__(16) short Asl[4096];
    __shared__ __align__(16) short Bsl[4096];

    const int sr = t >> 1;
    const int kh = t & 1;
    const int wbase = (sr >> 4) * 512 + (sr & 15) * 8;
    const int wslot0 = wbase + (2 * kh) * 128;
    const int wslot1 = wbase + (2 * kh + 1) * 128;

    floatx4 acc[4][4];
    #pragma unroll
    for (int i = 0; i < 4; i++)
        #pragma unroll
        for (int j = 0; j < 4; j++)
            acc[i][j] = (floatx4){0.f, 0.f, 0.f, 0.f};

    const short* Ab = (const short*)A + (long)bh * a_bo;
    const short* Bb = (const short*)B + (long)bh * b_bo;

    for (int k0 = 0; k0 < K; k0 += 32) {
        {
            const short* p = Ab + (long)(m0 + sr) * a_rs + k0 + kh * 16;
            *(short8*)&Asl[wslot0] = *(const short8*)p;
            *(short8*)&Asl[wslot1] = *(const short8*)(p + 8);
        }
        {
            const short* p = Bb + (long)(n0 + sr) * b_rs + k0 + kh * 16;
            *(short8*)&Bsl[wslot0] = *(const short8*)p;
            *(short8*)&Bsl[wslot1] = *(const short8*)(p + 8);
        }
        __syncthreads();

        short8 af[4], bfr[4];
        #pragma unroll
        for (int i = 0; i < 4; i++)
            af[i] = *(short8*)&Asl[(wmf + i) * 512 + lane * 8];
        #pragma unroll
        for (int j = 0; j < 4; j++)
            bfr[j] = *(short8*)&Bsl[(wnf + j) * 512 + lane * 8];
        #pragma unroll
        for (int i = 0; i < 4; i++)
            #pragma unroll
            for (int j = 0; j < 4; j++)
                acc[i][j] = __builtin_amdgcn_mfma_f32_16x16x32_bf16(
                    af[i], bfr[j], acc[i][j], 0, 0, 0);
        __syncthreads();
    }

    const int cl = lane & 15;
    const int rl = (lane >> 4) * 4;
    bf16* Cb = C + (long)bh * c_bo;
    #pragma unroll
    for (int j = 0; j < 4; j++) {
        const int col = n0 + wnf * 16 + j * 16 + cl;
        #pragma unroll
        for (int i = 0; i < 4; i++) {
            const int rowb = m0 + wmf * 16 + i * 16 + rl;
            #pragma unroll
            for (int r = 0; r < 4; r++)
                Cb[(long)(rowb + r) * c_rs + col] = f2b(acc[i][j][r] * alpha);
        }
    }
}

// ---------------- PV MFMA (cross-attn): C = P @ V ----------------
// P: [64 bh][256 q][1024 k] bf16 (k-contiguous).
// V: vca layout, elem (k, bh, d) at V[k*4096 + bh*64 + d] -> transpose-staged.
// C: E2b, elem (q, bh, d) at C[q*4096 + bh*64 + d].
// grid (256/64, 64), block 256. Wave w owns q rows [w*16, w*16+16).
__global__ __launch_bounds__(256) void pv_mfma_kernel(
    const bf16* __restrict__ P, const bf16* __restrict__ V,
    bf16* __restrict__ Cout)
{
    const int q0 = blockIdx.x * 64;
    const int bh = blockIdx.y;
    const int t = threadIdx.x;
    const int lane = t & 63;
    const int wave = t >> 6;

    __shared__ __align__(16) short As[4096];  // P tile 64q x 64k, fragment-major
    __shared__ __align__(16) short Vs[4096];  // V^T tile 64d x 64k, fragment-major

    const int sr = t >> 2;
    const int kh = t & 3;
    const int slot0 = ((sr >> 4) * 2 + (kh >> 1)) * 512
                    + ((sr & 15) + ((kh & 1) * 2) * 16) * 8;
    const int slot1 = slot0 + 128;
    const int vbase = (kh * 2 + (sr >> 5)) * 512 + ((sr & 31) >> 3) * 128 + (sr & 7);

    floatx4 acc[4];
    #pragma unroll
    for (int nf = 0; nf < 4; nf++) acc[nf] = (floatx4){0.f, 0.f, 0.f, 0.f};

    const short* Pb = (const short*)P + (long)bh * 262144;

    for (int kt = 0; kt < 1024; kt += 64) {
        // stage P (A-layout, pure copy): row q0+sr, k = kt + kh*16 .. +16
        {
            const short* p = Pb + (long)(q0 + sr) * 1024 + kt + kh * 16;
            *(short8*)&As[slot0] = *(const short8*)p;
            *(short8*)&As[slot1] = *(const short8*)(p + 8);
        }
        // stage V^T (B-layout, transpose): V row kt+sr, d = kh*16 .. +16
        {
            const short* vp = (const short*)V + (long)(kt + sr) * 4096 + bh * 64 + kh * 16;
            short8 v0 = *(const short8*)vp;
            short8 v1 = *(const short8*)(vp + 8);
            #pragma unroll
            for (int j = 0; j < 8; j++) {
                Vs[vbase + j * 8]       = v0[j];
                Vs[vbase + (8 + j) * 8] = v1[j];
            }
        }
        __syncthreads();

        short8 af0 = *(short8*)&As[(wave * 2 + 0) * 512 + lane * 8];
        short8 af1 = *(short8*)&As[(wave * 2 + 1) * 512 + lane * 8];
        #pragma unroll
        for (int nf = 0; nf < 4; nf++) {
            short8 vf0 = *(short8*)&Vs[(nf * 2 + 0) * 512 + lane * 8];
            short8 vf1 = *(short8*)&Vs[(nf * 2 + 1) * 512 + lane * 8];
            acc[nf] = __builtin_amdgcn_mfma_f32_16x16x32_bf16(af0, vf0, acc[nf], 0, 0, 0);
            acc[nf] = __builtin_amdgcn_mfma_f32_16x16x32_bf16(af1, vf1, acc[nf], 0, 0, 0);
        }
        __syncthreads();
    }

    // epilogue: q = q0 + wave*16 + (lane>>4)*4 + r, d = nf*16 + (lane&15)
    const int g = lane >> 4, c = lane & 15;
    #pragma unroll
    for (int r = 0; r < 4; r++) {
        const long off = (long)(q0 + wave * 16 + g * 4 + r) * 4096 + bh * 64 + c;
        #pragma unroll
        for (int nf = 0; nf < 4; nf++)
            Cout[off + nf * 16] = f2b(acc[nf][r]);
    }
}

// ---------------- MFMA flash self-attention ----------------
// One block = one (b,h) x 64-query tile. 4 waves; wave w owns q rows
// [w*16, w*16+16). Per 64-key tile: K staged in B-layout (pure bf16 copy),
// V transposed into B-layout (n=dh, k=key); QK^T = 8 MFMA/wave; online
// softmax in registers (C layout: col=lane&15, row=(lane>>4)*4+reg);
// P -> per-wave LDS buffer in A-layout; PV = 8 MFMA/wave.
// Fragment-major layout for a 64x64 (rows x k) tile:
//   elem (r,k) at ((r>>4)*2 + (k>>5))*512 + ((r&15) + ((k&31)>>3)*16)*8 + (k&7)
__global__ __launch_bounds__(256) void fattn_mfma_kernel(
    const bf16* __restrict__ qkv, bf16* __restrict__ out, int nk)
{
    const int q0 = blockIdx.x * 64;
    const int bh = blockIdx.y;
    const int b = bh >> 3, h = bh & 7;
    const int t = threadIdx.x;
    const int lane = t & 63;
    const int wave = t >> 6;

    __shared__ __align__(16) short Ks[4096];     // K tile, B-layout (n=key, k=dh)
    __shared__ __align__(16) short Vs[4096];     // V^T tile, B-layout (n=dh, k=key)
    __shared__ __align__(16) short Ps[4][1024];  // per-wave P, A-layout (16 q x 64 key)

    // staging: thread -> row sr (0..63), 16-elem k chunk kh (0..3)
    const int sr = t >> 2;
    const int kh = t & 3;
    const int slot0 = ((sr >> 4) * 2 + (kh >> 1)) * 512
                    + ((sr & 15) + ((kh & 1) * 2) * 16) * 8;
    const int slot1 = slot0 + 128;
    // V^T write base: n = kh*16 + j (j=0..15), k = sr
    const int vbase = (kh * 2 + (sr >> 5)) * 512 + ((sr & 31) >> 3) * 128 + (sr & 7);

    // ---- stage Q via Ks, pull A-frags to regs (bf16 passthrough, no cvt) ----
    {
        const short* p = (const short*)qkv
            + ((long)(q0 + sr) * BT + b) * 1536 + h * 64 + kh * 16;
        *(short8*)&Ks[slot0] = *(const short8*)p;
        *(short8*)&Ks[slot1] = *(const short8*)(p + 8);
    }
    __syncthreads();
    short8 qf0 = *(short8*)&Ks[(wave * 2 + 0) * 512 + lane * 8];
    short8 qf1 = *(short8*)&Ks[(wave * 2 + 1) * 512 + lane * 8];
    __syncthreads();

    const int g = lane >> 4, c = lane & 15;

    float mrow[4], lrow[4];
    #pragma unroll
    for (int r = 0; r < 4; r++) { mrow[r] = -1e30f; lrow[r] = 0.f; }
    floatx4 accO[4];
    #pragma unroll
    for (int of = 0; of < 4; of++) accO[of] = (floatx4){0.f, 0.f, 0.f, 0.f};

    for (int kt = 0; kt < nk; kt += 64) {
        // ---- stage K (copy) + V (transpose) ----
        const short* kp = (const short*)qkv
            + ((long)(kt + sr) * BT + b) * 1536 + 512 + h * 64 + kh * 16;
        *(short8*)&Ks[slot0] = *(const short8*)kp;
        *(short8*)&Ks[slot1] = *(const short8*)(kp + 8);
        short8 v0 = *(const short8*)(kp + 512);
        short8 v1 = *(const short8*)(kp + 520);
        #pragma unroll
        for (int j = 0; j < 8; j++) {
            Vs[vbase + j * 8]       = v0[j];
            Vs[vbase + (8 + j) * 8] = v1[j];
        }
        __syncthreads();

        // ---- QK^T: S[16 q][64 key] per wave ----
        floatx4 sacc[4];
        #pragma unroll
        for (int nf = 0; nf < 4; nf++) {
            sacc[nf] = (floatx4){0.f, 0.f, 0.f, 0.f};
            short8 bk0 = *(short8*)&Ks[(nf * 2 + 0) * 512 + lane * 8];
            short8 bk1 = *(short8*)&Ks[(nf * 2 + 1) * 512 + lane * 8];
            sacc[nf] = __builtin_amdgcn_mfma_f32_16x16x32_bf16(qf0, bk0, sacc[nf], 0, 0, 0);
            sacc[nf] = __builtin_amdgcn_mfma_f32_16x16x32_bf16(qf1, bk1, sacc[nf], 0, 0, 0);
        }

        // ---- online softmax; q row = wave*16 + g*4 + r, key = nf*16 + c ----
        #pragma unroll
        for (int r = 0; r < 4; r++) {
            float mx = fmaxf(fmaxf(sacc[0][r], sacc[1][r]),
                             fmaxf(sacc[2][r], sacc[3][r]));
            mx = fmaxf(mx, __shfl_xor(mx, 1));
            mx = fmaxf(mx, __shfl_xor(mx, 2));
            mx = fmaxf(mx, __shfl_xor(mx, 4));
            mx = fmaxf(mx, __shfl_xor(mx, 8));
            mx *= 0.125f;  // scale = 1/sqrt(64); positive, commutes with max
            float mn = fmaxf(mrow[r], mx);
            float al = __expf(mrow[r] - mn);
            mrow[r] = mn;
            float ps = 0.f;
            #pragma unroll
            for (int nf = 0; nf < 4; nf++) {
                float p = __expf(fmaf(sacc[nf][r], 0.125f, -mn));
                ps += p;
                // A-layout slot for (row=g*4+r, key=nf*16+c)
                Ps[wave][(nf >> 1) * 512
                         + ((g * 4 + r) + ((nf & 1) * 2 + (c >> 3)) * 16) * 8
                         + (c & 7)] = f2bs(p);
            }
            ps += __shfl_xor(ps, 1);
            ps += __shfl_xor(ps, 2);
            ps += __shfl_xor(ps, 4);
            ps += __shfl_xor(ps, 8);
            lrow[r] = lrow[r] * al + ps;
            #pragma unroll
            for (int of = 0; of < 4; of++) accO[of][r] *= al;
        }

        // ---- PV: O[16 q][64 dh] += P[16][64] * V[64][64] ----
        short8 pf0 = *(short8*)&Ps[wave][lane * 8];
        short8 pf1 = *(short8*)&Ps[wave][512 + lane * 8];
        #pragma unroll
        for (int of = 0; of < 4; of++) {
            short8 vf0 = *(short8*)&Vs[(of * 2 + 0) * 512 + lane * 8];
            short8 vf1 = *(short8*)&Vs[(of * 2 + 1) * 512 + lane * 8];
            accO[of] = __builtin_amdgcn_mfma_f32_16x16x32_bf16(pf0, vf0, accO[of], 0, 0, 0);
            accO[of] = __builtin_amdgcn_mfma_f32_16x16x32_bf16(pf1, vf1, accO[of], 0, 0, 0);
        }
        __syncthreads();
    }

    // ---- epilogue: normalize, write bf16 out[q*B+b][h*64 + dh] ----
    #pragma unroll
    for (int r = 0; r < 4; r++) {
        const float inv = 1.f / lrow[r];
        const long off = ((long)(q0 + wave * 16 + g * 4 + r) * BT + b) * DMODEL
                       + h * 64 + c;
        #pragma unroll
        for (int of = 0; of < 4; of++)
            out[off + of * 16] = f2b(accO[of][r] * inv);
    }
}

// ---------------- layer norm: y = LN(x + res) * w + b ----------------
__global__ __launch_bounds__(256) void ln_kernel(
    const float* __restrict__ x, const bf16* __restrict__ res,
    const float* __restrict__ w, const float* __restrict__ b,
    float* __restrict__ y)
{
    const long row = blockIdx.x;
    const int t = threadIdx.x;
    const float* xr = x + row * DMODEL;
    float v0 = xr[t], v1 = xr[t + 256];
    if (res) {
        v0 += b2f(res[row * DMODEL + t]);
        v1 += b2f(res[row * DMODEL + t + 256]);
    }

    __shared__ float red[256];
    red[t] = v0 + v1; __syncthreads();
    for (int s = 128; s > 0; s >>= 1) { if (t < s) red[t] += red[t + s]; __syncthreads(); }
    float mean = red[0] * (1.f / DMODEL);
    __syncthreads();
    float d0 = v0 - mean, d1 = v1 - mean;
    red[t] = d0 * d0 + d1 * d1; __syncthreads();
    for (int s = 128; s > 0; s >>= 1) { if (t < s) red[t] += red[t + s]; __syncthreads(); }
    float inv = rsqrtf(red[0] * (1.f / DMODEL) + 1e-5f);

    y[row * DMODEL + t]       = d0 * inv * w[t] + b[t];
    y[row * DMODEL + t + 256] = d1 * inv * w[t + 256] + b[t + 256];
}

// ---------------- column softmax over q (assign-attn) ----------------
__global__ __launch_bounds__(256) void col_softmax_kernel(bf16* __restrict__ s) {
    const int bh = blockIdx.y;
    const int n = blockIdx.x * 256 + threadIdx.x;
    bf16* base = s + (long)bh * (NQ * SEQ) + n;
    float mx = -1e30f;
    for (int q = 0; q < NQ; q++) mx = fmaxf(mx, b2f(base[(long)q * SEQ]));
    float sum = 0.f;
    for (int q = 0; q < NQ; q++) {
        float v = __expf(b2f(base[(long)q * SEQ]) - mx);
        base[(long)q * SEQ] = f2b(v);
        sum += v;
    }
    float inv = 1.f / sum;
    for (int q = 0; q < NQ; q++)
        base[(long)q * SEQ] = f2b(b2f(base[(long)q * SEQ]) * inv);
}

// mean over heads: o[b,q,n] = (1/8) sum_h s[b,h,q,n], fp32 out.
__global__ __launch_bounds__(256) void mean_h_kernel(
    const bf16* __restrict__ s, float* __restrict__ o)
{
    long i = (long)blockIdx.x * 256 + threadIdx.x;
    int n = (int)(i & (SEQ - 1));
    long r = i >> 10;
    int q = (int)(r & (NQ - 1));
    int b = (int)(r >> 8);
    float acc = 0.f;
    #pragma unroll
    for (int h = 0; h < 8; h++)
        acc += b2f(s[(((long)b * 8 + h) * NQ + q) * SEQ + n]);
    o[i] = acc * 0.125f;
}

// ---------------- host launch ----------------
extern "C" void kernel_launch(void* const* d_in, const int* in_sizes, int n_in,
                              void* d_out, int out_size, void* d_ws, size_t ws_size,
                              hipStream_t stream) {
    const float* src         = (const float*)d_in[0];
    const float* query_embed = (const float*)d_in[2];
    const float* pos_embed   = (const float*)d_in[3];
    const float* enc_in_w    = (const float*)d_in[4];
    const float* enc_in_b    = (const float*)d_in[5];
    const float* enc_out_w   = (const float*)d_in[6];
    const float* enc_out_b   = (const float*)d_in[7];
    const float* enc_ffn_w1  = (const float*)d_in[8];
    const float* enc_ffn_b1  = (const float*)d_in[9];
    const float* enc_ffn_w2  = (const float*)d_in[10];
    const float* enc_ffn_b2  = (const float*)d_in[11];
    const float* enc_ln_w    = (const float*)d_in[12];
    const float* enc_ln_b    = (const float*)d_in[13];
    const float* dec_in_w    = (const float*)d_in[14];
    const float* dec_in_b    = (const float*)d_in[15];
    const float* dec_out_w   = (const float*)d_in[16];
    const float* dec_out_b   = (const float*)d_in[17];
    const float* dec_ca_w    = (const float*)d_in[18];
    const float* dec_ca_b    = (const float*)d_in[19];
    const float* dec_ffn_w1  = (const float*)d_in[20];
    const float* dec_ffn_b1  = (const float*)d_in[21];
    const float* dec_ffn_w2  = (const float*)d_in[22];
    const float* dec_ffn_b2  = (const float*)d_in[23];
    const float* dec_ln_w    = (const float*)d_in[24];
    const float* dec_ln_b    = (const float*)d_in[25];
    const float* final_ln_w  = (const float*)d_in[26];
    const float* final_ln_b  = (const float*)d_in[27];

    float* wsf = (float*)d_ws;
    float* x   = wsf;                     // 4,194,304 f
    float* tgt = wsf + 4194304;           // 1,048,576 f
    bf16* QKVb = (bf16*)(wsf + 5242880);  // 12,582,912 bf16
    bf16* Fb   = QKVb + 12582912;         // 16,777,216
    bf16* E1b  = Fb + 16777216;           //  4,194,304
    bf16* E2b  = E1b + 4194304;           //  4,194,304
    bf16* kca  = QKVb + 3145728;          // decoder carve (after 2048*1536)
    bf16* vca  = kca + 4194304;

    float* out0 = (float*)d_out;          // (1,Q,B,D) 1,048,576
    float* outP = out0 + 1048576;         // (B,Q,S)   2,097,152
    float* outS = outP + 2097152;         // (B,Q,S)   2,097,152

    // dense MFMA gemm: C[M][N] = (A(+A2)) @ Bt^T + bias
    auto mgemm = [&](const void* A, int a_bf16, const float* A2, int a2_mode,
                     const float* Bt, const float* bias, void* C, int c_bf16,
                     int M, int N, int K, long a_rs, long c_rs, int relu) {
        dim3 g(N / 128, M / 128, 1);
        gemm_mfma_kernel<<<g, 256, 0, stream>>>(A, a_bf16, A2, a2_mode, Bt, bias,
                                                C, c_bf16, K, a_rs, c_rs, 1.f, relu);
    };

    copy_kernel<<<16384, 256, 0, stream>>>(src, x, 4194304);
    hipMemsetAsync(tgt, 0, 1048576 * sizeof(float), stream);

    // ---------------- encoder ----------------
    for (int i = 0; i < 6; i++) {
        const float* iw = enc_in_w + (long)i * 786432;
        const float* ib = enc_in_b + (long)i * 1536;
        mgemm(x, 0, pos_embed, 1, iw, ib, QKVb, 1, 8192, 1024, 512, 512, 1536, 0);
        mgemm(x, 0, nullptr, 0, iw + 524288, ib + 1024, QKVb + 1024, 1,
              8192, 512, 512, 512, 1536, 0);
        fattn_mfma_kernel<<<dim3(16, 64), 256, 0, stream>>>(QKVb, E1b, 1024);
        mgemm(E1b, 1, nullptr, 0, enc_out_w + (long)i * 262144, enc_out_b + (long)i * 512,
              E2b, 1, 8192, 512, 512, 512, 512, 0);
        ln_kernel<<<8192, 256, 0, stream>>>(x, E2b, enc_ln_w + (long)i * 1024,
                                            enc_ln_b + (long)i * 1024, x);
        mgemm(x, 0, nullptr, 0, enc_ffn_w1 + (long)i * 1048576, enc_ffn_b1 + (long)i * 2048,
              Fb, 1, 8192, 2048, 512, 512, 2048, 1);
        mgemm(Fb, 1, nullptr, 0, enc_ffn_w2 + (long)i * 1048576, enc_ffn_b2 + (long)i * 512,
              E1b, 1, 8192, 512, 2048, 2048, 512, 0);
        ln_kernel<<<8192, 256, 0, stream>>>(x, E1b, enc_ln_w + (long)i * 1024 + 512,
                                            enc_ln_b + (long)i * 1024 + 512, x);
    }
    // x = memory

    // ---------------- decoder ----------------
    for (int i = 0; i < 6; i++) {
        const float* iw = dec_in_w + (long)i * 786432;
        const float* ib = dec_in_b + (long)i * 1536;
        mgemm(tgt, 0, query_embed, 2, iw, ib, QKVb, 1, 2048, 1024, 512, 512, 1536, 0);
        mgemm(tgt, 0, nullptr, 0, iw + 524288, ib + 1024, QKVb + 1024, 1,
              2048, 512, 512, 512, 1536, 0);
        fattn_mfma_kernel<<<dim3(4, 64), 256, 0, stream>>>(QKVb, E1b, 256);
        mgemm(E1b, 1, nullptr, 0, dec_out_w + (long)i * 262144, dec_out_b + (long)i * 512,
              E2b, 1, 2048, 512, 512, 512, 512, 0);  // E2b = sa (keep)
        ln_kernel<<<2048, 256, 0, stream>>>(tgt, E2b, dec_ln_w + (long)i * 1536,
                                            dec_ln_b + (long)i * 1536, tgt);

        // assign (cross) attention: q = sa + qpos, k = memory + pos, v = memory
        const float* cw = dec_ca_w + (long)i * 1048576;
        const float* cb = dec_ca_b + (long)i * 2048;
        mgemm(E2b, 1, query_embed, 2, cw, cb, E1b, 1, 2048, 512, 512, 512, 512, 0);   // qca
        mgemm(x, 0, pos_embed, 1, cw + 262144, cb + 512, kca, 1,
              8192, 512, 512, 512, 512, 0);                                           // kca
        mgemm(x, 0, nullptr, 0, cw + 524288, cb + 1024, vca, 1,
              8192, 512, 512, 512, 512, 0);                                           // vca
        // scores[bh][q][n] = 0.125 * qca . kca   (batched over bh = b*8+h, MFMA)
        bgemm_mfma_kernel<<<dim3(8, 2, 64), 256, 0, stream>>>(
            E1b, 4096, 64, kca, 4096, 64, Fb, 1024, 262144, 64, 0.125f);
        if (i == 5) mean_h_kernel<<<8192, 256, 0, stream>>>(Fb, outS);
        col_softmax_kernel<<<dim3(4, 64), 256, 0, stream>>>(Fb);
        if (i == 5) mean_h_kernel<<<8192, 256, 0, stream>>>(Fb, outP);
        // ca[q,(b,h),d] = P @ v  -> E2b (MFMA, V transpose-staged)
        pv_mfma_kernel<<<dim3(4, 64), 256, 0, stream>>>(Fb, vca, E2b);
        mgemm(E2b, 1, nullptr, 0, cw + 786432, cb + 1536, E1b, 1,
              2048, 512, 512, 512, 512, 0);
        ln_kernel<<<2048, 256, 0, stream>>>(tgt, E1b, dec_ln_w + (long)i * 1536 + 512,
                                            dec_ln_b + (long)i * 1536 + 512, tgt);

        // FFN
        mgemm(tgt, 0, nullptr, 0, dec_ffn_w1 + (long)i * 1048576, dec_ffn_b1 + (long)i * 2048,
              Fb, 1, 2048, 2048, 512, 512, 2048, 1);
        mgemm(Fb, 1, nullptr, 0, dec_ffn_w2 + (long)i * 1048576, dec_ffn_b2 + (long)i * 512,
              E1b, 1, 2048, 512, 2048, 2048, 512, 0);
        ln_kernel<<<2048, 256, 0, stream>>>(tgt, E1b, dec_ln_w + (long)i * 1536 + 1024,
                                            dec_ln_b + (long)i * 1536 + 1024, tgt);
    }

    // final LN -> fp32 output 0
    ln_kernel<<<2048, 256, 0, stream>>>(tgt, nullptr, final_ln_w, final_ln_b, out0);
}

// Round 5
// 4827.751 us; speedup vs baseline: 1.4054x; 1.0060x over previous
//
#include <hip/hip_runtime.h>
#include <hip/hip_bf16.h>

// DETR-style transformer forward, round 10.
// Round-9 result: 4857us. Top-5: gemm_mfma_kernel ~95us (enc FFN2 + other
// N=512 GEMMs). Counters: occupancy 11%, MfmaUtil 6.7%, VALU 13%, HBM 10%
// -- grid starvation: 128x128 tiles give 256 blocks = 1 block/CU (encoder
// N=512) and 64 blocks = 0.25/CU (decoder). Added 64x64-tile MFMA GEMM
// (4 waves, 1 m-frag x 4 n-frags per wave, 8KB LDS) and routed all
// grid-starved GEMMs through it (4x block count). Enc QKV + enc FFN1 stay
// on the 128x128 kernel (already 2-4 blocks/CU).
//
// Shapes: D=512 H=8 dh=64 DFF=2048 S=1024 B=8 Q=256 LE=LD=6

#define DMODEL 512
#define SEQ    1024
#define BT     8
#define NQ     256

using bf16 = __hip_bfloat16;
typedef short short8 __attribute__((ext_vector_type(8)));
typedef float floatx4 __attribute__((ext_vector_type(4)));

__device__ __forceinline__ float us2f(unsigned short u) {
    return __uint_as_float(((unsigned int)u) << 16);
}
__device__ __forceinline__ float b2f(bf16 x) { return __bfloat162float(x); }
__device__ __forceinline__ bf16  f2b(float x) { return __float2bfloat16(x); }
__device__ __forceinline__ short f2bs(float f) {  // RNE fp32->bf16 bits
    unsigned u = __float_as_uint(f);
    return (short)((u + 0x7fffu + ((u >> 16) & 1u)) >> 16);
}

__global__ void copy_kernel(const float* __restrict__ in, float* __restrict__ out, long n) {
    long i = (long)blockIdx.x * 256 + threadIdx.x;
    if (i < n) out[i] = in[i];
}

// ---------------- MFMA GEMM 128x128: C = alpha*(A(+A2)) @ Bt^T + bias ----------------
// A fp32 or bf16, k-contiguous, row stride a_rs. A2 fp32 (stride DMODEL):
// mode 0=none, 1=A2[row], 2=A2[row>>3]. Bt fp32 dense [N][K]. C bf16/fp32.
// grid (N/128, M/128), block 256. K%32==0.
__global__ __launch_bounds__(256) void gemm_mfma_kernel(
    const void* __restrict__ A, int a_bf16,
    const float* __restrict__ A2, int a2_mode,
    const float* __restrict__ Bt,
    const float* __restrict__ bias,
    void* __restrict__ C, int c_bf16,
    int K, long a_rs, long c_rs,
    float alpha, int relu)
{
    const int m0 = blockIdx.y * 128;
    const int n0 = blockIdx.x * 128;
    const int t = threadIdx.x;
    const int lane = t & 63;
    const int wave = t >> 6;
    const int wmf = (wave >> 1) * 4;   // wave's first m-frag (of 8)
    const int wnf = (wave & 1) * 4;    // wave's first n-frag

    // fragment-major LDS: frag f occupies [f*512, f*512+512) shorts;
    // element (r,k) at f*512 + ((r&15) + (k>>3)*16)*8 + (k&7)
    __shared__ __align__(16) short Asl[4096];
    __shared__ __align__(16) short Bsl[4096];

    const int sr = t >> 1;          // staging row 0..127
    const int kh = t & 1;           // which 16-k half
    const int wbase = (sr >> 4) * 512 + (sr & 15) * 8;
    const int wslot0 = wbase + (2 * kh) * 128;
    const int wslot1 = wbase + (2 * kh + 1) * 128;

    floatx4 acc[4][4];
    #pragma unroll
    for (int i = 0; i < 4; i++)
        #pragma unroll
        for (int j = 0; j < 4; j++)
            acc[i][j] = (floatx4){0.f, 0.f, 0.f, 0.f};

    for (int k0 = 0; k0 < K; k0 += 32) {
        {
            float f[16];
            const long base = (long)(m0 + sr) * a_rs + k0 + kh * 16;
            if (a_bf16) {
                const unsigned short* p = (const unsigned short*)A + base;
                #pragma unroll
                for (int j = 0; j < 16; j += 4) {
                    ushort4 u = *(const ushort4*)(p + j);
                    f[j] = us2f(u.x); f[j+1] = us2f(u.y);
                    f[j+2] = us2f(u.z); f[j+3] = us2f(u.w);
                }
            } else {
                const float* p = (const float*)A + base;
                #pragma unroll
                for (int j = 0; j < 16; j += 4) {
                    float4 v = *(const float4*)(p + j);
                    f[j] = v.x; f[j+1] = v.y; f[j+2] = v.z; f[j+3] = v.w;
                }
            }
            if (a2_mode) {
                const long r2 = (a2_mode == 2) ? ((long)(m0 + sr) >> 3) : (long)(m0 + sr);
                const float* p = A2 + r2 * DMODEL + k0 + kh * 16;
                #pragma unroll
                for (int j = 0; j < 16; j += 4) {
                    float4 v = *(const float4*)(p + j);
                    f[j] += v.x; f[j+1] += v.y; f[j+2] += v.z; f[j+3] += v.w;
                }
            }
            short8 s0, s1;
            #pragma unroll
            for (int j = 0; j < 8; j++) { s0[j] = f2bs(f[j]); s1[j] = f2bs(f[8 + j]); }
            *(short8*)&Asl[wslot0] = s0;
            *(short8*)&Asl[wslot1] = s1;
        }
        {
            const float* p = Bt + (long)(n0 + sr) * K + k0 + kh * 16;
            float f[16];
            #pragma unroll
            for (int j = 0; j < 16; j += 4) {
                float4 v = *(const float4*)(p + j);
                f[j] = v.x; f[j+1] = v.y; f[j+2] = v.z; f[j+3] = v.w;
            }
            short8 s0, s1;
            #pragma unroll
            for (int j = 0; j < 8; j++) { s0[j] = f2bs(f[j]); s1[j] = f2bs(f[8 + j]); }
            *(short8*)&Bsl[wslot0] = s0;
            *(short8*)&Bsl[wslot1] = s1;
        }
        __syncthreads();

        short8 af[4], bfr[4];
        #pragma unroll
        for (int i = 0; i < 4; i++)
            af[i] = *(short8*)&Asl[(wmf + i) * 512 + lane * 8];
        #pragma unroll
        for (int j = 0; j < 4; j++)
            bfr[j] = *(short8*)&Bsl[(wnf + j) * 512 + lane * 8];
        #pragma unroll
        for (int i = 0; i < 4; i++)
            #pragma unroll
            for (int j = 0; j < 4; j++)
                acc[i][j] = __builtin_amdgcn_mfma_f32_16x16x32_bf16(
                    af[i], bfr[j], acc[i][j], 0, 0, 0);
        __syncthreads();
    }

    // epilogue: D mapping col=lane&15, row=(lane>>4)*4+reg  [m89-verified]
    const int cl = lane & 15;
    const int rl = (lane >> 4) * 4;
    #pragma unroll
    for (int j = 0; j < 4; j++) {
        const int col = n0 + wnf * 16 + j * 16 + cl;
        const float bv = bias ? bias[col] : 0.f;
        #pragma unroll
        for (int i = 0; i < 4; i++) {
            const int rowb = m0 + wmf * 16 + i * 16 + rl;
            #pragma unroll
            for (int r = 0; r < 4; r++) {
                float v = acc[i][j][r] * alpha + bv;
                if (relu) v = fmaxf(v, 0.f);
                const long ci = (long)(rowb + r) * c_rs + col;
                if (c_bf16) ((bf16*)C)[ci] = f2b(v);
                else        ((float*)C)[ci] = v;
            }
        }
    }
}

// ---------------- MFMA GEMM 64x64 (high-occupancy variant) ----------------
// Same contract as gemm_mfma_kernel; grid (N/64, M/64), block 256.
// Wave w owns rows [w*16, w*16+16) x all 64 cols: 4 MFMA/K-step, 8KB LDS.
__global__ __launch_bounds__(256) void gemm_mfma64_kernel(
    const void* __restrict__ A, int a_bf16,
    const float* __restrict__ A2, int a2_mode,
    const float* __restrict__ Bt,
    const float* __restrict__ bias,
    void* __restrict__ C, int c_bf16,
    int K, long a_rs, long c_rs,
    float alpha, int relu)
{
    const int m0 = blockIdx.y * 64;
    const int n0 = blockIdx.x * 64;
    const int t = threadIdx.x;
    const int lane = t & 63;
    const int wave = t >> 6;

    __shared__ __align__(16) short Asl[2048];
    __shared__ __align__(16) short Bsl[2048];

    const int sr = t >> 2;       // staging row 0..63
    const int kh = t & 3;        // 8-elem k chunk
    const int slot = (sr >> 4) * 512 + (sr & 15) * 8 + kh * 128;

    floatx4 acc[4];
    #pragma unroll
    for (int j = 0; j < 4; j++) acc[j] = (floatx4){0.f, 0.f, 0.f, 0.f};

    for (int k0 = 0; k0 < K; k0 += 32) {
        // ---- stage A (8 k-contiguous elems / thread) ----
        {
            float f[8];
            const long base = (long)(m0 + sr) * a_rs + k0 + kh * 8;
            if (a_bf16) {
                const unsigned short* p = (const unsigned short*)A + base;
                ushort4 u0 = *(const ushort4*)p;
                ushort4 u1 = *(const ushort4*)(p + 4);
                f[0] = us2f(u0.x); f[1] = us2f(u0.y); f[2] = us2f(u0.z); f[3] = us2f(u0.w);
                f[4] = us2f(u1.x); f[5] = us2f(u1.y); f[6] = us2f(u1.z); f[7] = us2f(u1.w);
            } else {
                const float* p = (const float*)A + base;
                float4 v0 = *(const float4*)p;
                float4 v1 = *(const float4*)(p + 4);
                f[0] = v0.x; f[1] = v0.y; f[2] = v0.z; f[3] = v0.w;
                f[4] = v1.x; f[5] = v1.y; f[6] = v1.z; f[7] = v1.w;
            }
            if (a2_mode) {
                const long r2 = (a2_mode == 2) ? ((long)(m0 + sr) >> 3) : (long)(m0 + sr);
                const float* p = A2 + r2 * DMODEL + k0 + kh * 8;
                float4 v0 = *(const float4*)p;
                float4 v1 = *(const float4*)(p + 4);
                f[0] += v0.x; f[1] += v0.y; f[2] += v0.z; f[3] += v0.w;
                f[4] += v1.x; f[5] += v1.y; f[6] += v1.z; f[7] += v1.w;
            }
            short8 s;
            #pragma unroll
            for (int j = 0; j < 8; j++) s[j] = f2bs(f[j]);
            *(short8*)&Asl[slot] = s;
        }
        // ---- stage B (fp32 weights) ----
        {
            const float* p = Bt + (long)(n0 + sr) * K + k0 + kh * 8;
            float4 v0 = *(const float4*)p;
            float4 v1 = *(const float4*)(p + 4);
            short8 s;
            s[0] = f2bs(v0.x); s[1] = f2bs(v0.y); s[2] = f2bs(v0.z); s[3] = f2bs(v0.w);
            s[4] = f2bs(v1.x); s[5] = f2bs(v1.y); s[6] = f2bs(v1.z); s[7] = f2bs(v1.w);
            *(short8*)&Bsl[slot] = s;
        }
        __syncthreads();

        short8 af = *(short8*)&Asl[wave * 512 + lane * 8];
        #pragma unroll
        for (int j = 0; j < 4; j++) {
            short8 bfr = *(short8*)&Bsl[j * 512 + lane * 8];
            acc[j] = __builtin_amdgcn_mfma_f32_16x16x32_bf16(af, bfr, acc[j], 0, 0, 0);
        }
        __syncthreads();
    }

    const int cl = lane & 15;
    const int rl = (lane >> 4) * 4;
    #pragma unroll
    for (int j = 0; j < 4; j++) {
        const int col = n0 + j * 16 + cl;
        const float bv = bias ? bias[col] : 0.f;
        #pragma unroll
        for (int r = 0; r < 4; r++) {
            const int row = m0 + wave * 16 + rl + r;
            float v = acc[j][r] * alpha + bv;
            if (relu) v = fmaxf(v, 0.f);
            const long ci = (long)row * c_rs + col;
            if (c_bf16) ((bf16*)C)[ci] = f2b(v);
            else        ((float*)C)[ci] = v;
        }
    }
}

// ---------------- batched bf16 MFMA GEMM (cross-attn scores) ----------------
// C[bh*c_bo + m*c_rs + n] = alpha * sum_k A[bh*a_bo + m*a_rs + k] * B[bh*b_bo + n*b_rs + k]
__global__ __launch_bounds__(256) void bgemm_mfma_kernel(
    const bf16* __restrict__ A, long a_rs, long a_bo,
    const bf16* __restrict__ B, long b_rs, long b_bo,
    bf16* __restrict__ C, long c_rs, long c_bo,
    int K, float alpha)
{
    const int bh = blockIdx.z;
    const int m0 = blockIdx.y * 128;
    const int n0 = blockIdx.x * 128;
    const int t = threadIdx.x;
    const int lane = t & 63;
    const int wave = t >> 6;
    const int wmf = (wave >> 1) * 4;
    const int wnf = (wave & 1) * 4;

    __shared__ __align__(16) short Asl[4096];
    __shared__ __align__(16) short Bsl[4096];

    const int sr = t >> 1;
    const int kh = t & 1;
    const int wbase = (sr >> 4) * 512 + (sr & 15) * 8;
    const int wslot0 = wbase + (2 * kh) * 128;
    const int wslot1 = wbase + (2 * kh + 1) * 128;

    floatx4 acc[4][4];
    #pragma unroll
    for (int i = 0; i < 4; i++)
        #pragma unroll
        for (int j = 0; j < 4; j++)
            acc[i][j] = (floatx4){0.f, 0.f, 0.f, 0.f};

    const short* Ab = (const short*)A + (long)bh * a_bo;
    const short* Bb = (const short*)B + (long)bh * b_bo;

    for (int k0 = 0; k0 < K; k0 += 32) {
        {
            const short* p = Ab + (long)(m0 + sr) * a_rs + k0 + kh * 16;
            *(short8*)&Asl[wslot0] = *(const short8*)p;
            *(short8*)&Asl[wslot1] = *(const short8*)(p + 8);
        }
        {
            const short* p = Bb + (long)(n0 + sr) * b_rs + k0 + kh * 16;
            *(short8*)&Bsl[wslot0] = *(const short8*)p;
            *(short8*)&Bsl[wslot1] = *(const short8*)(p + 8);
        }
        __syncthreads();

        short8 af[4], bfr[4];
        #pragma unroll
        for (int i = 0; i < 4; i++)
            af[i] = *(short8*)&Asl[(wmf + i) * 512 + lane * 8];
        #pragma unroll
        for (int j = 0; j < 4; j++)
            bfr[j] = *(short8*)&Bsl[(wnf + j) * 512 + lane * 8];
        #pragma unroll
        for (int i = 0; i < 4; i++)
            #pragma unroll
            for (int j = 0; j < 4; j++)
                acc[i][j] = __builtin_amdgcn_mfma_f32_16x16x32_bf16(
                    af[i], bfr[j], acc[i][j], 0, 0, 0);
        __syncthreads();
    }

    const int cl = lane & 15;
    const int rl = (lane >> 4) * 4;
    bf16* Cb = C + (long)bh * c_bo;
    #pragma unroll
    for (int j = 0; j < 4; j++) {
        const int col = n0 + wnf * 16 + j * 16 + cl;
        #pragma unroll
        for (int i = 0; i < 4; i++) {
            const int rowb = m0 + wmf * 16 + i * 16 + rl;
            #pragma unroll
            for (int r = 0; r < 4; r++)
                Cb[(long)(rowb + r) * c_rs + col] = f2b(acc[i][j][r] * alpha);
        }
    }
}

// ---------------- PV MFMA (cross-attn): C = P @ V ----------------
// P: [64 bh][256 q][1024 k] bf16. V: (k,bh,d) at V[k*4096+bh*64+d].
// C: (q,bh,d) at C[q*4096+bh*64+d]. grid (4, 64), block 256.
__global__ __launch_bounds__(256) void pv_mfma_kernel(
    const bf16* __restrict__ P, const bf16* __restrict__ V,
    bf16* __restrict__ Cout)
{
    const int q0 = blockIdx.x * 64;
    const int bh = blockIdx.y;
    const int t = threadIdx.x;
    const int lane = t & 63;
    const int wave = t >> 6;

    __shared__ __align__(16) short As[4096];
    __shared__ __align__(16) short Vs[4096];

    const int sr = t >> 2;
    const int kh = t & 3;
    const int slot0 = ((sr >> 4) * 2 + (kh >> 1)) * 512
                    + ((sr & 15) + ((kh & 1) * 2) * 16) * 8;
    const int slot1 = slot0 + 128;
    const int vbase = (kh * 2 + (sr >> 5)) * 512 + ((sr & 31) >> 3) * 128 + (sr & 7);

    floatx4 acc[4];
    #pragma unroll
    for (int nf = 0; nf < 4; nf++) acc[nf] = (floatx4){0.f, 0.f, 0.f, 0.f};

    const short* Pb = (const short*)P + (long)bh * 262144;

    for (int kt = 0; kt < 1024; kt += 64) {
        {
            const short* p = Pb + (long)(q0 + sr) * 1024 + kt + kh * 16;
            *(short8*)&As[slot0] = *(const short8*)p;
            *(short8*)&As[slot1] = *(const short8*)(p + 8);
        }
        {
            const short* vp = (const short*)V + (long)(kt + sr) * 4096 + bh * 64 + kh * 16;
            short8 v0 = *(const short8*)vp;
            short8 v1 = *(const short8*)(vp + 8);
            #pragma unroll
            for (int j = 0; j < 8; j++) {
                Vs[vbase + j * 8]       = v0[j];
                Vs[vbase + (8 + j) * 8] = v1[j];
            }
        }
        __syncthreads();

        short8 af0 = *(short8*)&As[(wave * 2 + 0) * 512 + lane * 8];
        short8 af1 = *(short8*)&As[(wave * 2 + 1) * 512 + lane * 8];
        #pragma unroll
        for (int nf = 0; nf < 4; nf++) {
            short8 vf0 = *(short8*)&Vs[(nf * 2 + 0) * 512 + lane * 8];
            short8 vf1 = *(short8*)&Vs[(nf * 2 + 1) * 512 + lane * 8];
            acc[nf] = __builtin_amdgcn_mfma_f32_16x16x32_bf16(af0, vf0, acc[nf], 0, 0, 0);
            acc[nf] = __builtin_amdgcn_mfma_f32_16x16x32_bf16(af1, vf1, acc[nf], 0, 0, 0);
        }
        __syncthreads();
    }

    const int g = lane >> 4, c = lane & 15;
    #pragma unroll
    for (int r = 0; r < 4; r++) {
        const long off = (long)(q0 + wave * 16 + g * 4 + r) * 4096 + bh * 64 + c;
        #pragma unroll
        for (int nf = 0; nf < 4; nf++)
            Cout[off + nf * 16] = f2b(acc[nf][r]);
    }
}

// ---------------- MFMA flash self-attention ----------------
__global__ __launch_bounds__(256) void fattn_mfma_kernel(
    const bf16* __restrict__ qkv, bf16* __restrict__ out, int nk)
{
    const int q0 = blockIdx.x * 64;
    const int bh = blockIdx.y;
    const int b = bh >> 3, h = bh & 7;
    const int t = threadIdx.x;
    const int lane = t & 63;
    const int wave = t >> 6;

    __shared__ __align__(16) short Ks[4096];
    __shared__ __align__(16) short Vs[4096];
    __shared__ __align__(16) short Ps[4][1024];

    const int sr = t >> 2;
    const int kh = t & 3;
    const int slot0 = ((sr >> 4) * 2 + (kh >> 1)) * 512
                    + ((sr & 15) + ((kh & 1) * 2) * 16) * 8;
    const int slot1 = slot0 + 128;
    const int vbase = (kh * 2 + (sr >> 5)) * 512 + ((sr & 31) >> 3) * 128 + (sr & 7);

    {
        const short* p = (const short*)qkv
            + ((long)(q0 + sr) * BT + b) * 1536 + h * 64 + kh * 16;
        *(short8*)&Ks[slot0] = *(const short8*)p;
        *(short8*)&Ks[slot1] = *(const short8*)(p + 8);
    }
    __syncthreads();
    short8 qf0 = *(short8*)&Ks[(wave * 2 + 0) * 512 + lane * 8];
    short8 qf1 = *(short8*)&Ks[(wave * 2 + 1) * 512 + lane * 8];
    __syncthreads();

    const int g = lane >> 4, c = lane & 15;

    float mrow[4], lrow[4];
    #pragma unroll
    for (int r = 0; r < 4; r++) { mrow[r] = -1e30f; lrow[r] = 0.f; }
    floatx4 accO[4];
    #pragma unroll
    for (int of = 0; of < 4; of++) accO[of] = (floatx4){0.f, 0.f, 0.f, 0.f};

    for (int kt = 0; kt < nk; kt += 64) {
        const short* kp = (const short*)qkv
            + ((long)(kt + sr) * BT + b) * 1536 + 512 + h * 64 + kh * 16;
        *(short8*)&Ks[slot0] = *(const short8*)kp;
        *(short8*)&Ks[slot1] = *(const short8*)(kp + 8);
        short8 v0 = *(const short8*)(kp + 512);
        short8 v1 = *(const short8*)(kp + 520);
        #pragma unroll
        for (int j = 0; j < 8; j++) {
            Vs[vbase + j * 8]       = v0[j];
            Vs[vbase + (8 + j) * 8] = v1[j];
        }
        __syncthreads();

        floatx4 sacc[4];
        #pragma unroll
        for (int nf = 0; nf < 4; nf++) {
            sacc[nf] = (floatx4){0.f, 0.f, 0.f, 0.f};
            short8 bk0 = *(short8*)&Ks[(nf * 2 + 0) * 512 + lane * 8];
            short8 bk1 = *(short8*)&Ks[(nf * 2 + 1) * 512 + lane * 8];
            sacc[nf] = __builtin_amdgcn_mfma_f32_16x16x32_bf16(qf0, bk0, sacc[nf], 0, 0, 0);
            sacc[nf] = __builtin_amdgcn_mfma_f32_16x16x32_bf16(qf1, bk1, sacc[nf], 0, 0, 0);
        }

        #pragma unroll
        for (int r = 0; r < 4; r++) {
            float mx = fmaxf(fmaxf(sacc[0][r], sacc[1][r]),
                             fmaxf(sacc[2][r], sacc[3][r]));
            mx = fmaxf(mx, __shfl_xor(mx, 1));
            mx = fmaxf(mx, __shfl_xor(mx, 2));
            mx = fmaxf(mx, __shfl_xor(mx, 4));
            mx = fmaxf(mx, __shfl_xor(mx, 8));
            mx *= 0.125f;
            float mn = fmaxf(mrow[r], mx);
            float al = __expf(mrow[r] - mn);
            mrow[r] = mn;
            float ps = 0.f;
            #pragma unroll
            for (int nf = 0; nf < 4; nf++) {
                float p = __expf(fmaf(sacc[nf][r], 0.125f, -mn));
                ps += p;
                Ps[wave][(nf >> 1) * 512
                         + ((g * 4 + r) + ((nf & 1) * 2 + (c >> 3)) * 16) * 8
                         + (c & 7)] = f2bs(p);
            }
            ps += __shfl_xor(ps, 1);
            ps += __shfl_xor(ps, 2);
            ps += __shfl_xor(ps, 4);
            ps += __shfl_xor(ps, 8);
            lrow[r] = lrow[r] * al + ps;
            #pragma unroll
            for (int of = 0; of < 4; of++) accO[of][r] *= al;
        }

        short8 pf0 = *(short8*)&Ps[wave][lane * 8];
        short8 pf1 = *(short8*)&Ps[wave][512 + lane * 8];
        #pragma unroll
        for (int of = 0; of < 4; of++) {
            short8 vf0 = *(short8*)&Vs[(of * 2 + 0) * 512 + lane * 8];
            short8 vf1 = *(short8*)&Vs[(of * 2 + 1) * 512 + lane * 8];
            accO[of] = __builtin_amdgcn_mfma_f32_16x16x32_bf16(pf0, vf0, accO[of], 0, 0, 0);
            accO[of] = __builtin_amdgcn_mfma_f32_16x16x32_bf16(pf1, vf1, accO[of], 0, 0, 0);
        }
        __syncthreads();
    }

    #pragma unroll
    for (int r = 0; r < 4; r++) {
        const float inv = 1.f / lrow[r];
        const long off = ((long)(q0 + wave * 16 + g * 4 + r) * BT + b) * DMODEL
                       + h * 64 + c;
        #pragma unroll
        for (int of = 0; of < 4; of++)
            out[off + of * 16] = f2b(accO[of][r] * inv);
    }
}

// ---------------- layer norm: y = LN(x + res) * w + b ----------------
__global__ __launch_bounds__(256) void ln_kernel(
    const float* __restrict__ x, const bf16* __restrict__ res,
    const float* __restrict__ w, const float* __restrict__ b,
    float* __restrict__ y)
{
    const long row = blockIdx.x;
    const int t = threadIdx.x;
    const float* xr = x + row * DMODEL;
    float v0 = xr[t], v1 = xr[t + 256];
    if (res) {
        v0 += b2f(res[row * DMODEL + t]);
        v1 += b2f(res[row * DMODEL + t + 256]);
    }

    __shared__ float red[256];
    red[t] = v0 + v1; __syncthreads();
    for (int s = 128; s > 0; s >>= 1) { if (t < s) red[t] += red[t + s]; __syncthreads(); }
    float mean = red[0] * (1.f / DMODEL);
    __syncthreads();
    float d0 = v0 - mean, d1 = v1 - mean;
    red[t] = d0 * d0 + d1 * d1; __syncthreads();
    for (int s = 128; s > 0; s >>= 1) { if (t < s) red[t] += red[t + s]; __syncthreads(); }
    float inv = rsqrtf(red[0] * (1.f / DMODEL) + 1e-5f);

    y[row * DMODEL + t]       = d0 * inv * w[t] + b[t];
    y[row * DMODEL + t + 256] = d1 * inv * w[t + 256] + b[t + 256];
}

// ---------------- column softmax over q (assign-attn) ----------------
__global__ __launch_bounds__(256) void col_softmax_kernel(bf16* __restrict__ s) {
    const int bh = blockIdx.y;
    const int n = blockIdx.x * 256 + threadIdx.x;
    bf16* base = s + (long)bh * (NQ * SEQ) + n;
    float mx = -1e30f;
    for (int q = 0; q < NQ; q++) mx = fmaxf(mx, b2f(base[(long)q * SEQ]));
    float sum = 0.f;
    for (int q = 0; q < NQ; q++) {
        float v = __expf(b2f(base[(long)q * SEQ]) - mx);
        base[(long)q * SEQ] = f2b(v);
        sum += v;
    }
    float inv = 1.f / sum;
    for (int q = 0; q < NQ; q++)
        base[(long)q * SEQ] = f2b(b2f(base[(long)q * SEQ]) * inv);
}

// mean over heads: o[b,q,n] = (1/8) sum_h s[b,h,q,n], fp32 out.
__global__ __launch_bounds__(256) void mean_h_kernel(
    const bf16* __restrict__ s, float* __restrict__ o)
{
    long i = (long)blockIdx.x * 256 + threadIdx.x;
    int n = (int)(i & (SEQ - 1));
    long r = i >> 10;
    int q = (int)(r & (NQ - 1));
    int b = (int)(r >> 8);
    float acc = 0.f;
    #pragma unroll
    for (int h = 0; h < 8; h++)
        acc += b2f(s[(((long)b * 8 + h) * NQ + q) * SEQ + n]);
    o[i] = acc * 0.125f;
}

// ---------------- host launch ----------------
extern "C" void kernel_launch(void* const* d_in, const int* in_sizes, int n_in,
                              void* d_out, int out_size, void* d_ws, size_t ws_size,
                              hipStream_t stream) {
    const float* src         = (const float*)d_in[0];
    const float* query_embed = (const float*)d_in[2];
    const float* pos_embed   = (const float*)d_in[3];
    const float* enc_in_w    = (const float*)d_in[4];
    const float* enc_in_b    = (const float*)d_in[5];
    const float* enc_out_w   = (const float*)d_in[6];
    const float* enc_out_b   = (const float*)d_in[7];
    const float* enc_ffn_w1  = (const float*)d_in[8];
    const float* enc_ffn_b1  = (const float*)d_in[9];
    const float* enc_ffn_w2  = (const float*)d_in[10];
    const float* enc_ffn_b2  = (const float*)d_in[11];
    const float* enc_ln_w    = (const float*)d_in[12];
    const float* enc_ln_b    = (const float*)d_in[13];
    const float* dec_in_w    = (const float*)d_in[14];
    const float* dec_in_b    = (const float*)d_in[15];
    const float* dec_out_w   = (const float*)d_in[16];
    const float* dec_out_b   = (const float*)d_in[17];
    const float* dec_ca_w    = (const float*)d_in[18];
    const float* dec_ca_b    = (const float*)d_in[19];
    const float* dec_ffn_w1  = (const float*)d_in[20];
    const float* dec_ffn_b1  = (const float*)d_in[21];
    const float* dec_ffn_w2  = (const float*)d_in[22];
    const float* dec_ffn_b2  = (const float*)d_in[23];
    const float* dec_ln_w    = (const float*)d_in[24];
    const float* dec_ln_b    = (const float*)d_in[25];
    const float* final_ln_w  = (const float*)d_in[26];
    const float* final_ln_b  = (const float*)d_in[27];

    float* wsf = (float*)d_ws;
    float* x   = wsf;                     // 4,194,304 f
    float* tgt = wsf + 4194304;           // 1,048,576 f
    bf16* QKVb = (bf16*)(wsf + 5242880);  // 12,582,912 bf16
    bf16* Fb   = QKVb + 12582912;         // 16,777,216
    bf16* E1b  = Fb + 16777216;           //  4,194,304
    bf16* E2b  = E1b + 4194304;           //  4,194,304
    bf16* kca  = QKVb + 3145728;          // decoder carve (after 2048*1536)
    bf16* vca  = kca + 4194304;

    float* out0 = (float*)d_out;          // (1,Q,B,D) 1,048,576
    float* outP = out0 + 1048576;         // (B,Q,S)   2,097,152
    float* outS = outP + 2097152;         // (B,Q,S)   2,097,152

    auto mgemm = [&](const void* A, int a_bf16, const float* A2, int a2_mode,
                     const float* Bt, const float* bias, void* C, int c_bf16,
                     int M, int N, int K, long a_rs, long c_rs, int relu) {
        dim3 g(N / 128, M / 128, 1);
        gemm_mfma_kernel<<<g, 256, 0, stream>>>(A, a_bf16, A2, a2_mode, Bt, bias,
                                                C, c_bf16, K, a_rs, c_rs, 1.f, relu);
    };
    auto mgemm64 = [&](const void* A, int a_bf16, const float* A2, int a2_mode,
                       const float* Bt, const float* bias, void* C, int c_bf16,
                       int M, int N, int K, long a_rs, long c_rs, int relu) {
        dim3 g(N / 64, M / 64, 1);
        gemm_mfma64_kernel<<<g, 256, 0, stream>>>(A, a_bf16, A2, a2_mode, Bt, bias,
                                                  C, c_bf16, K, a_rs, c_rs, 1.f, relu);
    };

    copy_kernel<<<16384, 256, 0, stream>>>(src, x, 4194304);
    hipMemsetAsync(tgt, 0, 1048576 * sizeof(float), stream);

    // ---------------- encoder ----------------
    for (int i = 0; i < 6; i++) {
        const float* iw = enc_in_w + (long)i * 786432;
        const float* ib = enc_in_b + (long)i * 1536;
        // QKV q+k (512 blocks @128^2, 2/CU) stays on 128^2
        mgemm(x, 0, pos_embed, 1, iw, ib, QKVb, 1, 8192, 1024, 512, 512, 1536, 0);
        mgemm64(x, 0, nullptr, 0, iw + 524288, ib + 1024, QKVb + 1024, 1,
                8192, 512, 512, 512, 1536, 0);
        fattn_mfma_kernel<<<dim3(16, 64), 256, 0, stream>>>(QKVb, E1b, 1024);
        mgemm64(E1b, 1, nullptr, 0, enc_out_w + (long)i * 262144, enc_out_b + (long)i * 512,
                E2b, 1, 8192, 512, 512, 512, 512, 0);
        ln_kernel<<<8192, 256, 0, stream>>>(x, E2b, enc_ln_w + (long)i * 1024,
                                            enc_ln_b + (long)i * 1024, x);
        // FFN1 (1024 blocks @128^2, 4/CU) stays on 128^2
        mgemm(x, 0, nullptr, 0, enc_ffn_w1 + (long)i * 1048576, enc_ffn_b1 + (long)i * 2048,
              Fb, 1, 8192, 2048, 512, 512, 2048, 1);
        mgemm64(Fb, 1, nullptr, 0, enc_ffn_w2 + (long)i * 1048576, enc_ffn_b2 + (long)i * 512,
                E1b, 1, 8192, 512, 2048, 2048, 512, 0);
        ln_kernel<<<8192, 256, 0, stream>>>(x, E1b, enc_ln_w + (long)i * 1024 + 512,
                                            enc_ln_b + (long)i * 1024 + 512, x);
    }
    // x = memory

    // ---------------- decoder ----------------
    for (int i = 0; i < 6; i++) {
        const float* iw = dec_in_w + (long)i * 786432;
        const float* ib = dec_in_b + (long)i * 1536;
        mgemm64(tgt, 0, query_embed, 2, iw, ib, QKVb, 1, 2048, 1024, 512, 512, 1536, 0);
        mgemm64(tgt, 0, nullptr, 0, iw + 524288, ib + 1024, QKVb + 1024, 1,
                2048, 512, 512, 512, 1536, 0);
        fattn_mfma_kernel<<<dim3(4, 64), 256, 0, stream>>>(QKVb, E1b, 256);
        mgemm64(E1b, 1, nullptr, 0, dec_out_w + (long)i * 262144, dec_out_b + (long)i * 512,
                E2b, 1, 2048, 512, 512, 512, 512, 0);  // E2b = sa (keep)
        ln_kernel<<<2048, 256, 0, stream>>>(tgt, E2b, dec_ln_w + (long)i * 1536,
                                            dec_ln_b + (long)i * 1536, tgt);

        // assign (cross) attention: q = sa + qpos, k = memory + pos, v = memory
        const float* cw = dec_ca_w + (long)i * 1048576;
        const float* cb = dec_ca_b + (long)i * 2048;
        mgemm64(E2b, 1, query_embed, 2, cw, cb, E1b, 1, 2048, 512, 512, 512, 512, 0); // qca
        mgemm64(x, 0, pos_embed, 1, cw + 262144, cb + 512, kca, 1,
                8192, 512, 512, 512, 512, 0);                                         // kca
        mgemm64(x, 0, nullptr, 0, cw + 524288, cb + 1024, vca, 1,
                8192, 512, 512, 512, 512, 0);                                         // vca
        // scores[bh][q][n] = 0.125 * qca . kca
        bgemm_mfma_kernel<<<dim3(8, 2, 64), 256, 0, stream>>>(
            E1b, 4096, 64, kca, 4096, 64, Fb, 1024, 262144, 64, 0.125f);
        if (i == 5) mean_h_kernel<<<8192, 256, 0, stream>>>(Fb, outS);
        col_softmax_kernel<<<dim3(4, 64), 256, 0, stream>>>(Fb);
        if (i == 5) mean_h_kernel<<<8192, 256, 0, stream>>>(Fb, outP);
        // ca = P @ v
        pv_mfma_kernel<<<dim3(4, 64), 256, 0, stream>>>(Fb, vca, E2b);
        mgemm64(E2b, 1, nullptr, 0, cw + 786432, cb + 1536, E1b, 1,
                2048, 512, 512, 512, 512, 0);
        ln_kernel<<<2048, 256, 0, stream>>>(tgt, E1b, dec_ln_w + (long)i * 1536 + 512,
                                            dec_ln_b + (long)i * 1536 + 512, tgt);

        // FFN
        mgemm64(tgt, 0, nullptr, 0, dec_ffn_w1 + (long)i * 1048576, dec_ffn_b1 + (long)i * 2048,
                Fb, 1, 2048, 2048, 512, 512, 2048, 1);
        mgemm64(Fb, 1, nullptr, 0, dec_ffn_w2 + (long)i * 1048576, dec_ffn_b2 + (long)i * 512,
                E1b, 1, 2048, 512, 2048, 2048, 512, 0);
        ln_kernel<<<2048, 256, 0, stream>>>(tgt, E1b, dec_ln_w + (long)i * 1536 + 1024,
                                            dec_ln_b + (long)i * 1536 + 1024, tgt);
    }

    // final LN -> fp32 output 0
    ln_kernel<<<2048, 256, 0, stream>>>(tgt, nullptr, final_ln_w, final_ln_b, out0);
}

// Round 6
// 3953.532 us; speedup vs baseline: 1.7162x; 1.2211x over previous
//
#include <hip/hip_runtime.h>
#include <hip/hip_bf16.h>

// DETR-style transformer forward, round 11.
// Round-10: 4828us (neutral). 64^2 tile raised occupancy (43%) but doubled
// FETCH (133MB) -- A re-read 8x + fp32 B weights re-fetched + staging cvt
// VALU (27% busy). Fix: everything bf16 ONCE (numerically identical to the
// per-tile RNE rounding the GEMMs already did):
//   - cvt_kernel: 9 weight tensors fp32->bf16 per forward (useB guard, +88MB ws)
//   - ln_kernel emits bf16 activation copies xb/xpb (x+pos) | tb/tqb (tgt+qpos)
//     (useA guard, +21MB ws); prep_x/prep_tgt seed them
//   - GEMM staging: pure short8 copies when A/B bf16 (b_bf16 flag, A fast path)
// Guards fall back to round-10 behavior when ws_size is insufficient.
//
// Shapes: D=512 H=8 dh=64 DFF=2048 S=1024 B=8 Q=256 LE=LD=6
// ws: base 96.5MB (x|tgt|QKVb|Fb|E1b|E2b) + xb/xpb/tb/tqb @96.5MB + Wb @117.4MB

#define DMODEL 512
#define SEQ    1024
#define BT     8
#define NQ     256

using bf16 = __hip_bfloat16;
typedef short short8 __attribute__((ext_vector_type(8)));
typedef float floatx4 __attribute__((ext_vector_type(4)));

__device__ __forceinline__ float us2f(unsigned short u) {
    return __uint_as_float(((unsigned int)u) << 16);
}
__device__ __forceinline__ float b2f(bf16 x) { return __bfloat162float(x); }
__device__ __forceinline__ bf16  f2b(float x) { return __float2bfloat16(x); }
__device__ __forceinline__ short f2bs(float f) {  // RNE fp32->bf16 bits
    unsigned u = __float_as_uint(f);
    return (short)((u + 0x7fffu + ((u >> 16) & 1u)) >> 16);
}

__global__ void copy_kernel(const float* __restrict__ in, float* __restrict__ out, long n) {
    long i = (long)blockIdx.x * 256 + threadIdx.x;
    if (i < n) out[i] = in[i];
}

// fp32 -> bf16 bulk convert (8 elems/thread, n % 2048 == 0)
__global__ void cvt_kernel(const float* __restrict__ in, bf16* __restrict__ out, long n) {
    long i = ((long)blockIdx.x * 256 + threadIdx.x) * 8;
    if (i >= n) return;
    float4 a = *(const float4*)(in + i);
    float4 b = *(const float4*)(in + i + 4);
    short8 s;
    s[0] = f2bs(a.x); s[1] = f2bs(a.y); s[2] = f2bs(a.z); s[3] = f2bs(a.w);
    s[4] = f2bs(b.x); s[5] = f2bs(b.y); s[6] = f2bs(b.z); s[7] = f2bs(b.w);
    *(short8*)((short*)out + i) = s;
}

// x = src; xb = bf16(src); xpb = bf16(src + pos)
__global__ void prep_x_kernel(const float* __restrict__ src, const float* __restrict__ pos,
                              float* __restrict__ x, bf16* __restrict__ xb,
                              bf16* __restrict__ xpb) {
    long i = (long)blockIdx.x * 256 + threadIdx.x;
    float v = src[i];
    x[i] = v; xb[i] = f2b(v); xpb[i] = f2b(v + pos[i]);
}

// tgt = 0; tb = 0; tqb = bf16(qpos)   (row = q*8+b -> qe[row>>3])
__global__ void prep_tgt_kernel(const float* __restrict__ qe, float* __restrict__ tgt,
                                bf16* __restrict__ tb, bf16* __restrict__ tqb) {
    long i = (long)blockIdx.x * 256 + threadIdx.x;
    tgt[i] = 0.f; tb[i] = f2b(0.f);
    tqb[i] = f2b(qe[((i >> 12) << 9) + (i & 511)]);
}

// ---------------- MFMA GEMM 128x128: C = alpha*(A(+A2)) @ Bt^T + bias ----------------
// A fp32/bf16 k-contiguous, row stride a_rs. A2 fp32 mode 0/1/2. Bt fp32 or bf16
// dense [N][K] (b_bf16). C bf16/fp32. grid (N/128, M/128), block 256. K%32==0.
__global__ __launch_bounds__(256) void gemm_mfma_kernel(
    const void* __restrict__ A, int a_bf16,
    const float* __restrict__ A2, int a2_mode,
    const void* __restrict__ Bt, int b_bf16,
    const float* __restrict__ bias,
    void* __restrict__ C, int c_bf16,
    int K, long a_rs, long c_rs,
    float alpha, int relu)
{
    const int m0 = blockIdx.y * 128;
    const int n0 = blockIdx.x * 128;
    const int t = threadIdx.x;
    const int lane = t & 63;
    const int wave = t >> 6;
    const int wmf = (wave >> 1) * 4;
    const int wnf = (wave & 1) * 4;

    // fragment-major LDS: frag f at [f*512, f*512+512) shorts;
    // elem (r,k) at f*512 + ((r&15) + (k>>3)*16)*8 + (k&7)
    __shared__ __align__(16) short Asl[4096];
    __shared__ __align__(16) short Bsl[4096];

    const int sr = t >> 1;
    const int kh = t & 1;
    const int wbase = (sr >> 4) * 512 + (sr & 15) * 8;
    const int wslot0 = wbase + (2 * kh) * 128;
    const int wslot1 = wbase + (2 * kh + 1) * 128;

    floatx4 acc[4][4];
    #pragma unroll
    for (int i = 0; i < 4; i++)
        #pragma unroll
        for (int j = 0; j < 4; j++)
            acc[i][j] = (floatx4){0.f, 0.f, 0.f, 0.f};

    for (int k0 = 0; k0 < K; k0 += 32) {
        // ---- stage A ----
        if (a_bf16 && a2_mode == 0) {   // pure copy fast path
            const short* p = (const short*)A + (long)(m0 + sr) * a_rs + k0 + kh * 16;
            *(short8*)&Asl[wslot0] = *(const short8*)p;
            *(short8*)&Asl[wslot1] = *(const short8*)(p + 8);
        } else {
            float f[16];
            const long base = (long)(m0 + sr) * a_rs + k0 + kh * 16;
            if (a_bf16) {
                const unsigned short* p = (const unsigned short*)A + base;
                #pragma unroll
                for (int j = 0; j < 16; j += 4) {
                    ushort4 u = *(const ushort4*)(p + j);
                    f[j] = us2f(u.x); f[j+1] = us2f(u.y);
                    f[j+2] = us2f(u.z); f[j+3] = us2f(u.w);
                }
            } else {
                const float* p = (const float*)A + base;
                #pragma unroll
                for (int j = 0; j < 16; j += 4) {
                    float4 v = *(const float4*)(p + j);
                    f[j] = v.x; f[j+1] = v.y; f[j+2] = v.z; f[j+3] = v.w;
                }
            }
            if (a2_mode) {
                const long r2 = (a2_mode == 2) ? ((long)(m0 + sr) >> 3) : (long)(m0 + sr);
                const float* p = A2 + r2 * DMODEL + k0 + kh * 16;
                #pragma unroll
                for (int j = 0; j < 16; j += 4) {
                    float4 v = *(const float4*)(p + j);
                    f[j] += v.x; f[j+1] += v.y; f[j+2] += v.z; f[j+3] += v.w;
                }
            }
            short8 s0, s1;
            #pragma unroll
            for (int j = 0; j < 8; j++) { s0[j] = f2bs(f[j]); s1[j] = f2bs(f[8 + j]); }
            *(short8*)&Asl[wslot0] = s0;
            *(short8*)&Asl[wslot1] = s1;
        }
        // ---- stage B ----
        if (b_bf16) {
            const short* p = (const short*)Bt + (long)(n0 + sr) * K + k0 + kh * 16;
            *(short8*)&Bsl[wslot0] = *(const short8*)p;
            *(short8*)&Bsl[wslot1] = *(const short8*)(p + 8);
        } else {
            const float* p = (const float*)Bt + (long)(n0 + sr) * K + k0 + kh * 16;
            float f[16];
            #pragma unroll
            for (int j = 0; j < 16; j += 4) {
                float4 v = *(const float4*)(p + j);
                f[j] = v.x; f[j+1] = v.y; f[j+2] = v.z; f[j+3] = v.w;
            }
            short8 s0, s1;
            #pragma unroll
            for (int j = 0; j < 8; j++) { s0[j] = f2bs(f[j]); s1[j] = f2bs(f[8 + j]); }
            *(short8*)&Bsl[wslot0] = s0;
            *(short8*)&Bsl[wslot1] = s1;
        }
        __syncthreads();

        short8 af[4], bfr[4];
        #pragma unroll
        for (int i = 0; i < 4; i++)
            af[i] = *(short8*)&Asl[(wmf + i) * 512 + lane * 8];
        #pragma unroll
        for (int j = 0; j < 4; j++)
            bfr[j] = *(short8*)&Bsl[(wnf + j) * 512 + lane * 8];
        #pragma unroll
        for (int i = 0; i < 4; i++)
            #pragma unroll
            for (int j = 0; j < 4; j++)
                acc[i][j] = __builtin_amdgcn_mfma_f32_16x16x32_bf16(
                    af[i], bfr[j], acc[i][j], 0, 0, 0);
        __syncthreads();
    }

    const int cl = lane & 15;
    const int rl = (lane >> 4) * 4;
    #pragma unroll
    for (int j = 0; j < 4; j++) {
        const int col = n0 + wnf * 16 + j * 16 + cl;
        const float bv = bias ? bias[col] : 0.f;
        #pragma unroll
        for (int i = 0; i < 4; i++) {
            const int rowb = m0 + wmf * 16 + i * 16 + rl;
            #pragma unroll
            for (int r = 0; r < 4; r++) {
                float v = acc[i][j][r] * alpha + bv;
                if (relu) v = fmaxf(v, 0.f);
                const long ci = (long)(rowb + r) * c_rs + col;
                if (c_bf16) ((bf16*)C)[ci] = f2b(v);
                else        ((float*)C)[ci] = v;
            }
        }
    }
}

// ---------------- MFMA GEMM 64x64 (high-occupancy variant) ----------------
__global__ __launch_bounds__(256) void gemm_mfma64_kernel(
    const void* __restrict__ A, int a_bf16,
    const float* __restrict__ A2, int a2_mode,
    const void* __restrict__ Bt, int b_bf16,
    const float* __restrict__ bias,
    void* __restrict__ C, int c_bf16,
    int K, long a_rs, long c_rs,
    float alpha, int relu)
{
    const int m0 = blockIdx.y * 64;
    const int n0 = blockIdx.x * 64;
    const int t = threadIdx.x;
    const int lane = t & 63;
    const int wave = t >> 6;

    __shared__ __align__(16) short Asl[2048];
    __shared__ __align__(16) short Bsl[2048];

    const int sr = t >> 2;
    const int kh = t & 3;
    const int slot = (sr >> 4) * 512 + (sr & 15) * 8 + kh * 128;

    floatx4 acc[4];
    #pragma unroll
    for (int j = 0; j < 4; j++) acc[j] = (floatx4){0.f, 0.f, 0.f, 0.f};

    for (int k0 = 0; k0 < K; k0 += 32) {
        // ---- stage A (8 elems/thread) ----
        if (a_bf16 && a2_mode == 0) {   // pure copy fast path
            const short* p = (const short*)A + (long)(m0 + sr) * a_rs + k0 + kh * 8;
            *(short8*)&Asl[slot] = *(const short8*)p;
        } else {
            float f[8];
            const long base = (long)(m0 + sr) * a_rs + k0 + kh * 8;
            if (a_bf16) {
                const unsigned short* p = (const unsigned short*)A + base;
                ushort4 u0 = *(const ushort4*)p;
                ushort4 u1 = *(const ushort4*)(p + 4);
                f[0] = us2f(u0.x); f[1] = us2f(u0.y); f[2] = us2f(u0.z); f[3] = us2f(u0.w);
                f[4] = us2f(u1.x); f[5] = us2f(u1.y); f[6] = us2f(u1.z); f[7] = us2f(u1.w);
            } else {
                const float* p = (const float*)A + base;
                float4 v0 = *(const float4*)p;
                float4 v1 = *(const float4*)(p + 4);
                f[0] = v0.x; f[1] = v0.y; f[2] = v0.z; f[3] = v0.w;
                f[4] = v1.x; f[5] = v1.y; f[6] = v1.z; f[7] = v1.w;
            }
            if (a2_mode) {
                const long r2 = (a2_mode == 2) ? ((long)(m0 + sr) >> 3) : (long)(m0 + sr);
                const float* p = A2 + r2 * DMODEL + k0 + kh * 8;
                float4 v0 = *(const float4*)p;
                float4 v1 = *(const float4*)(p + 4);
                f[0] += v0.x; f[1] += v0.y; f[2] += v0.z; f[3] += v0.w;
                f[4] += v1.x; f[5] += v1.y; f[6] += v1.z; f[7] += v1.w;
            }
            short8 s;
            #pragma unroll
            for (int j = 0; j < 8; j++) s[j] = f2bs(f[j]);
            *(short8*)&Asl[slot] = s;
        }
        // ---- stage B ----
        if (b_bf16) {
            const short* p = (const short*)Bt + (long)(n0 + sr) * K + k0 + kh * 8;
            *(short8*)&Bsl[slot] = *(const short8*)p;
        } else {
            const float* p = (const float*)Bt + (long)(n0 + sr) * K + k0 + kh * 8;
            float4 v0 = *(const float4*)p;
            float4 v1 = *(const float4*)(p + 4);
            short8 s;
            s[0] = f2bs(v0.x); s[1] = f2bs(v0.y); s[2] = f2bs(v0.z); s[3] = f2bs(v0.w);
            s[4] = f2bs(v1.x); s[5] = f2bs(v1.y); s[6] = f2bs(v1.z); s[7] = f2bs(v1.w);
            *(short8*)&Bsl[slot] = s;
        }
        __syncthreads();

        short8 af = *(short8*)&Asl[wave * 512 + lane * 8];
        #pragma unroll
        for (int j = 0; j < 4; j++) {
            short8 bfr = *(short8*)&Bsl[j * 512 + lane * 8];
            acc[j] = __builtin_amdgcn_mfma_f32_16x16x32_bf16(af, bfr, acc[j], 0, 0, 0);
        }
        __syncthreads();
    }

    const int cl = lane & 15;
    const int rl = (lane >> 4) * 4;
    #pragma unroll
    for (int j = 0; j < 4; j++) {
        const int col = n0 + j * 16 + cl;
        const float bv = bias ? bias[col] : 0.f;
        #pragma unroll
        for (int r = 0; r < 4; r++) {
            const int row = m0 + wave * 16 + rl + r;
            float v = acc[j][r] * alpha + bv;
            if (relu) v = fmaxf(v, 0.f);
            const long ci = (long)row * c_rs + col;
            if (c_bf16) ((bf16*)C)[ci] = f2b(v);
            else        ((float*)C)[ci] = v;
        }
    }
}

// ---------------- batched bf16 MFMA GEMM (cross-attn scores) ----------------
__global__ __launch_bounds__(256) void bgemm_mfma_kernel(
    const bf16* __restrict__ A, long a_rs, long a_bo,
    const bf16* __restrict__ B, long b_rs, long b_bo,
    bf16* __restrict__ C, long c_rs, long c_bo,
    int K, float alpha)
{
    const int bh = blockIdx.z;
    const int m0 = blockIdx.y * 128;
    const int n0 = blockIdx.x * 128;
    const int t = threadIdx.x;
    const int lane = t & 63;
    const int wave = t >> 6;
    const int wmf = (wave >> 1) * 4;
    const int wnf = (wave & 1) * 4;

    __shared__ __align__(16) short Asl[4096];
    __shared__ __align__(16) short Bsl[4096];

    const int sr = t >> 1;
    const int kh = t & 1;
    const int wbase = (sr >> 4) * 512 + (sr & 15) * 8;
    const int wslot0 = wbase + (2 * kh) * 128;
    const int wslot1 = wbase + (2 * kh + 1) * 128;

    floatx4 acc[4][4];
    #pragma unroll
    for (int i = 0; i < 4; i++)
        #pragma unroll
        for (int j = 0; j < 4; j++)
            acc[i][j] = (floatx4){0.f, 0.f, 0.f, 0.f};

    const short* Ab = (const short*)A + (long)bh * a_bo;
    const short* Bb = (const short*)B + (long)bh * b_bo;

    for (int k0 = 0; k0 < K; k0 += 32) {
        {
            const short* p = Ab + (long)(m0 + sr) * a_rs + k0 + kh * 16;
            *(short8*)&Asl[wslot0] = *(const short8*)p;
            *(short8*)&Asl[wslot1] = *(const short8*)(p + 8);
        }
        {
            const short* p = Bb + (long)(n0 + sr) * b_rs + k0 + kh * 16;
            *(short8*)&Bsl[wslot0] = *(const short8*)p;
            *(short8*)&Bsl[wslot1] = *(const short8*)(p + 8);
        }
        __syncthreads();

        short8 af[4], bfr[4];
        #pragma unroll
        for (int i = 0; i < 4; i++)
            af[i] = *(short8*)&Asl[(wmf + i) * 512 + lane * 8];
        #pragma unroll
        for (int j = 0; j < 4; j++)
            bfr[j] = *(short8*)&Bsl[(wnf + j) * 512 + lane * 8];
        #pragma unroll
        for (int i = 0; i < 4; i++)
            #pragma unroll
            for (int j = 0; j < 4; j++)
                acc[i][j] = __builtin_amdgcn_mfma_f32_16x16x32_bf16(
                    af[i], bfr[j], acc[i][j], 0, 0, 0);
        __syncthreads();
    }

    const int cl = lane & 15;
    const int rl = (lane >> 4) * 4;
    bf16* Cb = C + (long)bh * c_bo;
    #pragma unroll
    for (int j = 0; j < 4; j++) {
        const int col = n0 + wnf * 16 + j * 16 + cl;
        #pragma unroll
        for (int i = 0; i < 4; i++) {
            const int rowb = m0 + wmf * 16 + i * 16 + rl;
            #pragma unroll
            for (int r = 0; r < 4; r++)
                Cb[(long)(rowb + r) * c_rs + col] = f2b(acc[i][j][r] * alpha);
        }
    }
}

// ---------------- PV MFMA (cross-attn): C = P @ V ----------------
__global__ __launch_bounds__(256) void pv_mfma_kernel(
    const bf16* __restrict__ P, const bf16* __restrict__ V,
    bf16* __restrict__ Cout)
{
    const int q0 = blockIdx.x * 64;
    const int bh = blockIdx.y;
    const int t = threadIdx.x;
    const int lane = t & 63;
    const int wave = t >> 6;

    __shared__ __align__(16) short As[4096];
    __shared__ __align__(16) short Vs[4096];

    const int sr = t >> 2;
    const int kh = t & 3;
    const int slot0 = ((sr >> 4) * 2 + (kh >> 1)) * 512
                    + ((sr & 15) + ((kh & 1) * 2) * 16) * 8;
    const int slot1 = slot0 + 128;
    const int vbase = (kh * 2 + (sr >> 5)) * 512 + ((sr & 31) >> 3) * 128 + (sr & 7);

    floatx4 acc[4];
    #pragma unroll
    for (int nf = 0; nf < 4; nf++) acc[nf] = (floatx4){0.f, 0.f, 0.f, 0.f};

    const short* Pb = (const short*)P + (long)bh * 262144;

    for (int kt = 0; kt < 1024; kt += 64) {
        {
            const short* p = Pb + (long)(q0 + sr) * 1024 + kt + kh * 16;
            *(short8*)&As[slot0] = *(const short8*)p;
            *(short8*)&As[slot1] = *(const short8*)(p + 8);
        }
        {
            const short* vp = (const short*)V + (long)(kt + sr) * 4096 + bh * 64 + kh * 16;
            short8 v0 = *(const short8*)vp;
            short8 v1 = *(const short8*)(vp + 8);
            #pragma unroll
            for (int j = 0; j < 8; j++) {
                Vs[vbase + j * 8]       = v0[j];
                Vs[vbase + (8 + j) * 8] = v1[j];
            }
        }
        __syncthreads();

        short8 af0 = *(short8*)&As[(wave * 2 + 0) * 512 + lane * 8];
        short8 af1 = *(short8*)&As[(wave * 2 + 1) * 512 + lane * 8];
        #pragma unroll
        for (int nf = 0; nf < 4; nf++) {
            short8 vf0 = *(short8*)&Vs[(nf * 2 + 0) * 512 + lane * 8];
            short8 vf1 = *(short8*)&Vs[(nf * 2 + 1) * 512 + lane * 8];
            acc[nf] = __builtin_amdgcn_mfma_f32_16x16x32_bf16(af0, vf0, acc[nf], 0, 0, 0);
            acc[nf] = __builtin_amdgcn_mfma_f32_16x16x32_bf16(af1, vf1, acc[nf], 0, 0, 0);
        }
        __syncthreads();
    }

    const int g = lane >> 4, c = lane & 15;
    #pragma unroll
    for (int r = 0; r < 4; r++) {
        const long off = (long)(q0 + wave * 16 + g * 4 + r) * 4096 + bh * 64 + c;
        #pragma unroll
        for (int nf = 0; nf < 4; nf++)
            Cout[off + nf * 16] = f2b(acc[nf][r]);
    }
}

// ---------------- MFMA flash self-attention ----------------
__global__ __launch_bounds__(256) void fattn_mfma_kernel(
    const bf16* __restrict__ qkv, bf16* __restrict__ out, int nk)
{
    const int q0 = blockIdx.x * 64;
    const int bh = blockIdx.y;
    const int b = bh >> 3, h = bh & 7;
    const int t = threadIdx.x;
    const int lane = t & 63;
    const int wave = t >> 6;

    __shared__ __align__(16) short Ks[4096];
    __shared__ __align__(16) short Vs[4096];
    __shared__ __align__(16) short Ps[4][1024];

    const int sr = t >> 2;
    const int kh = t & 3;
    const int slot0 = ((sr >> 4) * 2 + (kh >> 1)) * 512
                    + ((sr & 15) + ((kh & 1) * 2) * 16) * 8;
    const int slot1 = slot0 + 128;
    const int vbase = (kh * 2 + (sr >> 5)) * 512 + ((sr & 31) >> 3) * 128 + (sr & 7);

    {
        const short* p = (const short*)qkv
            + ((long)(q0 + sr) * BT + b) * 1536 + h * 64 + kh * 16;
        *(short8*)&Ks[slot0] = *(const short8*)p;
        *(short8*)&Ks[slot1] = *(const short8*)(p + 8);
    }
    __syncthreads();
    short8 qf0 = *(short8*)&Ks[(wave * 2 + 0) * 512 + lane * 8];
    short8 qf1 = *(short8*)&Ks[(wave * 2 + 1) * 512 + lane * 8];
    __syncthreads();

    const int g = lane >> 4, c = lane & 15;

    float mrow[4], lrow[4];
    #pragma unroll
    for (int r = 0; r < 4; r++) { mrow[r] = -1e30f; lrow[r] = 0.f; }
    floatx4 accO[4];
    #pragma unroll
    for (int of = 0; of < 4; of++) accO[of] = (floatx4){0.f, 0.f, 0.f, 0.f};

    for (int kt = 0; kt < nk; kt += 64) {
        const short* kp = (const short*)qkv
            + ((long)(kt + sr) * BT + b) * 1536 + 512 + h * 64 + kh * 16;
        *(short8*)&Ks[slot0] = *(const short8*)kp;
        *(short8*)&Ks[slot1] = *(const short8*)(kp + 8);
        short8 v0 = *(const short8*)(kp + 512);
        short8 v1 = *(const short8*)(kp + 520);
        #pragma unroll
        for (int j = 0; j < 8; j++) {
            Vs[vbase + j * 8]       = v0[j];
            Vs[vbase + (8 + j) * 8] = v1[j];
        }
        __syncthreads();

        floatx4 sacc[4];
        #pragma unroll
        for (int nf = 0; nf < 4; nf++) {
            sacc[nf] = (floatx4){0.f, 0.f, 0.f, 0.f};
            short8 bk0 = *(short8*)&Ks[(nf * 2 + 0) * 512 + lane * 8];
            short8 bk1 = *(short8*)&Ks[(nf * 2 + 1) * 512 + lane * 8];
            sacc[nf] = __builtin_amdgcn_mfma_f32_16x16x32_bf16(qf0, bk0, sacc[nf], 0, 0, 0);
            sacc[nf] = __builtin_amdgcn_mfma_f32_16x16x32_bf16(qf1, bk1, sacc[nf], 0, 0, 0);
        }

        #pragma unroll
        for (int r = 0; r < 4; r++) {
            float mx = fmaxf(fmaxf(sacc[0][r], sacc[1][r]),
                             fmaxf(sacc[2][r], sacc[3][r]));
            mx = fmaxf(mx, __shfl_xor(mx, 1));
            mx = fmaxf(mx, __shfl_xor(mx, 2));
            mx = fmaxf(mx, __shfl_xor(mx, 4));
            mx = fmaxf(mx, __shfl_xor(mx, 8));
            mx *= 0.125f;
            float mn = fmaxf(mrow[r], mx);
            float al = __expf(mrow[r] - mn);
            mrow[r] = mn;
            float ps = 0.f;
            #pragma unroll
            for (int nf = 0; nf < 4; nf++) {
                float p = __expf(fmaf(sacc[nf][r], 0.125f, -mn));
                ps += p;
                Ps[wave][(nf >> 1) * 512
                         + ((g * 4 + r) + ((nf & 1) * 2 + (c >> 3)) * 16) * 8
                         + (c & 7)] = f2bs(p);
            }
            ps += __shfl_xor(ps, 1);
            ps += __shfl_xor(ps, 2);
            ps += __shfl_xor(ps, 4);
            ps += __shfl_xor(ps, 8);
            lrow[r] = lrow[r] * al + ps;
            #pragma unroll
            for (int of = 0; of < 4; of++) accO[of][r] *= al;
        }

        short8 pf0 = *(short8*)&Ps[wave][lane * 8];
        short8 pf1 = *(short8*)&Ps[wave][512 + lane * 8];
        #pragma unroll
        for (int of = 0; of < 4; of++) {
            short8 vf0 = *(short8*)&Vs[(of * 2 + 0) * 512 + lane * 8];
            short8 vf1 = *(short8*)&Vs[(of * 2 + 1) * 512 + lane * 8];
            accO[of] = __builtin_amdgcn_mfma_f32_16x16x32_bf16(pf0, vf0, accO[of], 0, 0, 0);
            accO[of] = __builtin_amdgcn_mfma_f32_16x16x32_bf16(pf1, vf1, accO[of], 0, 0, 0);
        }
        __syncthreads();
    }

    #pragma unroll
    for (int r = 0; r < 4; r++) {
        const float inv = 1.f / lrow[r];
        const long off = ((long)(q0 + wave * 16 + g * 4 + r) * BT + b) * DMODEL
                       + h * 64 + c;
        #pragma unroll
        for (int of = 0; of < 4; of++)
            out[off + of * 16] = f2b(accO[of][r] * inv);
    }
}

// ---------------- layer norm: y = LN(x + res) * w + b (+ bf16 copies) ----------------
// yb (opt): bf16(y). ypb (opt): bf16(y + pos[row or row>>3]).
__global__ __launch_bounds__(256) void ln_kernel(
    const float* __restrict__ x, const bf16* __restrict__ res,
    const float* __restrict__ w, const float* __restrict__ b,
    float* __restrict__ y, bf16* __restrict__ yb, bf16* __restrict__ ypb,
    const float* __restrict__ pos, int pos_mode)
{
    const long row = blockIdx.x;
    const int t = threadIdx.x;
    const float* xr = x + row * DMODEL;
    float v0 = xr[t], v1 = xr[t + 256];
    if (res) {
        v0 += b2f(res[row * DMODEL + t]);
        v1 += b2f(res[row * DMODEL + t + 256]);
    }

    __shared__ float red[256];
    red[t] = v0 + v1; __syncthreads();
    for (int s = 128; s > 0; s >>= 1) { if (t < s) red[t] += red[t + s]; __syncthreads(); }
    float mean = red[0] * (1.f / DMODEL);
    __syncthreads();
    float d0 = v0 - mean, d1 = v1 - mean;
    red[t] = d0 * d0 + d1 * d1; __syncthreads();
    for (int s = 128; s > 0; s >>= 1) { if (t < s) red[t] += red[t + s]; __syncthreads(); }
    float inv = rsqrtf(red[0] * (1.f / DMODEL) + 1e-5f);

    float o0 = d0 * inv * w[t] + b[t];
    float o1 = d1 * inv * w[t + 256] + b[t + 256];
    y[row * DMODEL + t]       = o0;
    y[row * DMODEL + t + 256] = o1;
    if (yb) {
        yb[row * DMODEL + t]       = f2b(o0);
        yb[row * DMODEL + t + 256] = f2b(o1);
    }
    if (ypb) {
        const float* pr = pos + ((pos_mode == 2) ? (row >> 3) : row) * DMODEL;
        ypb[row * DMODEL + t]       = f2b(o0 + pr[t]);
        ypb[row * DMODEL + t + 256] = f2b(o1 + pr[t + 256]);
    }
}

// ---------------- column softmax over q (assign-attn) ----------------
__global__ __launch_bounds__(256) void col_softmax_kernel(bf16* __restrict__ s) {
    const int bh = blockIdx.y;
    const int n = blockIdx.x * 256 + threadIdx.x;
    bf16* base = s + (long)bh * (NQ * SEQ) + n;
    float mx = -1e30f;
    for (int q = 0; q < NQ; q++) mx = fmaxf(mx, b2f(base[(long)q * SEQ]));
    float sum = 0.f;
    for (int q = 0; q < NQ; q++) {
        float v = __expf(b2f(base[(long)q * SEQ]) - mx);
        base[(long)q * SEQ] = f2b(v);
        sum += v;
    }
    float inv = 1.f / sum;
    for (int q = 0; q < NQ; q++)
        base[(long)q * SEQ] = f2b(b2f(base[(long)q * SEQ]) * inv);
}

// mean over heads: o[b,q,n] = (1/8) sum_h s[b,h,q,n], fp32 out.
__global__ __launch_bounds__(256) void mean_h_kernel(
    const bf16* __restrict__ s, float* __restrict__ o)
{
    long i = (long)blockIdx.x * 256 + threadIdx.x;
    int n = (int)(i & (SEQ - 1));
    long r = i >> 10;
    int q = (int)(r & (NQ - 1));
    int b = (int)(r >> 8);
    float acc = 0.f;
    #pragma unroll
    for (int h = 0; h < 8; h++)
        acc += b2f(s[(((long)b * 8 + h) * NQ + q) * SEQ + n]);
    o[i] = acc * 0.125f;
}

// ---------------- host launch ----------------
extern "C" void kernel_launch(void* const* d_in, const int* in_sizes, int n_in,
                              void* d_out, int out_size, void* d_ws, size_t ws_size,
                              hipStream_t stream) {
    const float* src         = (const float*)d_in[0];
    const float* query_embed = (const float*)d_in[2];
    const float* pos_embed   = (const float*)d_in[3];
    const float* enc_in_w    = (const float*)d_in[4];
    const float* enc_in_b    = (const float*)d_in[5];
    const float* enc_out_w   = (const float*)d_in[6];
    const float* enc_out_b   = (const float*)d_in[7];
    const float* enc_ffn_w1  = (const float*)d_in[8];
    const float* enc_ffn_b1  = (const float*)d_in[9];
    const float* enc_ffn_w2  = (const float*)d_in[10];
    const float* enc_ffn_b2  = (const float*)d_in[11];
    const float* enc_ln_w    = (const float*)d_in[12];
    const float* enc_ln_b    = (const float*)d_in[13];
    const float* dec_in_w    = (const float*)d_in[14];
    const float* dec_in_b    = (const float*)d_in[15];
    const float* dec_out_w   = (const float*)d_in[16];
    const float* dec_out_b   = (const float*)d_in[17];
    const float* dec_ca_w    = (const float*)d_in[18];
    const float* dec_ca_b    = (const float*)d_in[19];
    const float* dec_ffn_w1  = (const float*)d_in[20];
    const float* dec_ffn_b1  = (const float*)d_in[21];
    const float* dec_ffn_w2  = (const float*)d_in[22];
    const float* dec_ffn_b2  = (const float*)d_in[23];
    const float* dec_ln_w    = (const float*)d_in[24];
    const float* dec_ln_b    = (const float*)d_in[25];
    const float* final_ln_w  = (const float*)d_in[26];
    const float* final_ln_b  = (const float*)d_in[27];

    float* wsf = (float*)d_ws;
    float* x   = wsf;                     // 4,194,304 f
    float* tgt = wsf + 4194304;           // 1,048,576 f
    bf16* QKVb = (bf16*)(wsf + 5242880);  // 12,582,912 bf16
    bf16* Fb   = QKVb + 12582912;         // 16,777,216
    bf16* E1b  = Fb + 16777216;           //  4,194,304
    bf16* E2b  = E1b + 4194304;           //  4,194,304
    bf16* kca  = QKVb + 3145728;          // decoder carve (after 2048*1536)
    bf16* vca  = kca + 4194304;

    // extended regions (guarded)
    const bool useA = ws_size >= 117440512ull;   // + xb/xpb/tb/tqb (21 MB)
    const bool useB = ws_size >= 205520896ull;   // + bf16 weights (88 MB)
    bf16* xb   = (bf16*)((char*)d_ws + 96468992);
    bf16* xpb  = (bf16*)((char*)d_ws + 104857600);
    bf16* tb   = (bf16*)((char*)d_ws + 113246208);
    bf16* tqb  = (bf16*)((char*)d_ws + 115343360);
    bf16* Wb   = (bf16*)((char*)d_ws + 117440512);
    bf16* ei16  = Wb;
    bf16* eo16  = Wb + 4718592;
    bf16* ef116 = Wb + 6291456;
    bf16* ef216 = Wb + 12582912;
    bf16* di16  = Wb + 18874368;
    bf16* do16  = Wb + 23592960;
    bf16* dca16 = Wb + 25165824;
    bf16* df116 = Wb + 31457280;
    bf16* df216 = Wb + 37748736;

    float* out0 = (float*)d_out;          // (1,Q,B,D) 1,048,576
    float* outP = out0 + 1048576;         // (B,Q,S)   2,097,152
    float* outS = outP + 2097152;         // (B,Q,S)   2,097,152

    auto mgemm = [&](const void* A, int a_bf16, const float* A2, int a2_mode,
                     const void* Bt, int b_bf16, const float* bias, void* C, int c_bf16,
                     int M, int N, int K, long a_rs, long c_rs, int relu) {
        dim3 g(N / 128, M / 128, 1);
        gemm_mfma_kernel<<<g, 256, 0, stream>>>(A, a_bf16, A2, a2_mode, Bt, b_bf16, bias,
                                                C, c_bf16, K, a_rs, c_rs, 1.f, relu);
    };
    auto mgemm64 = [&](const void* A, int a_bf16, const float* A2, int a2_mode,
                       const void* Bt, int b_bf16, const float* bias, void* C, int c_bf16,
                       int M, int N, int K, long a_rs, long c_rs, int relu) {
        dim3 g(N / 64, M / 64, 1);
        gemm_mfma64_kernel<<<g, 256, 0, stream>>>(A, a_bf16, A2, a2_mode, Bt, b_bf16, bias,
                                                  C, c_bf16, K, a_rs, c_rs, 1.f, relu);
    };

    // one-time weight conversion (per forward; ~30us)
    if (useB) {
        cvt_kernel<<<2304, 256, 0, stream>>>(enc_in_w,   ei16,  4718592);
        cvt_kernel<<<768,  256, 0, stream>>>(enc_out_w,  eo16,  1572864);
        cvt_kernel<<<3072, 256, 0, stream>>>(enc_ffn_w1, ef116, 6291456);
        cvt_kernel<<<3072, 256, 0, stream>>>(enc_ffn_w2, ef216, 6291456);
        cvt_kernel<<<2304, 256, 0, stream>>>(dec_in_w,   di16,  4718592);
        cvt_kernel<<<768,  256, 0, stream>>>(dec_out_w,  do16,  1572864);
        cvt_kernel<<<3072, 256, 0, stream>>>(dec_ca_w,   dca16, 6291456);
        cvt_kernel<<<3072, 256, 0, stream>>>(dec_ffn_w1, df116, 6291456);
        cvt_kernel<<<3072, 256, 0, stream>>>(dec_ffn_w2, df216, 6291456);
    }

    if (useA) prep_x_kernel<<<16384, 256, 0, stream>>>(src, pos_embed, x, xb, xpb);
    else      copy_kernel<<<16384, 256, 0, stream>>>(src, x, 4194304);
    if (useA) prep_tgt_kernel<<<4096, 256, 0, stream>>>(query_embed, tgt, tb, tqb);
    else      hipMemsetAsync(tgt, 0, 1048576 * sizeof(float), stream);

    // ---------------- encoder ----------------
    for (int i = 0; i < 6; i++) {
        const float* iw = enc_in_w + (long)i * 786432;
        const float* ib = enc_in_b + (long)i * 1536;
        const void* Bqk = useB ? (const void*)(ei16 + (long)i * 786432) : (const void*)iw;
        const void* Bv  = useB ? (const void*)(ei16 + (long)i * 786432 + 524288)
                               : (const void*)(iw + 524288);
        const void* Bo  = useB ? (const void*)(eo16 + (long)i * 262144)
                               : (const void*)(enc_out_w + (long)i * 262144);
        const void* Bf1 = useB ? (const void*)(ef116 + (long)i * 1048576)
                               : (const void*)(enc_ffn_w1 + (long)i * 1048576);
        const void* Bf2 = useB ? (const void*)(ef216 + (long)i * 1048576)
                               : (const void*)(enc_ffn_w2 + (long)i * 1048576);

        if (useA) mgemm(xpb, 1, nullptr, 0, Bqk, useB, ib, QKVb, 1,
                        8192, 1024, 512, 512, 1536, 0);
        else      mgemm(x, 0, pos_embed, 1, Bqk, useB, ib, QKVb, 1,
                        8192, 1024, 512, 512, 1536, 0);
        mgemm64(useA ? (const void*)xb : (const void*)x, useA, nullptr, 0,
                Bv, useB, ib + 1024, QKVb + 1024, 1, 8192, 512, 512, 512, 1536, 0);
        fattn_mfma_kernel<<<dim3(16, 64), 256, 0, stream>>>(QKVb, E1b, 1024);
        mgemm64(E1b, 1, nullptr, 0, Bo, useB, enc_out_b + (long)i * 512,
                E2b, 1, 8192, 512, 512, 512, 512, 0);
        ln_kernel<<<8192, 256, 0, stream>>>(x, E2b, enc_ln_w + (long)i * 1024,
                                            enc_ln_b + (long)i * 1024, x,
                                            useA ? xb : nullptr, useA ? xpb : nullptr,
                                            pos_embed, 1);
        mgemm(useA ? (const void*)xb : (const void*)x, useA, nullptr, 0,
              Bf1, useB, enc_ffn_b1 + (long)i * 2048, Fb, 1,
              8192, 2048, 512, 512, 2048, 1);
        mgemm64(Fb, 1, nullptr, 0, Bf2, useB, enc_ffn_b2 + (long)i * 512,
                E1b, 1, 8192, 512, 2048, 2048, 512, 0);
        ln_kernel<<<8192, 256, 0, stream>>>(x, E1b, enc_ln_w + (long)i * 1024 + 512,
                                            enc_ln_b + (long)i * 1024 + 512, x,
                                            useA ? xb : nullptr, useA ? xpb : nullptr,
                                            pos_embed, 1);
    }
    // x = memory; xb = bf16(memory); xpb = bf16(memory + pos)

    // ---------------- decoder ----------------
    for (int i = 0; i < 6; i++) {
        const float* iw = dec_in_w + (long)i * 786432;
        const float* ib = dec_in_b + (long)i * 1536;
        const float* cw = dec_ca_w + (long)i * 1048576;
        const float* cb = dec_ca_b + (long)i * 2048;
        const void* Bqk = useB ? (const void*)(di16 + (long)i * 786432) : (const void*)iw;
        const void* Bv  = useB ? (const void*)(di16 + (long)i * 786432 + 524288)
                               : (const void*)(iw + 524288);
        const void* Bo  = useB ? (const void*)(do16 + (long)i * 262144)
                               : (const void*)(dec_out_w + (long)i * 262144);
        const void* Bcq = useB ? (const void*)(dca16 + (long)i * 1048576) : (const void*)cw;
        const void* Bck = useB ? (const void*)(dca16 + (long)i * 1048576 + 262144)
                               : (const void*)(cw + 262144);
        const void* Bcv = useB ? (const void*)(dca16 + (long)i * 1048576 + 524288)
                               : (const void*)(cw + 524288);
        const void* Bco = useB ? (const void*)(dca16 + (long)i * 1048576 + 786432)
                               : (const void*)(cw + 786432);
        const void* Bf1 = useB ? (const void*)(df116 + (long)i * 1048576)
                               : (const void*)(dec_ffn_w1 + (long)i * 1048576);
        const void* Bf2 = useB ? (const void*)(df216 + (long)i * 1048576)
                               : (const void*)(dec_ffn_w2 + (long)i * 1048576);

        if (useA) mgemm64(tqb, 1, nullptr, 0, Bqk, useB, ib, QKVb, 1,
                          2048, 1024, 512, 512, 1536, 0);
        else      mgemm64(tgt, 0, query_embed, 2, Bqk, useB, ib, QKVb, 1,
                          2048, 1024, 512, 512, 1536, 0);
        mgemm64(useA ? (const void*)tb : (const void*)tgt, useA, nullptr, 0,
                Bv, useB, ib + 1024, QKVb + 1024, 1, 2048, 512, 512, 512, 1536, 0);
        fattn_mfma_kernel<<<dim3(4, 64), 256, 0, stream>>>(QKVb, E1b, 256);
        mgemm64(E1b, 1, nullptr, 0, Bo, useB, dec_out_b + (long)i * 512,
                E2b, 1, 2048, 512, 512, 512, 512, 0);  // E2b = sa (keep)
        ln_kernel<<<2048, 256, 0, stream>>>(tgt, E2b, dec_ln_w + (long)i * 1536,
                                            dec_ln_b + (long)i * 1536, tgt,
                                            useA ? tb : nullptr, useA ? tqb : nullptr,
                                            query_embed, 2);

        // assign (cross) attention: q = sa + qpos, k = memory + pos, v = memory
        mgemm64(E2b, 1, query_embed, 2, Bcq, useB, cb, E1b, 1,
                2048, 512, 512, 512, 512, 0);                                        // qca
        if (useA) mgemm64(xpb, 1, nullptr, 0, Bck, useB, cb + 512, kca, 1,
                          8192, 512, 512, 512, 512, 0);                              // kca
        else      mgemm64(x, 0, pos_embed, 1, Bck, useB, cb + 512, kca, 1,
                          8192, 512, 512, 512, 512, 0);
        mgemm64(useA ? (const void*)xb : (const void*)x, useA, nullptr, 0,
                Bcv, useB, cb + 1024, vca, 1, 8192, 512, 512, 512, 512, 0);          // vca
        bgemm_mfma_kernel<<<dim3(8, 2, 64), 256, 0, stream>>>(
            E1b, 4096, 64, kca, 4096, 64, Fb, 1024, 262144, 64, 0.125f);
        if (i == 5) mean_h_kernel<<<8192, 256, 0, stream>>>(Fb, outS);
        col_softmax_kernel<<<dim3(4, 64), 256, 0, stream>>>(Fb);
        if (i == 5) mean_h_kernel<<<8192, 256, 0, stream>>>(Fb, outP);
        pv_mfma_kernel<<<dim3(4, 64), 256, 0, stream>>>(Fb, vca, E2b);
        mgemm64(E2b, 1, nullptr, 0, Bco, useB, cb + 1536, E1b, 1,
                2048, 512, 512, 512, 512, 0);
        ln_kernel<<<2048, 256, 0, stream>>>(tgt, E1b, dec_ln_w + (long)i * 1536 + 512,
                                            dec_ln_b + (long)i * 1536 + 512, tgt,
                                            useA ? tb : nullptr, useA ? tqb : nullptr,
                                            query_embed, 2);

        // FFN
        mgemm64(useA ? (const void*)tb : (const void*)tgt, useA, nullptr, 0,
                Bf1, useB, dec_ffn_b1 + (long)i * 2048, Fb, 1,
                2048, 2048, 512, 512, 2048, 1);
        mgemm64(Fb, 1, nullptr, 0, Bf2, useB, dec_ffn_b2 + (long)i * 512,
                E1b, 1, 2048, 512, 2048, 2048, 512, 0);
        ln_kernel<<<2048, 256, 0, stream>>>(tgt, E1b, dec_ln_w + (long)i * 1536 + 1024,
                                            dec_ln_b + (long)i * 1536 + 1024, tgt,
                                            useA ? tb : nullptr, useA ? tqb : nullptr,
                                            query_embed, 2);
    }

    // final LN -> fp32 output 0
    ln_kernel<<<2048, 256, 0, stream>>>(tgt, nullptr, final_ln_w, final_ln_b, out0,
                                        nullptr, nullptr, nullptr, 0);
}

// Round 7
// 3664.218 us; speedup vs baseline: 1.8517x; 1.0790x over previous
//
#include <hip/hip_runtime.h>
#include <hip/hip_bf16.h>

// DETR-style transformer forward, round 12.
// Round-11: 3954us. Top: gemm_mfma64 (FFN2, 82us, MfmaUtil 8%, ~770cyc per
// K-step = latency-serial staging) and fattn (82us). This round: GEMM staging
// moved to global_load_lds width=16 (no VGPR round-trip; guide m151/m193:
// +35..67%) on all pure-bf16 paths (= all GEMMs since round-11), and the
// 64^2 kernel's K-step doubled to 64 (8 MFMA/wave per barrier-pair).
// LDS frag layout is linear-in-lane per frag: frag f, lane l <-> row
// f*16+(l&15), k (l>>4)*8 -- each wave issues per-frag gload_lds with
// per-lane global addresses and wave-uniform LDS base. fattn unchanged.
//
// Shapes: D=512 H=8 dh=64 DFF=2048 S=1024 B=8 Q=256 LE=LD=6

#define DMODEL 512
#define SEQ    1024
#define BT     8
#define NQ     256

using bf16 = __hip_bfloat16;
typedef short short8 __attribute__((ext_vector_type(8)));
typedef float floatx4 __attribute__((ext_vector_type(4)));

__device__ __forceinline__ float us2f(unsigned short u) {
    return __uint_as_float(((unsigned int)u) << 16);
}
__device__ __forceinline__ float b2f(bf16 x) { return __bfloat162float(x); }
__device__ __forceinline__ bf16  f2b(float x) { return __float2bfloat16(x); }
__device__ __forceinline__ short f2bs(float f) {  // RNE fp32->bf16 bits
    unsigned u = __float_as_uint(f);
    return (short)((u + 0x7fffu + ((u >> 16) & 1u)) >> 16);
}

// async global->LDS, 16B per lane; LDS dest = wave-uniform base + lane*16.
__device__ __forceinline__ void gl_lds16(const void* g, void* l) {
    __builtin_amdgcn_global_load_lds(
        (__attribute__((address_space(1))) void*)g,
        (__attribute__((address_space(3))) void*)l, 16, 0, 0);
}

__global__ void copy_kernel(const float* __restrict__ in, float* __restrict__ out, long n) {
    long i = (long)blockIdx.x * 256 + threadIdx.x;
    if (i < n) out[i] = in[i];
}

// fp32 -> bf16 bulk convert (8 elems/thread, n % 2048 == 0)
__global__ void cvt_kernel(const float* __restrict__ in, bf16* __restrict__ out, long n) {
    long i = ((long)blockIdx.x * 256 + threadIdx.x) * 8;
    if (i >= n) return;
    float4 a = *(const float4*)(in + i);
    float4 b = *(const float4*)(in + i + 4);
    short8 s;
    s[0] = f2bs(a.x); s[1] = f2bs(a.y); s[2] = f2bs(a.z); s[3] = f2bs(a.w);
    s[4] = f2bs(b.x); s[5] = f2bs(b.y); s[6] = f2bs(b.z); s[7] = f2bs(b.w);
    *(short8*)((short*)out + i) = s;
}

// x = src; xb = bf16(src); xpb = bf16(src + pos)
__global__ void prep_x_kernel(const float* __restrict__ src, const float* __restrict__ pos,
                              float* __restrict__ x, bf16* __restrict__ xb,
                              bf16* __restrict__ xpb) {
    long i = (long)blockIdx.x * 256 + threadIdx.x;
    float v = src[i];
    x[i] = v; xb[i] = f2b(v); xpb[i] = f2b(v + pos[i]);
}

// tgt = 0; tb = 0; tqb = bf16(qpos)   (row = q*8+b -> qe[row>>3])
__global__ void prep_tgt_kernel(const float* __restrict__ qe, float* __restrict__ tgt,
                                bf16* __restrict__ tb, bf16* __restrict__ tqb) {
    long i = (long)blockIdx.x * 256 + threadIdx.x;
    tgt[i] = 0.f; tb[i] = f2b(0.f);
    tqb[i] = f2b(qe[((i >> 12) << 9) + (i & 511)]);
}

// ---------------- MFMA GEMM 128x128: C = alpha*(A(+A2)) @ Bt^T + bias ----------------
// A fp32/bf16 k-contiguous, row stride a_rs. A2 fp32 mode 0/1/2. Bt fp32 or bf16
// dense [N][K] (b_bf16). C bf16/fp32. grid (N/128, M/128), block 256. K%32==0.
__global__ __launch_bounds__(256) void gemm_mfma_kernel(
    const void* __restrict__ A, int a_bf16,
    const float* __restrict__ A2, int a2_mode,
    const void* __restrict__ Bt, int b_bf16,
    const float* __restrict__ bias,
    void* __restrict__ C, int c_bf16,
    int K, long a_rs, long c_rs,
    float alpha, int relu)
{
    const int m0 = blockIdx.y * 128;
    const int n0 = blockIdx.x * 128;
    const int t = threadIdx.x;
    const int lane = t & 63;
    const int wave = t >> 6;
    const int wmf = (wave >> 1) * 4;
    const int wnf = (wave & 1) * 4;

    // fragment-major LDS: frag f at [f*512, f*512+512) shorts;
    // elem (r,k) at f*512 + ((r&15) + (k>>3)*16)*8 + (k&7)
    // => 16B slot l of frag f holds row f*16+(l&15), k (l>>4)*8..+8  (lane-linear)
    __shared__ __align__(16) short Asl[4096];
    __shared__ __align__(16) short Bsl[4096];

    const int sr = t >> 1;
    const int kh = t & 1;
    const int wbase = (sr >> 4) * 512 + (sr & 15) * 8;
    const int wslot0 = wbase + (2 * kh) * 128;
    const int wslot1 = wbase + (2 * kh + 1) * 128;

    floatx4 acc[4][4];
    #pragma unroll
    for (int i = 0; i < 4; i++)
        #pragma unroll
        for (int j = 0; j < 4; j++)
            acc[i][j] = (floatx4){0.f, 0.f, 0.f, 0.f};

    for (int k0 = 0; k0 < K; k0 += 32) {
        // ---- stage A ----
        if (a_bf16 && a2_mode == 0) {   // async direct-to-LDS (frags 2w, 2w+1)
            const short* Ag = (const short*)A
                + (long)(m0 + wave * 32 + (lane & 15)) * a_rs + k0 + (lane >> 4) * 8;
            gl_lds16(Ag,             &Asl[(wave * 2 + 0) * 512]);
            gl_lds16(Ag + 16 * a_rs, &Asl[(wave * 2 + 1) * 512]);
        } else {
            float f[16];
            const long base = (long)(m0 + sr) * a_rs + k0 + kh * 16;
            if (a_bf16) {
                const unsigned short* p = (const unsigned short*)A + base;
                #pragma unroll
                for (int j = 0; j < 16; j += 4) {
                    ushort4 u = *(const ushort4*)(p + j);
                    f[j] = us2f(u.x); f[j+1] = us2f(u.y);
                    f[j+2] = us2f(u.z); f[j+3] = us2f(u.w);
                }
            } else {
                const float* p = (const float*)A + base;
                #pragma unroll
                for (int j = 0; j < 16; j += 4) {
                    float4 v = *(const float4*)(p + j);
                    f[j] = v.x; f[j+1] = v.y; f[j+2] = v.z; f[j+3] = v.w;
                }
            }
            if (a2_mode) {
                const long r2 = (a2_mode == 2) ? ((long)(m0 + sr) >> 3) : (long)(m0 + sr);
                const float* p = A2 + r2 * DMODEL + k0 + kh * 16;
                #pragma unroll
                for (int j = 0; j < 16; j += 4) {
                    float4 v = *(const float4*)(p + j);
                    f[j] += v.x; f[j+1] += v.y; f[j+2] += v.z; f[j+3] += v.w;
                }
            }
            short8 s0, s1;
            #pragma unroll
            for (int j = 0; j < 8; j++) { s0[j] = f2bs(f[j]); s1[j] = f2bs(f[8 + j]); }
            *(short8*)&Asl[wslot0] = s0;
            *(short8*)&Asl[wslot1] = s1;
        }
        // ---- stage B ----
        if (b_bf16) {
            const short* Bg = (const short*)Bt
                + (long)(n0 + wave * 32 + (lane & 15)) * K + k0 + (lane >> 4) * 8;
            gl_lds16(Bg,          &Bsl[(wave * 2 + 0) * 512]);
            gl_lds16(Bg + 16 * K, &Bsl[(wave * 2 + 1) * 512]);
        } else {
            const float* p = (const float*)Bt + (long)(n0 + sr) * K + k0 + kh * 16;
            float f[16];
            #pragma unroll
            for (int j = 0; j < 16; j += 4) {
                float4 v = *(const float4*)(p + j);
                f[j] = v.x; f[j+1] = v.y; f[j+2] = v.z; f[j+3] = v.w;
            }
            short8 s0, s1;
            #pragma unroll
            for (int j = 0; j < 8; j++) { s0[j] = f2bs(f[j]); s1[j] = f2bs(f[8 + j]); }
            *(short8*)&Bsl[wslot0] = s0;
            *(short8*)&Bsl[wslot1] = s1;
        }
        __syncthreads();

        short8 af[4], bfr[4];
        #pragma unroll
        for (int i = 0; i < 4; i++)
            af[i] = *(short8*)&Asl[(wmf + i) * 512 + lane * 8];
        #pragma unroll
        for (int j = 0; j < 4; j++)
            bfr[j] = *(short8*)&Bsl[(wnf + j) * 512 + lane * 8];
        #pragma unroll
        for (int i = 0; i < 4; i++)
            #pragma unroll
            for (int j = 0; j < 4; j++)
                acc[i][j] = __builtin_amdgcn_mfma_f32_16x16x32_bf16(
                    af[i], bfr[j], acc[i][j], 0, 0, 0);
        __syncthreads();
    }

    const int cl = lane & 15;
    const int rl = (lane >> 4) * 4;
    #pragma unroll
    for (int j = 0; j < 4; j++) {
        const int col = n0 + wnf * 16 + j * 16 + cl;
        const float bv = bias ? bias[col] : 0.f;
        #pragma unroll
        for (int i = 0; i < 4; i++) {
            const int rowb = m0 + wmf * 16 + i * 16 + rl;
            #pragma unroll
            for (int r = 0; r < 4; r++) {
                float v = acc[i][j][r] * alpha + bv;
                if (relu) v = fmaxf(v, 0.f);
                const long ci = (long)(rowb + r) * c_rs + col;
                if (c_bf16) ((bf16*)C)[ci] = f2b(v);
                else        ((float*)C)[ci] = v;
            }
        }
    }
}

// ---------------- MFMA GEMM 64x64, K-step 64 (high-occupancy variant) ----------------
// grid (N/64, M/64), block 256. K%64==0. Frag f = (r>>4)*2 + (k>>5);
// wave w owns rows [w*16,w*16+16) x all 64 cols: 8 MFMA/K-step.
__global__ __launch_bounds__(256) void gemm_mfma64_kernel(
    const void* __restrict__ A, int a_bf16,
    const float* __restrict__ A2, int a2_mode,
    const void* __restrict__ Bt, int b_bf16,
    const float* __restrict__ bias,
    void* __restrict__ C, int c_bf16,
    int K, long a_rs, long c_rs,
    float alpha, int relu)
{
    const int m0 = blockIdx.y * 64;
    const int n0 = blockIdx.x * 64;
    const int t = threadIdx.x;
    const int lane = t & 63;
    const int wave = t >> 6;

    __shared__ __align__(16) short Asl[4096];
    __shared__ __align__(16) short Bsl[4096];

    // fallback staging: thread -> row sr, 16-elem k chunk kq
    const int sr = t >> 2, kq = t & 3;
    const int fb_s0 = ((sr >> 4) * 2 + (kq >> 1)) * 512 + (sr & 15) * 8 + (kq & 1) * 256;

    floatx4 acc[4];
    #pragma unroll
    for (int j = 0; j < 4; j++) acc[j] = (floatx4){0.f, 0.f, 0.f, 0.f};

    for (int k0 = 0; k0 < K; k0 += 64) {
        // ---- stage A ----
        if (a_bf16 && a2_mode == 0) {
            const short* Ag = (const short*)A
                + (long)(m0 + wave * 16 + (lane & 15)) * a_rs + k0 + (lane >> 4) * 8;
            gl_lds16(Ag,      &Asl[(wave * 2 + 0) * 512]);   // k-half 0
            gl_lds16(Ag + 32, &Asl[(wave * 2 + 1) * 512]);   // k-half 1
        } else {
            float f[16];
            const long base = (long)(m0 + sr) * a_rs + k0 + kq * 16;
            if (a_bf16) {
                const unsigned short* p = (const unsigned short*)A + base;
                #pragma unroll
                for (int j = 0; j < 16; j += 4) {
                    ushort4 u = *(const ushort4*)(p + j);
                    f[j] = us2f(u.x); f[j+1] = us2f(u.y);
                    f[j+2] = us2f(u.z); f[j+3] = us2f(u.w);
                }
            } else {
                const float* p = (const float*)A + base;
                #pragma unroll
                for (int j = 0; j < 16; j += 4) {
                    float4 v = *(const float4*)(p + j);
                    f[j] = v.x; f[j+1] = v.y; f[j+2] = v.z; f[j+3] = v.w;
                }
            }
            if (a2_mode) {
                const long r2 = (a2_mode == 2) ? ((long)(m0 + sr) >> 3) : (long)(m0 + sr);
                const float* p = A2 + r2 * DMODEL + k0 + kq * 16;
                #pragma unroll
                for (int j = 0; j < 16; j += 4) {
                    float4 v = *(const float4*)(p + j);
                    f[j] += v.x; f[j+1] += v.y; f[j+2] += v.z; f[j+3] += v.w;
                }
            }
            short8 s0, s1;
            #pragma unroll
            for (int j = 0; j < 8; j++) { s0[j] = f2bs(f[j]); s1[j] = f2bs(f[8 + j]); }
            *(short8*)&Asl[fb_s0] = s0;
            *(short8*)&Asl[fb_s0 + 128] = s1;
        }
        // ---- stage B ----
        if (b_bf16) {
            const short* Bg = (const short*)Bt
                + (long)(n0 + wave * 16 + (lane & 15)) * K + k0 + (lane >> 4) * 8;
            gl_lds16(Bg,      &Bsl[(wave * 2 + 0) * 512]);
            gl_lds16(Bg + 32, &Bsl[(wave * 2 + 1) * 512]);
        } else {
            const float* p = (const float*)Bt + (long)(n0 + sr) * K + k0 + kq * 16;
            float f[16];
            #pragma unroll
            for (int j = 0; j < 16; j += 4) {
                float4 v = *(const float4*)(p + j);
                f[j] = v.x; f[j+1] = v.y; f[j+2] = v.z; f[j+3] = v.w;
            }
            short8 s0, s1;
            #pragma unroll
            for (int j = 0; j < 8; j++) { s0[j] = f2bs(f[j]); s1[j] = f2bs(f[8 + j]); }
            *(short8*)&Bsl[fb_s0] = s0;
            *(short8*)&Bsl[fb_s0 + 128] = s1;
        }
        __syncthreads();

        short8 a0 = *(short8*)&Asl[(wave * 2 + 0) * 512 + lane * 8];
        short8 a1 = *(short8*)&Asl[(wave * 2 + 1) * 512 + lane * 8];
        #pragma unroll
        for (int j = 0; j < 4; j++) {
            short8 b0 = *(short8*)&Bsl[(j * 2 + 0) * 512 + lane * 8];
            short8 b1 = *(short8*)&Bsl[(j * 2 + 1) * 512 + lane * 8];
            acc[j] = __builtin_amdgcn_mfma_f32_16x16x32_bf16(a0, b0, acc[j], 0, 0, 0);
            acc[j] = __builtin_amdgcn_mfma_f32_16x16x32_bf16(a1, b1, acc[j], 0, 0, 0);
        }
        __syncthreads();
    }

    const int cl = lane & 15;
    const int rl = (lane >> 4) * 4;
    #pragma unroll
    for (int j = 0; j < 4; j++) {
        const int col = n0 + j * 16 + cl;
        const float bv = bias ? bias[col] : 0.f;
        #pragma unroll
        for (int r = 0; r < 4; r++) {
            const int row = m0 + wave * 16 + rl + r;
            float v = acc[j][r] * alpha + bv;
            if (relu) v = fmaxf(v, 0.f);
            const long ci = (long)row * c_rs + col;
            if (c_bf16) ((bf16*)C)[ci] = f2b(v);
            else        ((float*)C)[ci] = v;
        }
    }
}

// ---------------- batched bf16 MFMA GEMM (cross-attn scores) ----------------
__global__ __launch_bounds__(256) void bgemm_mfma_kernel(
    const bf16* __restrict__ A, long a_rs, long a_bo,
    const bf16* __restrict__ B, long b_rs, long b_bo,
    bf16* __restrict__ C, long c_rs, long c_bo,
    int K, float alpha)
{
    const int bh = blockIdx.z;
    const int m0 = blockIdx.y * 128;
    const int n0 = blockIdx.x * 128;
    const int t = threadIdx.x;
    const int lane = t & 63;
    const int wave = t >> 6;
    const int wmf = (wave >> 1) * 4;
    const int wnf = (wave & 1) * 4;

    __shared__ __align__(16) short Asl[4096];
    __shared__ __align__(16) short Bsl[4096];

    floatx4 acc[4][4];
    #pragma unroll
    for (int i = 0; i < 4; i++)
        #pragma unroll
        for (int j = 0; j < 4; j++)
            acc[i][j] = (floatx4){0.f, 0.f, 0.f, 0.f};

    const short* Ab = (const short*)A + (long)bh * a_bo;
    const short* Bb = (const short*)B + (long)bh * b_bo;

    for (int k0 = 0; k0 < K; k0 += 32) {
        const short* Ag = Ab + (long)(m0 + wave * 32 + (lane & 15)) * a_rs + k0 + (lane >> 4) * 8;
        gl_lds16(Ag,             &Asl[(wave * 2 + 0) * 512]);
        gl_lds16(Ag + 16 * a_rs, &Asl[(wave * 2 + 1) * 512]);
        const short* Bg = Bb + (long)(n0 + wave * 32 + (lane & 15)) * b_rs + k0 + (lane >> 4) * 8;
        gl_lds16(Bg,             &Bsl[(wave * 2 + 0) * 512]);
        gl_lds16(Bg + 16 * b_rs, &Bsl[(wave * 2 + 1) * 512]);
        __syncthreads();

        short8 af[4], bfr[4];
        #pragma unroll
        for (int i = 0; i < 4; i++)
            af[i] = *(short8*)&Asl[(wmf + i) * 512 + lane * 8];
        #pragma unroll
        for (int j = 0; j < 4; j++)
            bfr[j] = *(short8*)&Bsl[(wnf + j) * 512 + lane * 8];
        #pragma unroll
        for (int i = 0; i < 4; i++)
            #pragma unroll
            for (int j = 0; j < 4; j++)
                acc[i][j] = __builtin_amdgcn_mfma_f32_16x16x32_bf16(
                    af[i], bfr[j], acc[i][j], 0, 0, 0);
        __syncthreads();
    }

    const int cl = lane & 15;
    const int rl = (lane >> 4) * 4;
    bf16* Cb = C + (long)bh * c_bo;
    #pragma unroll
    for (int j = 0; j < 4; j++) {
        const int col = n0 + wnf * 16 + j * 16 + cl;
        #pragma unroll
        for (int i = 0; i < 4; i++) {
            const int rowb = m0 + wmf * 16 + i * 16 + rl;
            #pragma unroll
            for (int r = 0; r < 4; r++)
                Cb[(long)(rowb + r) * c_rs + col] = f2b(acc[i][j][r] * alpha);
        }
    }
}

// ---------------- PV MFMA (cross-attn): C = P @ V ----------------
__global__ __launch_bounds__(256) void pv_mfma_kernel(
    const bf16* __restrict__ P, const bf16* __restrict__ V,
    bf16* __restrict__ Cout)
{
    const int q0 = blockIdx.x * 64;
    const int bh = blockIdx.y;
    const int t = threadIdx.x;
    const int lane = t & 63;
    const int wave = t >> 6;

    __shared__ __align__(16) short As[4096];
    __shared__ __align__(16) short Vs[4096];

    const int sr = t >> 2;
    const int kh = t & 3;
    const int vbase = (kh * 2 + (sr >> 5)) * 512 + ((sr & 31) >> 3) * 128 + (sr & 7);

    floatx4 acc[4];
    #pragma unroll
    for (int nf = 0; nf < 4; nf++) acc[nf] = (floatx4){0.f, 0.f, 0.f, 0.f};

    const short* Pb = (const short*)P + (long)bh * 262144;

    for (int kt = 0; kt < 1024; kt += 64) {
        // stage P via async direct-to-LDS (frags 2w = k-half 0, 2w+1 = k-half 1)
        {
            const short* Pg = Pb + (long)(q0 + wave * 16 + (lane & 15)) * 1024
                            + kt + (lane >> 4) * 8;
            gl_lds16(Pg,      &As[(wave * 2 + 0) * 512]);
            gl_lds16(Pg + 32, &As[(wave * 2 + 1) * 512]);
        }
        // stage V^T (B-layout, transpose): V row kt+sr, d = kh*16 .. +16
        {
            const short* vp = (const short*)V + (long)(kt + sr) * 4096 + bh * 64 + kh * 16;
            short8 v0 = *(const short8*)vp;
            short8 v1 = *(const short8*)(vp + 8);
            #pragma unroll
            for (int j = 0; j < 8; j++) {
                Vs[vbase + j * 8]       = v0[j];
                Vs[vbase + (8 + j) * 8] = v1[j];
            }
        }
        __syncthreads();

        short8 af0 = *(short8*)&As[(wave * 2 + 0) * 512 + lane * 8];
        short8 af1 = *(short8*)&As[(wave * 2 + 1) * 512 + lane * 8];
        #pragma unroll
        for (int nf = 0; nf < 4; nf++) {
            short8 vf0 = *(short8*)&Vs[(nf * 2 + 0) * 512 + lane * 8];
            short8 vf1 = *(short8*)&Vs[(nf * 2 + 1) * 512 + lane * 8];
            acc[nf] = __builtin_amdgcn_mfma_f32_16x16x32_bf16(af0, vf0, acc[nf], 0, 0, 0);
            acc[nf] = __builtin_amdgcn_mfma_f32_16x16x32_bf16(af1, vf1, acc[nf], 0, 0, 0);
        }
        __syncthreads();
    }

    const int g = lane >> 4, c = lane & 15;
    #pragma unroll
    for (int r = 0; r < 4; r++) {
        const long off = (long)(q0 + wave * 16 + g * 4 + r) * 4096 + bh * 64 + c;
        #pragma unroll
        for (int nf = 0; nf < 4; nf++)
            Cout[off + nf * 16] = f2b(acc[nf][r]);
    }
}

// ---------------- MFMA flash self-attention (unchanged) ----------------
__global__ __launch_bounds__(256) void fattn_mfma_kernel(
    const bf16* __restrict__ qkv, bf16* __restrict__ out, int nk)
{
    const int q0 = blockIdx.x * 64;
    const int bh = blockIdx.y;
    const int b = bh >> 3, h = bh & 7;
    const int t = threadIdx.x;
    const int lane = t & 63;
    const int wave = t >> 6;

    __shared__ __align__(16) short Ks[4096];
    __shared__ __align__(16) short Vs[4096];
    __shared__ __align__(16) short Ps[4][1024];

    const int sr = t >> 2;
    const int kh = t & 3;
    const int slot0 = ((sr >> 4) * 2 + (kh >> 1)) * 512
                    + ((sr & 15) + ((kh & 1) * 2) * 16) * 8;
    const int slot1 = slot0 + 128;
    const int vbase = (kh * 2 + (sr >> 5)) * 512 + ((sr & 31) >> 3) * 128 + (sr & 7);

    {
        const short* p = (const short*)qkv
            + ((long)(q0 + sr) * BT + b) * 1536 + h * 64 + kh * 16;
        *(short8*)&Ks[slot0] = *(const short8*)p;
        *(short8*)&Ks[slot1] = *(const short8*)(p + 8);
    }
    __syncthreads();
    short8 qf0 = *(short8*)&Ks[(wave * 2 + 0) * 512 + lane * 8];
    short8 qf1 = *(short8*)&Ks[(wave * 2 + 1) * 512 + lane * 8];
    __syncthreads();

    const int g = lane >> 4, c = lane & 15;

    float mrow[4], lrow[4];
    #pragma unroll
    for (int r = 0; r < 4; r++) { mrow[r] = -1e30f; lrow[r] = 0.f; }
    floatx4 accO[4];
    #pragma unroll
    for (int of = 0; of < 4; of++) accO[of] = (floatx4){0.f, 0.f, 0.f, 0.f};

    for (int kt = 0; kt < nk; kt += 64) {
        const short* kp = (const short*)qkv
            + ((long)(kt + sr) * BT + b) * 1536 + 512 + h * 64 + kh * 16;
        *(short8*)&Ks[slot0] = *(const short8*)kp;
        *(short8*)&Ks[slot1] = *(const short8*)(kp + 8);
        short8 v0 = *(const short8*)(kp + 512);
        short8 v1 = *(const short8*)(kp + 520);
        #pragma unroll
        for (int j = 0; j < 8; j++) {
            Vs[vbase + j * 8]       = v0[j];
            Vs[vbase + (8 + j) * 8] = v1[j];
        }
        __syncthreads();

        floatx4 sacc[4];
        #pragma unroll
        for (int nf = 0; nf < 4; nf++) {
            sacc[nf] = (floatx4){0.f, 0.f, 0.f, 0.f};
            short8 bk0 = *(short8*)&Ks[(nf * 2 + 0) * 512 + lane * 8];
            short8 bk1 = *(short8*)&Ks[(nf * 2 + 1) * 512 + lane * 8];
            sacc[nf] = __builtin_amdgcn_mfma_f32_16x16x32_bf16(qf0, bk0, sacc[nf], 0, 0, 0);
            sacc[nf] = __builtin_amdgcn_mfma_f32_16x16x32_bf16(qf1, bk1, sacc[nf], 0, 0, 0);
        }

        #pragma unroll
        for (int r = 0; r < 4; r++) {
            float mx = fmaxf(fmaxf(sacc[0][r], sacc[1][r]),
                             fmaxf(sacc[2][r], sacc[3][r]));
            mx = fmaxf(mx, __shfl_xor(mx, 1));
            mx = fmaxf(mx, __shfl_xor(mx, 2));
            mx = fmaxf(mx, __shfl_xor(mx, 4));
            mx = fmaxf(mx, __shfl_xor(mx, 8));
            mx *= 0.125f;
            float mn = fmaxf(mrow[r], mx);
            float al = __expf(mrow[r] - mn);
            mrow[r] = mn;
            float ps = 0.f;
            #pragma unroll
            for (int nf = 0; nf < 4; nf++) {
                float p = __expf(fmaf(sacc[nf][r], 0.125f, -mn));
                ps += p;
                Ps[wave][(nf >> 1) * 512
                         + ((g * 4 + r) + ((nf & 1) * 2 + (c >> 3)) * 16) * 8
                         + (c & 7)] = f2bs(p);
            }
            ps += __shfl_xor(ps, 1);
            ps += __shfl_xor(ps, 2);
            ps += __shfl_xor(ps, 4);
            ps += __shfl_xor(ps, 8);
            lrow[r] = lrow[r] * al + ps;
            #pragma unroll
            for (int of = 0; of < 4; of++) accO[of][r] *= al;
        }

        short8 pf0 = *(short8*)&Ps[wave][lane * 8];
        short8 pf1 = *(short8*)&Ps[wave][512 + lane * 8];
        #pragma unroll
        for (int of = 0; of < 4; of++) {
            short8 vf0 = *(short8*)&Vs[(of * 2 + 0) * 512 + lane * 8];
            short8 vf1 = *(short8*)&Vs[(of * 2 + 1) * 512 + lane * 8];
            accO[of] = __builtin_amdgcn_mfma_f32_16x16x32_bf16(pf0, vf0, accO[of], 0, 0, 0);
            accO[of] = __builtin_amdgcn_mfma_f32_16x16x32_bf16(pf1, vf1, accO[of], 0, 0, 0);
        }
        __syncthreads();
    }

    #pragma unroll
    for (int r = 0; r < 4; r++) {
        const float inv = 1.f / lrow[r];
        const long off = ((long)(q0 + wave * 16 + g * 4 + r) * BT + b) * DMODEL
                       + h * 64 + c;
        #pragma unroll
        for (int of = 0; of < 4; of++)
            out[off + of * 16] = f2b(accO[of][r] * inv);
    }
}

// ---------------- layer norm: y = LN(x + res) * w + b (+ bf16 copies) ----------------
__global__ __launch_bounds__(256) void ln_kernel(
    const float* __restrict__ x, const bf16* __restrict__ res,
    const float* __restrict__ w, const float* __restrict__ b,
    float* __restrict__ y, bf16* __restrict__ yb, bf16* __restrict__ ypb,
    const float* __restrict__ pos, int pos_mode)
{
    const long row = blockIdx.x;
    const int t = threadIdx.x;
    const float* xr = x + row * DMODEL;
    float v0 = xr[t], v1 = xr[t + 256];
    if (res) {
        v0 += b2f(res[row * DMODEL + t]);
        v1 += b2f(res[row * DMODEL + t + 256]);
    }

    __shared__ float red[256];
    red[t] = v0 + v1; __syncthreads();
    for (int s = 128; s > 0; s >>= 1) { if (t < s) red[t] += red[t + s]; __syncthreads(); }
    float mean = red[0] * (1.f / DMODEL);
    __syncthreads();
    float d0 = v0 - mean, d1 = v1 - mean;
    red[t] = d0 * d0 + d1 * d1; __syncthreads();
    for (int s = 128; s > 0; s >>= 1) { if (t < s) red[t] += red[t + s]; __syncthreads(); }
    float inv = rsqrtf(red[0] * (1.f / DMODEL) + 1e-5f);

    float o0 = d0 * inv * w[t] + b[t];
    float o1 = d1 * inv * w[t + 256] + b[t + 256];
    y[row * DMODEL + t]       = o0;
    y[row * DMODEL + t + 256] = o1;
    if (yb) {
        yb[row * DMODEL + t]       = f2b(o0);
        yb[row * DMODEL + t + 256] = f2b(o1);
    }
    if (ypb) {
        const float* pr = pos + ((pos_mode == 2) ? (row >> 3) : row) * DMODEL;
        ypb[row * DMODEL + t]       = f2b(o0 + pr[t]);
        ypb[row * DMODEL + t + 256] = f2b(o1 + pr[t + 256]);
    }
}

// ---------------- column softmax over q (assign-attn) ----------------
__global__ __launch_bounds__(256) void col_softmax_kernel(bf16* __restrict__ s) {
    const int bh = blockIdx.y;
    const int n = blockIdx.x * 256 + threadIdx.x;
    bf16* base = s + (long)bh * (NQ * SEQ) + n;
    float mx = -1e30f;
    for (int q = 0; q < NQ; q++) mx = fmaxf(mx, b2f(base[(long)q * SEQ]));
    float sum = 0.f;
    for (int q = 0; q < NQ; q++) {
        float v = __expf(b2f(base[(long)q * SEQ]) - mx);
        base[(long)q * SEQ] = f2b(v);
        sum += v;
    }
    float inv = 1.f / sum;
    for (int q = 0; q < NQ; q++)
        base[(long)q * SEQ] = f2b(b2f(base[(long)q * SEQ]) * inv);
}

// mean over heads: o[b,q,n] = (1/8) sum_h s[b,h,q,n], fp32 out.
__global__ __launch_bounds__(256) void mean_h_kernel(
    const bf16* __restrict__ s, float* __restrict__ o)
{
    long i = (long)blockIdx.x * 256 + threadIdx.x;
    int n = (int)(i & (SEQ - 1));
    long r = i >> 10;
    int q = (int)(r & (NQ - 1));
    int b = (int)(r >> 8);
    float acc = 0.f;
    #pragma unroll
    for (int h = 0; h < 8; h++)
        acc += b2f(s[(((long)b * 8 + h) * NQ + q) * SEQ + n]);
    o[i] = acc * 0.125f;
}

// ---------------- host launch ----------------
extern "C" void kernel_launch(void* const* d_in, const int* in_sizes, int n_in,
                              void* d_out, int out_size, void* d_ws, size_t ws_size,
                              hipStream_t stream) {
    const float* src         = (const float*)d_in[0];
    const float* query_embed = (const float*)d_in[2];
    const float* pos_embed   = (const float*)d_in[3];
    const float* enc_in_w    = (const float*)d_in[4];
    const float* enc_in_b    = (const float*)d_in[5];
    const float* enc_out_w   = (const float*)d_in[6];
    const float* enc_out_b   = (const float*)d_in[7];
    const float* enc_ffn_w1  = (const float*)d_in[8];
    const float* enc_ffn_b1  = (const float*)d_in[9];
    const float* enc_ffn_w2  = (const float*)d_in[10];
    const float* enc_ffn_b2  = (const float*)d_in[11];
    const float* enc_ln_w    = (const float*)d_in[12];
    const float* enc_ln_b    = (const float*)d_in[13];
    const float* dec_in_w    = (const float*)d_in[14];
    const float* dec_in_b    = (const float*)d_in[15];
    const float* dec_out_w   = (const float*)d_in[16];
    const float* dec_out_b   = (const float*)d_in[17];
    const float* dec_ca_w    = (const float*)d_in[18];
    const float* dec_ca_b    = (const float*)d_in[19];
    const float* dec_ffn_w1  = (const float*)d_in[20];
    const float* dec_ffn_b1  = (const float*)d_in[21];
    const float* dec_ffn_w2  = (const float*)d_in[22];
    const float* dec_ffn_b2  = (const float*)d_in[23];
    const float* dec_ln_w    = (const float*)d_in[24];
    const float* dec_ln_b    = (const float*)d_in[25];
    const float* final_ln_w  = (const float*)d_in[26];
    const float* final_ln_b  = (const float*)d_in[27];

    float* wsf = (float*)d_ws;
    float* x   = wsf;                     // 4,194,304 f
    float* tgt = wsf + 4194304;           // 1,048,576 f
    bf16* QKVb = (bf16*)(wsf + 5242880);  // 12,582,912 bf16
    bf16* Fb   = QKVb + 12582912;         // 16,777,216
    bf16* E1b  = Fb + 16777216;           //  4,194,304
    bf16* E2b  = E1b + 4194304;           //  4,194,304
    bf16* kca  = QKVb + 3145728;          // decoder carve (after 2048*1536)
    bf16* vca  = kca + 4194304;

    // extended regions (guarded)
    const bool useA = ws_size >= 117440512ull;   // + xb/xpb/tb/tqb (21 MB)
    const bool useB = ws_size >= 205520896ull;   // + bf16 weights (88 MB)
    bf16* xb   = (bf16*)((char*)d_ws + 96468992);
    bf16* xpb  = (bf16*)((char*)d_ws + 104857600);
    bf16* tb   = (bf16*)((char*)d_ws + 113246208);
    bf16* tqb  = (bf16*)((char*)d_ws + 115343360);
    bf16* Wb   = (bf16*)((char*)d_ws + 117440512);
    bf16* ei16  = Wb;
    bf16* eo16  = Wb + 4718592;
    bf16* ef116 = Wb + 6291456;
    bf16* ef216 = Wb + 12582912;
    bf16* di16  = Wb + 18874368;
    bf16* do16  = Wb + 23592960;
    bf16* dca16 = Wb + 25165824;
    bf16* df116 = Wb + 31457280;
    bf16* df216 = Wb + 37748736;

    float* out0 = (float*)d_out;          // (1,Q,B,D) 1,048,576
    float* outP = out0 + 1048576;         // (B,Q,S)   2,097,152
    float* outS = outP + 2097152;         // (B,Q,S)   2,097,152

    auto mgemm = [&](const void* A, int a_bf16, const float* A2, int a2_mode,
                     const void* Bt, int b_bf16, const float* bias, void* C, int c_bf16,
                     int M, int N, int K, long a_rs, long c_rs, int relu) {
        dim3 g(N / 128, M / 128, 1);
        gemm_mfma_kernel<<<g, 256, 0, stream>>>(A, a_bf16, A2, a2_mode, Bt, b_bf16, bias,
                                                C, c_bf16, K, a_rs, c_rs, 1.f, relu);
    };
    auto mgemm64 = [&](const void* A, int a_bf16, const float* A2, int a2_mode,
                       const void* Bt, int b_bf16, const float* bias, void* C, int c_bf16,
                       int M, int N, int K, long a_rs, long c_rs, int relu) {
        dim3 g(N / 64, M / 64, 1);
        gemm_mfma64_kernel<<<g, 256, 0, stream>>>(A, a_bf16, A2, a2_mode, Bt, b_bf16, bias,
                                                  C, c_bf16, K, a_rs, c_rs, 1.f, relu);
    };

    // one-time weight conversion (per forward; ~30us)
    if (useB) {
        cvt_kernel<<<2304, 256, 0, stream>>>(enc_in_w,   ei16,  4718592);
        cvt_kernel<<<768,  256, 0, stream>>>(enc_out_w,  eo16,  1572864);
        cvt_kernel<<<3072, 256, 0, stream>>>(enc_ffn_w1, ef116, 6291456);
        cvt_kernel<<<3072, 256, 0, stream>>>(enc_ffn_w2, ef216, 6291456);
        cvt_kernel<<<2304, 256, 0, stream>>>(dec_in_w,   di16,  4718592);
        cvt_kernel<<<768,  256, 0, stream>>>(dec_out_w,  do16,  1572864);
        cvt_kernel<<<3072, 256, 0, stream>>>(dec_ca_w,   dca16, 6291456);
        cvt_kernel<<<3072, 256, 0, stream>>>(dec_ffn_w1, df116, 6291456);
        cvt_kernel<<<3072, 256, 0, stream>>>(dec_ffn_w2, df216, 6291456);
    }

    if (useA) prep_x_kernel<<<16384, 256, 0, stream>>>(src, pos_embed, x, xb, xpb);
    else      copy_kernel<<<16384, 256, 0, stream>>>(src, x, 4194304);
    if (useA) prep_tgt_kernel<<<4096, 256, 0, stream>>>(query_embed, tgt, tb, tqb);
    else      hipMemsetAsync(tgt, 0, 1048576 * sizeof(float), stream);

    // ---------------- encoder ----------------
    for (int i = 0; i < 6; i++) {
        const float* iw = enc_in_w + (long)i * 786432;
        const float* ib = enc_in_b + (long)i * 1536;
        const void* Bqk = useB ? (const void*)(ei16 + (long)i * 786432) : (const void*)iw;
        const void* Bv  = useB ? (const void*)(ei16 + (long)i * 786432 + 524288)
                               : (const void*)(iw + 524288);
        const void* Bo  = useB ? (const void*)(eo16 + (long)i * 262144)
                               : (const void*)(enc_out_w + (long)i * 262144);
        const void* Bf1 = useB ? (const void*)(ef116 + (long)i * 1048576)
                               : (const void*)(enc_ffn_w1 + (long)i * 1048576);
        const void* Bf2 = useB ? (const void*)(ef216 + (long)i * 1048576)
                               : (const void*)(enc_ffn_w2 + (long)i * 1048576);

        if (useA) mgemm(xpb, 1, nullptr, 0, Bqk, useB, ib, QKVb, 1,
                        8192, 1024, 512, 512, 1536, 0);
        else      mgemm(x, 0, pos_embed, 1, Bqk, useB, ib, QKVb, 1,
                        8192, 1024, 512, 512, 1536, 0);
        mgemm64(useA ? (const void*)xb : (const void*)x, useA, nullptr, 0,
                Bv, useB, ib + 1024, QKVb + 1024, 1, 8192, 512, 512, 512, 1536, 0);
        fattn_mfma_kernel<<<dim3(16, 64), 256, 0, stream>>>(QKVb, E1b, 1024);
        mgemm64(E1b, 1, nullptr, 0, Bo, useB, enc_out_b + (long)i * 512,
                E2b, 1, 8192, 512, 512, 512, 512, 0);
        ln_kernel<<<8192, 256, 0, stream>>>(x, E2b, enc_ln_w + (long)i * 1024,
                                            enc_ln_b + (long)i * 1024, x,
                                            useA ? xb : nullptr, useA ? xpb : nullptr,
                                            pos_embed, 1);
        mgemm(useA ? (const void*)xb : (const void*)x, useA, nullptr, 0,
              Bf1, useB, enc_ffn_b1 + (long)i * 2048, Fb, 1,
              8192, 2048, 512, 512, 2048, 1);
        mgemm64(Fb, 1, nullptr, 0, Bf2, useB, enc_ffn_b2 + (long)i * 512,
                E1b, 1, 8192, 512, 2048, 2048, 512, 0);
        ln_kernel<<<8192, 256, 0, stream>>>(x, E1b, enc_ln_w + (long)i * 1024 + 512,
                                            enc_ln_b + (long)i * 1024 + 512, x,
                                            useA ? xb : nullptr, useA ? xpb : nullptr,
                                            pos_embed, 1);
    }
    // x = memory; xb = bf16(memory); xpb = bf16(memory + pos)

    // ---------------- decoder ----------------
    for (int i = 0; i < 6; i++) {
        const float* iw = dec_in_w + (long)i * 786432;
        const float* ib = dec_in_b + (long)i * 1536;
        const float* cw = dec_ca_w + (long)i * 1048576;
        const float* cb = dec_ca_b + (long)i * 2048;
        const void* Bqk = useB ? (const void*)(di16 + (long)i * 786432) : (const void*)iw;
        const void* Bv  = useB ? (const void*)(di16 + (long)i * 786432 + 524288)
                               : (const void*)(iw + 524288);
        const void* Bo  = useB ? (const void*)(do16 + (long)i * 262144)
                               : (const void*)(dec_out_w + (long)i * 262144);
        const void* Bcq = useB ? (const void*)(dca16 + (long)i * 1048576) : (const void*)cw;
        const void* Bck = useB ? (const void*)(dca16 + (long)i * 1048576 + 262144)
                               : (const void*)(cw + 262144);
        const void* Bcv = useB ? (const void*)(dca16 + (long)i * 1048576 + 524288)
                               : (const void*)(cw + 524288);
        const void* Bco = useB ? (const void*)(dca16 + (long)i * 1048576 + 786432)
                               : (const void*)(cw + 786432);
        const void* Bf1 = useB ? (const void*)(df116 + (long)i * 1048576)
                               : (const void*)(dec_ffn_w1 + (long)i * 1048576);
        const void* Bf2 = useB ? (const void*)(df216 + (long)i * 1048576)
                               : (const void*)(dec_ffn_w2 + (long)i * 1048576);

        if (useA) mgemm64(tqb, 1, nullptr, 0, Bqk, useB, ib, QKVb, 1,
                          2048, 1024, 512, 512, 1536, 0);
        else      mgemm64(tgt, 0, query_embed, 2, Bqk, useB, ib, QKVb, 1,
                          2048, 1024, 512, 512, 1536, 0);
        mgemm64(useA ? (const void*)tb : (const void*)tgt, useA, nullptr, 0,
                Bv, useB, ib + 1024, QKVb + 1024, 1, 2048, 512, 512, 512, 1536, 0);
        fattn_mfma_kernel<<<dim3(4, 64), 256, 0, stream>>>(QKVb, E1b, 256);
        mgemm64(E1b, 1, nullptr, 0, Bo, useB, dec_out_b + (long)i * 512,
                E2b, 1, 2048, 512, 512, 512, 512, 0);  // E2b = sa (keep)
        ln_kernel<<<2048, 256, 0, stream>>>(tgt, E2b, dec_ln_w + (long)i * 1536,
                                            dec_ln_b + (long)i * 1536, tgt,
                                            useA ? tb : nullptr, useA ? tqb : nullptr,
                                            query_embed, 2);

        // assign (cross) attention: q = sa + qpos, k = memory + pos, v = memory
        mgemm64(E2b, 1, query_embed, 2, Bcq, useB, cb, E1b, 1,
                2048, 512, 512, 512, 512, 0);                                        // qca
        if (useA) mgemm64(xpb, 1, nullptr, 0, Bck, useB, cb + 512, kca, 1,
                          8192, 512, 512, 512, 512, 0);                              // kca
        else      mgemm64(x, 0, pos_embed, 1, Bck, useB, cb + 512, kca, 1,
                          8192, 512, 512, 512, 512, 0);
        mgemm64(useA ? (const void*)xb : (const void*)x, useA, nullptr, 0,
                Bcv, useB, cb + 1024, vca, 1, 8192, 512, 512, 512, 512, 0);          // vca
        bgemm_mfma_kernel<<<dim3(8, 2, 64), 256, 0, stream>>>(
            E1b, 4096, 64, kca, 4096, 64, Fb, 1024, 262144, 64, 0.125f);
        if (i == 5) mean_h_kernel<<<8192, 256, 0, stream>>>(Fb, outS);
        col_softmax_kernel<<<dim3(4, 64), 256, 0, stream>>>(Fb);
        if (i == 5) mean_h_kernel<<<8192, 256, 0, stream>>>(Fb, outP);
        pv_mfma_kernel<<<dim3(4, 64), 256, 0, stream>>>(Fb, vca, E2b);
        mgemm64(E2b, 1, nullptr, 0, Bco, useB, cb + 1536, E1b, 1,
                2048, 512, 512, 512, 512, 0);
        ln_kernel<<<2048, 256, 0, stream>>>(tgt, E1b, dec_ln_w + (long)i * 1536 + 512,
                                            dec_ln_b + (long)i * 1536 + 512, tgt,
                                            useA ? tb : nullptr, useA ? tqb : nullptr,
                                            query_embed, 2);

        // FFN
        mgemm64(useA ? (const void*)tb : (const void*)tgt, useA, nullptr, 0,
                Bf1, useB, dec_ffn_b1 + (long)i * 2048, Fb, 1,
                2048, 2048, 512, 512, 2048, 1);
        mgemm64(Fb, 1, nullptr, 0, Bf2, useB, dec_ffn_b2 + (long)i * 512,
                E1b, 1, 2048, 512, 2048, 2048, 512, 0);
        ln_kernel<<<2048, 256, 0, stream>>>(tgt, E1b, dec_ln_w + (long)i * 1536 + 1024,
                                            dec_ln_b + (long)i * 1536 + 1024, tgt,
                                            useA ? tb : nullptr, useA ? tqb : nullptr,
                                            query_embed, 2);
    }

    // final LN -> fp32 output 0
    ln_kernel<<<2048, 256, 0, stream>>>(tgt, nullptr, final_ln_w, final_ln_b, out0,
                                        nullptr, nullptr, nullptr, 0);
}

// Round 8
// 3501.301 us; speedup vs baseline: 1.9379x; 1.0465x over previous
//
#include <hip/hip_runtime.h>
#include <hip/hip_bf16.h>

// DETR-style transformer forward, round 13.
// Round-12: 3664us. Top-5 all enc fattn (83us): SQ_LDS_BANK_CONFLICT 1.17e7
// = 23% of time. V-transpose scalar stores were 16-way conflicts (bank =
// (d&7)*4+((k&7)>>1), d&7 uniform per store), P-stores 8-way. Fixes:
//  - Vs region stride 512->536 shorts (3F mod 8 bijective -> 4-way) [fattn+pv]
//  - Ps XOR granule swizzle idx^=((R>>3)&7)<<3 -> 2-way; read via bijective
//    lane^((lane>>3)&7) permuted-linear (phase-equivalent to linear)
//  - defer-max: skip rescale when __all(mx<=mrow) (wave-uniform, bit-exact)
//  - col_softmax: 3-pass -> 2-pass online (160->96 MB L2/L3 traffic)
//
// Shapes: D=512 H=8 dh=64 DFF=2048 S=1024 B=8 Q=256 LE=LD=6

#define DMODEL 512
#define SEQ    1024
#define BT     8
#define NQ     256

using bf16 = __hip_bfloat16;
typedef short short8 __attribute__((ext_vector_type(8)));
typedef float floatx4 __attribute__((ext_vector_type(4)));

__device__ __forceinline__ float us2f(unsigned short u) {
    return __uint_as_float(((unsigned int)u) << 16);
}
__device__ __forceinline__ float b2f(bf16 x) { return __bfloat162float(x); }
__device__ __forceinline__ bf16  f2b(float x) { return __float2bfloat16(x); }
__device__ __forceinline__ short f2bs(float f) {  // RNE fp32->bf16 bits
    unsigned u = __float_as_uint(f);
    return (short)((u + 0x7fffu + ((u >> 16) & 1u)) >> 16);
}

// async global->LDS, 16B per lane; LDS dest = wave-uniform base + lane*16.
__device__ __forceinline__ void gl_lds16(const void* g, void* l) {
    __builtin_amdgcn_global_load_lds(
        (__attribute__((address_space(1))) void*)g,
        (__attribute__((address_space(3))) void*)l, 16, 0, 0);
}

__global__ void copy_kernel(const float* __restrict__ in, float* __restrict__ out, long n) {
    long i = (long)blockIdx.x * 256 + threadIdx.x;
    if (i < n) out[i] = in[i];
}

// fp32 -> bf16 bulk convert (8 elems/thread, n % 2048 == 0)
__global__ void cvt_kernel(const float* __restrict__ in, bf16* __restrict__ out, long n) {
    long i = ((long)blockIdx.x * 256 + threadIdx.x) * 8;
    if (i >= n) return;
    float4 a = *(const float4*)(in + i);
    float4 b = *(const float4*)(in + i + 4);
    short8 s;
    s[0] = f2bs(a.x); s[1] = f2bs(a.y); s[2] = f2bs(a.z); s[3] = f2bs(a.w);
    s[4] = f2bs(b.x); s[5] = f2bs(b.y); s[6] = f2bs(b.z); s[7] = f2bs(b.w);
    *(short8*)((short*)out + i) = s;
}

// x = src; xb = bf16(src); xpb = bf16(src + pos)
__global__ void prep_x_kernel(const float* __restrict__ src, const float* __restrict__ pos,
                              float* __restrict__ x, bf16* __restrict__ xb,
                              bf16* __restrict__ xpb) {
    long i = (long)blockIdx.x * 256 + threadIdx.x;
    float v = src[i];
    x[i] = v; xb[i] = f2b(v); xpb[i] = f2b(v + pos[i]);
}

// tgt = 0; tb = 0; tqb = bf16(qpos)   (row = q*8+b -> qe[row>>3])
__global__ void prep_tgt_kernel(const float* __restrict__ qe, float* __restrict__ tgt,
                                bf16* __restrict__ tb, bf16* __restrict__ tqb) {
    long i = (long)blockIdx.x * 256 + threadIdx.x;
    tgt[i] = 0.f; tb[i] = f2b(0.f);
    tqb[i] = f2b(qe[((i >> 12) << 9) + (i & 511)]);
}

// ---------------- MFMA GEMM 128x128: C = alpha*(A(+A2)) @ Bt^T + bias ----------------
__global__ __launch_bounds__(256) void gemm_mfma_kernel(
    const void* __restrict__ A, int a_bf16,
    const float* __restrict__ A2, int a2_mode,
    const void* __restrict__ Bt, int b_bf16,
    const float* __restrict__ bias,
    void* __restrict__ C, int c_bf16,
    int K, long a_rs, long c_rs,
    float alpha, int relu)
{
    const int m0 = blockIdx.y * 128;
    const int n0 = blockIdx.x * 128;
    const int t = threadIdx.x;
    const int lane = t & 63;
    const int wave = t >> 6;
    const int wmf = (wave >> 1) * 4;
    const int wnf = (wave & 1) * 4;

    __shared__ __align__(16) short Asl[4096];
    __shared__ __align__(16) short Bsl[4096];

    const int sr = t >> 1;
    const int kh = t & 1;
    const int wbase = (sr >> 4) * 512 + (sr & 15) * 8;
    const int wslot0 = wbase + (2 * kh) * 128;
    const int wslot1 = wbase + (2 * kh + 1) * 128;

    floatx4 acc[4][4];
    #pragma unroll
    for (int i = 0; i < 4; i++)
        #pragma unroll
        for (int j = 0; j < 4; j++)
            acc[i][j] = (floatx4){0.f, 0.f, 0.f, 0.f};

    for (int k0 = 0; k0 < K; k0 += 32) {
        if (a_bf16 && a2_mode == 0) {
            const short* Ag = (const short*)A
                + (long)(m0 + wave * 32 + (lane & 15)) * a_rs + k0 + (lane >> 4) * 8;
            gl_lds16(Ag,             &Asl[(wave * 2 + 0) * 512]);
            gl_lds16(Ag + 16 * a_rs, &Asl[(wave * 2 + 1) * 512]);
        } else {
            float f[16];
            const long base = (long)(m0 + sr) * a_rs + k0 + kh * 16;
            if (a_bf16) {
                const unsigned short* p = (const unsigned short*)A + base;
                #pragma unroll
                for (int j = 0; j < 16; j += 4) {
                    ushort4 u = *(const ushort4*)(p + j);
                    f[j] = us2f(u.x); f[j+1] = us2f(u.y);
                    f[j+2] = us2f(u.z); f[j+3] = us2f(u.w);
                }
            } else {
                const float* p = (const float*)A + base;
                #pragma unroll
                for (int j = 0; j < 16; j += 4) {
                    float4 v = *(const float4*)(p + j);
                    f[j] = v.x; f[j+1] = v.y; f[j+2] = v.z; f[j+3] = v.w;
                }
            }
            if (a2_mode) {
                const long r2 = (a2_mode == 2) ? ((long)(m0 + sr) >> 3) : (long)(m0 + sr);
                const float* p = A2 + r2 * DMODEL + k0 + kh * 16;
                #pragma unroll
                for (int j = 0; j < 16; j += 4) {
                    float4 v = *(const float4*)(p + j);
                    f[j] += v.x; f[j+1] += v.y; f[j+2] += v.z; f[j+3] += v.w;
                }
            }
            short8 s0, s1;
            #pragma unroll
            for (int j = 0; j < 8; j++) { s0[j] = f2bs(f[j]); s1[j] = f2bs(f[8 + j]); }
            *(short8*)&Asl[wslot0] = s0;
            *(short8*)&Asl[wslot1] = s1;
        }
        if (b_bf16) {
            const short* Bg = (const short*)Bt
                + (long)(n0 + wave * 32 + (lane & 15)) * K + k0 + (lane >> 4) * 8;
            gl_lds16(Bg,          &Bsl[(wave * 2 + 0) * 512]);
            gl_lds16(Bg + 16 * K, &Bsl[(wave * 2 + 1) * 512]);
        } else {
            const float* p = (const float*)Bt + (long)(n0 + sr) * K + k0 + kh * 16;
            float f[16];
            #pragma unroll
            for (int j = 0; j < 16; j += 4) {
                float4 v = *(const float4*)(p + j);
                f[j] = v.x; f[j+1] = v.y; f[j+2] = v.z; f[j+3] = v.w;
            }
            short8 s0, s1;
            #pragma unroll
            for (int j = 0; j < 8; j++) { s0[j] = f2bs(f[j]); s1[j] = f2bs(f[8 + j]); }
            *(short8*)&Bsl[wslot0] = s0;
            *(short8*)&Bsl[wslot1] = s1;
        }
        __syncthreads();

        short8 af[4], bfr[4];
        #pragma unroll
        for (int i = 0; i < 4; i++)
            af[i] = *(short8*)&Asl[(wmf + i) * 512 + lane * 8];
        #pragma unroll
        for (int j = 0; j < 4; j++)
            bfr[j] = *(short8*)&Bsl[(wnf + j) * 512 + lane * 8];
        #pragma unroll
        for (int i = 0; i < 4; i++)
            #pragma unroll
            for (int j = 0; j < 4; j++)
                acc[i][j] = __builtin_amdgcn_mfma_f32_16x16x32_bf16(
                    af[i], bfr[j], acc[i][j], 0, 0, 0);
        __syncthreads();
    }

    const int cl = lane & 15;
    const int rl = (lane >> 4) * 4;
    #pragma unroll
    for (int j = 0; j < 4; j++) {
        const int col = n0 + wnf * 16 + j * 16 + cl;
        const float bv = bias ? bias[col] : 0.f;
        #pragma unroll
        for (int i = 0; i < 4; i++) {
            const int rowb = m0 + wmf * 16 + i * 16 + rl;
            #pragma unroll
            for (int r = 0; r < 4; r++) {
                float v = acc[i][j][r] * alpha + bv;
                if (relu) v = fmaxf(v, 0.f);
                const long ci = (long)(rowb + r) * c_rs + col;
                if (c_bf16) ((bf16*)C)[ci] = f2b(v);
                else        ((float*)C)[ci] = v;
            }
        }
    }
}

// ---------------- MFMA GEMM 64x64, K-step 64 (high-occupancy variant) ----------------
__global__ __launch_bounds__(256) void gemm_mfma64_kernel(
    const void* __restrict__ A, int a_bf16,
    const float* __restrict__ A2, int a2_mode,
    const void* __restrict__ Bt, int b_bf16,
    const float* __restrict__ bias,
    void* __restrict__ C, int c_bf16,
    int K, long a_rs, long c_rs,
    float alpha, int relu)
{
    const int m0 = blockIdx.y * 64;
    const int n0 = blockIdx.x * 64;
    const int t = threadIdx.x;
    const int lane = t & 63;
    const int wave = t >> 6;

    __shared__ __align__(16) short Asl[4096];
    __shared__ __align__(16) short Bsl[4096];

    const int sr = t >> 2, kq = t & 3;
    const int fb_s0 = ((sr >> 4) * 2 + (kq >> 1)) * 512 + (sr & 15) * 8 + (kq & 1) * 256;

    floatx4 acc[4];
    #pragma unroll
    for (int j = 0; j < 4; j++) acc[j] = (floatx4){0.f, 0.f, 0.f, 0.f};

    for (int k0 = 0; k0 < K; k0 += 64) {
        if (a_bf16 && a2_mode == 0) {
            const short* Ag = (const short*)A
                + (long)(m0 + wave * 16 + (lane & 15)) * a_rs + k0 + (lane >> 4) * 8;
            gl_lds16(Ag,      &Asl[(wave * 2 + 0) * 512]);
            gl_lds16(Ag + 32, &Asl[(wave * 2 + 1) * 512]);
        } else {
            float f[16];
            const long base = (long)(m0 + sr) * a_rs + k0 + kq * 16;
            if (a_bf16) {
                const unsigned short* p = (const unsigned short*)A + base;
                #pragma unroll
                for (int j = 0; j < 16; j += 4) {
                    ushort4 u = *(const ushort4*)(p + j);
                    f[j] = us2f(u.x); f[j+1] = us2f(u.y);
                    f[j+2] = us2f(u.z); f[j+3] = us2f(u.w);
                }
            } else {
                const float* p = (const float*)A + base;
                #pragma unroll
                for (int j = 0; j < 16; j += 4) {
                    float4 v = *(const float4*)(p + j);
                    f[j] = v.x; f[j+1] = v.y; f[j+2] = v.z; f[j+3] = v.w;
                }
            }
            if (a2_mode) {
                const long r2 = (a2_mode == 2) ? ((long)(m0 + sr) >> 3) : (long)(m0 + sr);
                const float* p = A2 + r2 * DMODEL + k0 + kq * 16;
                #pragma unroll
                for (int j = 0; j < 16; j += 4) {
                    float4 v = *(const float4*)(p + j);
                    f[j] += v.x; f[j+1] += v.y; f[j+2] += v.z; f[j+3] += v.w;
                }
            }
            short8 s0, s1;
            #pragma unroll
            for (int j = 0; j < 8; j++) { s0[j] = f2bs(f[j]); s1[j] = f2bs(f[8 + j]); }
            *(short8*)&Asl[fb_s0] = s0;
            *(short8*)&Asl[fb_s0 + 128] = s1;
        }
        if (b_bf16) {
            const short* Bg = (const short*)Bt
                + (long)(n0 + wave * 16 + (lane & 15)) * K + k0 + (lane >> 4) * 8;
            gl_lds16(Bg,      &Bsl[(wave * 2 + 0) * 512]);
            gl_lds16(Bg + 32, &Bsl[(wave * 2 + 1) * 512]);
        } else {
            const float* p = (const float*)Bt + (long)(n0 + sr) * K + k0 + kq * 16;
            float f[16];
            #pragma unroll
            for (int j = 0; j < 16; j += 4) {
                float4 v = *(const float4*)(p + j);
                f[j] = v.x; f[j+1] = v.y; f[j+2] = v.z; f[j+3] = v.w;
            }
            short8 s0, s1;
            #pragma unroll
            for (int j = 0; j < 8; j++) { s0[j] = f2bs(f[j]); s1[j] = f2bs(f[8 + j]); }
            *(short8*)&Bsl[fb_s0] = s0;
            *(short8*)&Bsl[fb_s0 + 128] = s1;
        }
        __syncthreads();

        short8 a0 = *(short8*)&Asl[(wave * 2 + 0) * 512 + lane * 8];
        short8 a1 = *(short8*)&Asl[(wave * 2 + 1) * 512 + lane * 8];
        #pragma unroll
        for (int j = 0; j < 4; j++) {
            short8 b0 = *(short8*)&Bsl[(j * 2 + 0) * 512 + lane * 8];
            short8 b1 = *(short8*)&Bsl[(j * 2 + 1) * 512 + lane * 8];
            acc[j] = __builtin_amdgcn_mfma_f32_16x16x32_bf16(a0, b0, acc[j], 0, 0, 0);
            acc[j] = __builtin_amdgcn_mfma_f32_16x16x32_bf16(a1, b1, acc[j], 0, 0, 0);
        }
        __syncthreads();
    }

    const int cl = lane & 15;
    const int rl = (lane >> 4) * 4;
    #pragma unroll
    for (int j = 0; j < 4; j++) {
        const int col = n0 + j * 16 + cl;
        const float bv = bias ? bias[col] : 0.f;
        #pragma unroll
        for (int r = 0; r < 4; r++) {
            const int row = m0 + wave * 16 + rl + r;
            float v = acc[j][r] * alpha + bv;
            if (relu) v = fmaxf(v, 0.f);
            const long ci = (long)row * c_rs + col;
            if (c_bf16) ((bf16*)C)[ci] = f2b(v);
            else        ((float*)C)[ci] = v;
        }
    }
}

// ---------------- batched bf16 MFMA GEMM (cross-attn scores) ----------------
__global__ __launch_bounds__(256) void bgemm_mfma_kernel(
    const bf16* __restrict__ A, long a_rs, long a_bo,
    const bf16* __restrict__ B, long b_rs, long b_bo,
    bf16* __restrict__ C, long c_rs, long c_bo,
    int K, float alpha)
{
    const int bh = blockIdx.z;
    const int m0 = blockIdx.y * 128;
    const int n0 = blockIdx.x * 128;
    const int t = threadIdx.x;
    const int lane = t & 63;
    const int wave = t >> 6;
    const int wmf = (wave >> 1) * 4;
    const int wnf = (wave & 1) * 4;

    __shared__ __align__(16) short Asl[4096];
    __shared__ __align__(16) short Bsl[4096];

    floatx4 acc[4][4];
    #pragma unroll
    for (int i = 0; i < 4; i++)
        #pragma unroll
        for (int j = 0; j < 4; j++)
            acc[i][j] = (floatx4){0.f, 0.f, 0.f, 0.f};

    const short* Ab = (const short*)A + (long)bh * a_bo;
    const short* Bb = (const short*)B + (long)bh * b_bo;

    for (int k0 = 0; k0 < K; k0 += 32) {
        const short* Ag = Ab + (long)(m0 + wave * 32 + (lane & 15)) * a_rs + k0 + (lane >> 4) * 8;
        gl_lds16(Ag,             &Asl[(wave * 2 + 0) * 512]);
        gl_lds16(Ag + 16 * a_rs, &Asl[(wave * 2 + 1) * 512]);
        const short* Bg = Bb + (long)(n0 + wave * 32 + (lane & 15)) * b_rs + k0 + (lane >> 4) * 8;
        gl_lds16(Bg,             &Bsl[(wave * 2 + 0) * 512]);
        gl_lds16(Bg + 16 * b_rs, &Bsl[(wave * 2 + 1) * 512]);
        __syncthreads();

        short8 af[4], bfr[4];
        #pragma unroll
        for (int i = 0; i < 4; i++)
            af[i] = *(short8*)&Asl[(wmf + i) * 512 + lane * 8];
        #pragma unroll
        for (int j = 0; j < 4; j++)
            bfr[j] = *(short8*)&Bsl[(wnf + j) * 512 + lane * 8];
        #pragma unroll
        for (int i = 0; i < 4; i++)
            #pragma unroll
            for (int j = 0; j < 4; j++)
                acc[i][j] = __builtin_amdgcn_mfma_f32_16x16x32_bf16(
                    af[i], bfr[j], acc[i][j], 0, 0, 0);
        __syncthreads();
    }

    const int cl = lane & 15;
    const int rl = (lane >> 4) * 4;
    bf16* Cb = C + (long)bh * c_bo;
    #pragma unroll
    for (int j = 0; j < 4; j++) {
        const int col = n0 + wnf * 16 + j * 16 + cl;
        #pragma unroll
        for (int i = 0; i < 4; i++) {
            const int rowb = m0 + wmf * 16 + i * 16 + rl;
            #pragma unroll
            for (int r = 0; r < 4; r++)
                Cb[(long)(rowb + r) * c_rs + col] = f2b(acc[i][j][r] * alpha);
        }
    }
}

// ---------------- PV MFMA (cross-attn): C = P @ V ----------------
// Vs region stride 536 (= 512+24): region F contributes 3F mod 8 to bank
// index -> V-transpose scalar stores 16-way -> 4-way. Reads linear.
__global__ __launch_bounds__(256) void pv_mfma_kernel(
    const bf16* __restrict__ P, const bf16* __restrict__ V,
    bf16* __restrict__ Cout)
{
    const int q0 = blockIdx.x * 64;
    const int bh = blockIdx.y;
    const int t = threadIdx.x;
    const int lane = t & 63;
    const int wave = t >> 6;

    __shared__ __align__(16) short As[4096];
    __shared__ __align__(16) short Vs[4288];   // 8 frags x 536

    const int sr = t >> 2;
    const int kh = t & 3;
    const int vbase = (kh * 2 + (sr >> 5)) * 536 + ((sr & 31) >> 3) * 128 + (sr & 7);

    floatx4 acc[4];
    #pragma unroll
    for (int nf = 0; nf < 4; nf++) acc[nf] = (floatx4){0.f, 0.f, 0.f, 0.f};

    const short* Pb = (const short*)P + (long)bh * 262144;

    for (int kt = 0; kt < 1024; kt += 64) {
        {
            const short* Pg = Pb + (long)(q0 + wave * 16 + (lane & 15)) * 1024
                            + kt + (lane >> 4) * 8;
            gl_lds16(Pg,      &As[(wave * 2 + 0) * 512]);
            gl_lds16(Pg + 32, &As[(wave * 2 + 1) * 512]);
        }
        {
            const short* vp = (const short*)V + (long)(kt + sr) * 4096 + bh * 64 + kh * 16;
            short8 v0 = *(const short8*)vp;
            short8 v1 = *(const short8*)(vp + 8);
            #pragma unroll
            for (int j = 0; j < 8; j++) {
                Vs[vbase + j * 8]       = v0[j];
                Vs[vbase + (8 + j) * 8] = v1[j];
            }
        }
        __syncthreads();

        short8 af0 = *(short8*)&As[(wave * 2 + 0) * 512 + lane * 8];
        short8 af1 = *(short8*)&As[(wave * 2 + 1) * 512 + lane * 8];
        #pragma unroll
        for (int nf = 0; nf < 4; nf++) {
            short8 vf0 = *(short8*)&Vs[(nf * 2 + 0) * 536 + lane * 8];
            short8 vf1 = *(short8*)&Vs[(nf * 2 + 1) * 536 + lane * 8];
            acc[nf] = __builtin_amdgcn_mfma_f32_16x16x32_bf16(af0, vf0, acc[nf], 0, 0, 0);
            acc[nf] = __builtin_amdgcn_mfma_f32_16x16x32_bf16(af1, vf1, acc[nf], 0, 0, 0);
        }
        __syncthreads();
    }

    const int g = lane >> 4, c = lane & 15;
    #pragma unroll
    for (int r = 0; r < 4; r++) {
        const long off = (long)(q0 + wave * 16 + g * 4 + r) * 4096 + bh * 64 + c;
        #pragma unroll
        for (int nf = 0; nf < 4; nf++)
            Cout[off + nf * 16] = f2b(acc[nf][r]);
    }
}

// ---------------- MFMA flash self-attention ----------------
// Vs stride 536 (4-way V-stores); Ps XOR granule swizzle (2-way stores,
// permuted-linear reads); defer-max skip (exact, wave-uniform).
__global__ __launch_bounds__(256) void fattn_mfma_kernel(
    const bf16* __restrict__ qkv, bf16* __restrict__ out, int nk)
{
    const int q0 = blockIdx.x * 64;
    const int bh = blockIdx.y;
    const int b = bh >> 3, h = bh & 7;
    const int t = threadIdx.x;
    const int lane = t & 63;
    const int wave = t >> 6;

    __shared__ __align__(16) short Ks[4096];
    __shared__ __align__(16) short Vs[4288];     // 8 frags x 536
    __shared__ __align__(16) short Ps[4][1024];

    const int sr = t >> 2;
    const int kh = t & 3;
    const int slot0 = ((sr >> 4) * 2 + (kh >> 1)) * 512
                    + ((sr & 15) + ((kh & 1) * 2) * 16) * 8;
    const int slot1 = slot0 + 128;
    const int vbase = (kh * 2 + (sr >> 5)) * 536 + ((sr & 31) >> 3) * 128 + (sr & 7);
    const int lsw = (lane ^ ((lane >> 3) & 7)) * 8;   // Ps swizzled read granule

    {
        const short* p = (const short*)qkv
            + ((long)(q0 + sr) * BT + b) * 1536 + h * 64 + kh * 16;
        *(short8*)&Ks[slot0] = *(const short8*)p;
        *(short8*)&Ks[slot1] = *(const short8*)(p + 8);
    }
    __syncthreads();
    short8 qf0 = *(short8*)&Ks[(wave * 2 + 0) * 512 + lane * 8];
    short8 qf1 = *(short8*)&Ks[(wave * 2 + 1) * 512 + lane * 8];
    __syncthreads();

    const int g = lane >> 4, c = lane & 15;

    float mrow[4], lrow[4];
    #pragma unroll
    for (int r = 0; r < 4; r++) { mrow[r] = -1e30f; lrow[r] = 0.f; }
    floatx4 accO[4];
    #pragma unroll
    for (int of = 0; of < 4; of++) accO[of] = (floatx4){0.f, 0.f, 0.f, 0.f};

    for (int kt = 0; kt < nk; kt += 64) {
        const short* kp = (const short*)qkv
            + ((long)(kt + sr) * BT + b) * 1536 + 512 + h * 64 + kh * 16;
        *(short8*)&Ks[slot0] = *(const short8*)kp;
        *(short8*)&Ks[slot1] = *(const short8*)(kp + 8);
        short8 v0 = *(const short8*)(kp + 512);
        short8 v1 = *(const short8*)(kp + 520);
        #pragma unroll
        for (int j = 0; j < 8; j++) {
            Vs[vbase + j * 8]       = v0[j];
            Vs[vbase + (8 + j) * 8] = v1[j];
        }
        __syncthreads();

        floatx4 sacc[4];
        #pragma unroll
        for (int nf = 0; nf < 4; nf++) {
            sacc[nf] = (floatx4){0.f, 0.f, 0.f, 0.f};
            short8 bk0 = *(short8*)&Ks[(nf * 2 + 0) * 512 + lane * 8];
            short8 bk1 = *(short8*)&Ks[(nf * 2 + 1) * 512 + lane * 8];
            sacc[nf] = __builtin_amdgcn_mfma_f32_16x16x32_bf16(qf0, bk0, sacc[nf], 0, 0, 0);
            sacc[nf] = __builtin_amdgcn_mfma_f32_16x16x32_bf16(qf1, bk1, sacc[nf], 0, 0, 0);
        }

        #pragma unroll
        for (int r = 0; r < 4; r++) {
            float mx = fmaxf(fmaxf(sacc[0][r], sacc[1][r]),
                             fmaxf(sacc[2][r], sacc[3][r]));
            mx = fmaxf(mx, __shfl_xor(mx, 1));
            mx = fmaxf(mx, __shfl_xor(mx, 2));
            mx = fmaxf(mx, __shfl_xor(mx, 4));
            mx = fmaxf(mx, __shfl_xor(mx, 8));
            mx *= 0.125f;
            if (!__all(mx <= mrow[r])) {   // defer-max: exact skip when no new max
                float mn = fmaxf(mrow[r], mx);
                float al = __expf(mrow[r] - mn);
                mrow[r] = mn;
                lrow[r] *= al;
                #pragma unroll
                for (int of = 0; of < 4; of++) accO[of][r] *= al;
            }
            const float m = mrow[r];
            float ps = 0.f;
            #pragma unroll
            for (int nf = 0; nf < 4; nf++) {
                float p = __expf(fmaf(sacc[nf][r], 0.125f, -m));
                ps += p;
                // A-layout slot for (row=g*4+r, key=nf*16+c), XOR granule swizzle
                int Rp = (g * 4 + r) + ((nf & 1) * 2 + (c >> 3)) * 16;
                Ps[wave][(nf >> 1) * 512
                         + ((Rp * 8 + (c & 7)) ^ (((Rp >> 3) & 7) << 3))] = f2bs(p);
            }
            ps += __shfl_xor(ps, 1);
            ps += __shfl_xor(ps, 2);
            ps += __shfl_xor(ps, 4);
            ps += __shfl_xor(ps, 8);
            lrow[r] += ps;
        }

        short8 pf0 = *(short8*)&Ps[wave][lsw];
        short8 pf1 = *(short8*)&Ps[wave][512 + lsw];
        #pragma unroll
        for (int of = 0; of < 4; of++) {
            short8 vf0 = *(short8*)&Vs[(of * 2 + 0) * 536 + lane * 8];
            short8 vf1 = *(short8*)&Vs[(of * 2 + 1) * 536 + lane * 8];
            accO[of] = __builtin_amdgcn_mfma_f32_16x16x32_bf16(pf0, vf0, accO[of], 0, 0, 0);
            accO[of] = __builtin_amdgcn_mfma_f32_16x16x32_bf16(pf1, vf1, accO[of], 0, 0, 0);
        }
        __syncthreads();
    }

    #pragma unroll
    for (int r = 0; r < 4; r++) {
        const float inv = 1.f / lrow[r];
        const long off = ((long)(q0 + wave * 16 + g * 4 + r) * BT + b) * DMODEL
                       + h * 64 + c;
        #pragma unroll
        for (int of = 0; of < 4; of++)
            out[off + of * 16] = f2b(accO[of][r] * inv);
    }
}

// ---------------- layer norm: y = LN(x + res) * w + b (+ bf16 copies) ----------------
__global__ __launch_bounds__(256) void ln_kernel(
    const float* __restrict__ x, const bf16* __restrict__ res,
    const float* __restrict__ w, const float* __restrict__ b,
    float* __restrict__ y, bf16* __restrict__ yb, bf16* __restrict__ ypb,
    const float* __restrict__ pos, int pos_mode)
{
    const long row = blockIdx.x;
    const int t = threadIdx.x;
    const float* xr = x + row * DMODEL;
    float v0 = xr[t], v1 = xr[t + 256];
    if (res) {
        v0 += b2f(res[row * DMODEL + t]);
        v1 += b2f(res[row * DMODEL + t + 256]);
    }

    __shared__ float red[256];
    red[t] = v0 + v1; __syncthreads();
    for (int s = 128; s > 0; s >>= 1) { if (t < s) red[t] += red[t + s]; __syncthreads(); }
    float mean = red[0] * (1.f / DMODEL);
    __syncthreads();
    float d0 = v0 - mean, d1 = v1 - mean;
    red[t] = d0 * d0 + d1 * d1; __syncthreads();
    for (int s = 128; s > 0; s >>= 1) { if (t < s) red[t] += red[t + s]; __syncthreads(); }
    float inv = rsqrtf(red[0] * (1.f / DMODEL) + 1e-5f);

    float o0 = d0 * inv * w[t] + b[t];
    float o1 = d1 * inv * w[t + 256] + b[t + 256];
    y[row * DMODEL + t]       = o0;
    y[row * DMODEL + t + 256] = o1;
    if (yb) {
        yb[row * DMODEL + t]       = f2b(o0);
        yb[row * DMODEL + t + 256] = f2b(o1);
    }
    if (ypb) {
        const float* pr = pos + ((pos_mode == 2) ? (row >> 3) : row) * DMODEL;
        ypb[row * DMODEL + t]       = f2b(o0 + pr[t]);
        ypb[row * DMODEL + t + 256] = f2b(o1 + pr[t + 256]);
    }
}

// ---------------- column softmax over q (assign-attn), 2-pass online ----------------
__global__ __launch_bounds__(256) void col_softmax_kernel(bf16* __restrict__ s) {
    const int bh = blockIdx.y;
    const int n = blockIdx.x * 256 + threadIdx.x;
    bf16* base = s + (long)bh * (NQ * SEQ) + n;
    float mx = -1e30f, sum = 0.f;
    for (int q = 0; q < NQ; q++) {
        float v = b2f(base[(long)q * SEQ]);
        float mn = fmaxf(mx, v);
        sum = sum * __expf(mx - mn) + __expf(v - mn);
        mx = mn;
    }
    float inv = 1.f / sum;
    for (int q = 0; q < NQ; q++) {
        float v = __expf(b2f(base[(long)q * SEQ]) - mx);
        base[(long)q * SEQ] = f2b(v * inv);
    }
}

// mean over heads: o[b,q,n] = (1/8) sum_h s[b,h,q,n], fp32 out.
__global__ __launch_bounds__(256) void mean_h_kernel(
    const bf16* __restrict__ s, float* __restrict__ o)
{
    long i = (long)blockIdx.x * 256 + threadIdx.x;
    int n = (int)(i & (SEQ - 1));
    long r = i >> 10;
    int q = (int)(r & (NQ - 1));
    int b = (int)(r >> 8);
    float acc = 0.f;
    #pragma unroll
    for (int h = 0; h < 8; h++)
        acc += b2f(s[(((long)b * 8 + h) * NQ + q) * SEQ + n]);
    o[i] = acc * 0.125f;
}

// ---------------- host launch ----------------
extern "C" void kernel_launch(void* const* d_in, const int* in_sizes, int n_in,
                              void* d_out, int out_size, void* d_ws, size_t ws_size,
                              hipStream_t stream) {
    const float* src         = (const float*)d_in[0];
    const float* query_embed = (const float*)d_in[2];
    const float* pos_embed   = (const float*)d_in[3];
    const float* enc_in_w    = (const float*)d_in[4];
    const float* enc_in_b    = (const float*)d_in[5];
    const float* enc_out_w   = (const float*)d_in[6];
    const float* enc_out_b   = (const float*)d_in[7];
    const float* enc_ffn_w1  = (const float*)d_in[8];
    const float* enc_ffn_b1  = (const float*)d_in[9];
    const float* enc_ffn_w2  = (const float*)d_in[10];
    const float* enc_ffn_b2  = (const float*)d_in[11];
    const float* enc_ln_w    = (const float*)d_in[12];
    const float* enc_ln_b    = (const float*)d_in[13];
    const float* dec_in_w    = (const float*)d_in[14];
    const float* dec_in_b    = (const float*)d_in[15];
    const float* dec_out_w   = (const float*)d_in[16];
    const float* dec_out_b   = (const float*)d_in[17];
    const float* dec_ca_w    = (const float*)d_in[18];
    const float* dec_ca_b    = (const float*)d_in[19];
    const float* dec_ffn_w1  = (const float*)d_in[20];
    const float* dec_ffn_b1  = (const float*)d_in[21];
    const float* dec_ffn_w2  = (const float*)d_in[22];
    const float* dec_ffn_b2  = (const float*)d_in[23];
    const float* dec_ln_w    = (const float*)d_in[24];
    const float* dec_ln_b    = (const float*)d_in[25];
    const float* final_ln_w  = (const float*)d_in[26];
    const float* final_ln_b  = (const float*)d_in[27];

    float* wsf = (float*)d_ws;
    float* x   = wsf;                     // 4,194,304 f
    float* tgt = wsf + 4194304;           // 1,048,576 f
    bf16* QKVb = (bf16*)(wsf + 5242880);  // 12,582,912 bf16
    bf16* Fb   = QKVb + 12582912;         // 16,777,216
    bf16* E1b  = Fb + 16777216;           //  4,194,304
    bf16* E2b  = E1b + 4194304;           //  4,194,304
    bf16* kca  = QKVb + 3145728;          // decoder carve (after 2048*1536)
    bf16* vca  = kca + 4194304;

    const bool useA = ws_size >= 117440512ull;   // + xb/xpb/tb/tqb (21 MB)
    const bool useB = ws_size >= 205520896ull;   // + bf16 weights (88 MB)
    bf16* xb   = (bf16*)((char*)d_ws + 96468992);
    bf16* xpb  = (bf16*)((char*)d_ws + 104857600);
    bf16* tb   = (bf16*)((char*)d_ws + 113246208);
    bf16* tqb  = (bf16*)((char*)d_ws + 115343360);
    bf16* Wb   = (bf16*)((char*)d_ws + 117440512);
    bf16* ei16  = Wb;
    bf16* eo16  = Wb + 4718592;
    bf16* ef116 = Wb + 6291456;
    bf16* ef216 = Wb + 12582912;
    bf16* di16  = Wb + 18874368;
    bf16* do16  = Wb + 23592960;
    bf16* dca16 = Wb + 25165824;
    bf16* df116 = Wb + 31457280;
    bf16* df216 = Wb + 37748736;

    float* out0 = (float*)d_out;          // (1,Q,B,D) 1,048,576
    float* outP = out0 + 1048576;         // (B,Q,S)   2,097,152
    float* outS = outP + 2097152;         // (B,Q,S)   2,097,152

    auto mgemm = [&](const void* A, int a_bf16, const float* A2, int a2_mode,
                     const void* Bt, int b_bf16, const float* bias, void* C, int c_bf16,
                     int M, int N, int K, long a_rs, long c_rs, int relu) {
        dim3 g(N / 128, M / 128, 1);
        gemm_mfma_kernel<<<g, 256, 0, stream>>>(A, a_bf16, A2, a2_mode, Bt, b_bf16, bias,
                                                C, c_bf16, K, a_rs, c_rs, 1.f, relu);
    };
    auto mgemm64 = [&](const void* A, int a_bf16, const float* A2, int a2_mode,
                       const void* Bt, int b_bf16, const float* bias, void* C, int c_bf16,
                       int M, int N, int K, long a_rs, long c_rs, int relu) {
        dim3 g(N / 64, M / 64, 1);
        gemm_mfma64_kernel<<<g, 256, 0, stream>>>(A, a_bf16, A2, a2_mode, Bt, b_bf16, bias,
                                                  C, c_bf16, K, a_rs, c_rs, 1.f, relu);
    };

    if (useB) {
        cvt_kernel<<<2304, 256, 0, stream>>>(enc_in_w,   ei16,  4718592);
        cvt_kernel<<<768,  256, 0, stream>>>(enc_out_w,  eo16,  1572864);
        cvt_kernel<<<3072, 256, 0, stream>>>(enc_ffn_w1, ef116, 6291456);
        cvt_kernel<<<3072, 256, 0, stream>>>(enc_ffn_w2, ef216, 6291456);
        cvt_kernel<<<2304, 256, 0, stream>>>(dec_in_w,   di16,  4718592);
        cvt_kernel<<<768,  256, 0, stream>>>(dec_out_w,  do16,  1572864);
        cvt_kernel<<<3072, 256, 0, stream>>>(dec_ca_w,   dca16, 6291456);
        cvt_kernel<<<3072, 256, 0, stream>>>(dec_ffn_w1, df116, 6291456);
        cvt_kernel<<<3072, 256, 0, stream>>>(dec_ffn_w2, df216, 6291456);
    }

    if (useA) prep_x_kernel<<<16384, 256, 0, stream>>>(src, pos_embed, x, xb, xpb);
    else      copy_kernel<<<16384, 256, 0, stream>>>(src, x, 4194304);
    if (useA) prep_tgt_kernel<<<4096, 256, 0, stream>>>(query_embed, tgt, tb, tqb);
    else      hipMemsetAsync(tgt, 0, 1048576 * sizeof(float), stream);

    // ---------------- encoder ----------------
    for (int i = 0; i < 6; i++) {
        const float* iw = enc_in_w + (long)i * 786432;
        const float* ib = enc_in_b + (long)i * 1536;
        const void* Bqk = useB ? (const void*)(ei16 + (long)i * 786432) : (const void*)iw;
        const void* Bv  = useB ? (const void*)(ei16 + (long)i * 786432 + 524288)
                               : (const void*)(iw + 524288);
        const void* Bo  = useB ? (const void*)(eo16 + (long)i * 262144)
                               : (const void*)(enc_out_w + (long)i * 262144);
        const void* Bf1 = useB ? (const void*)(ef116 + (long)i * 1048576)
                               : (const void*)(enc_ffn_w1 + (long)i * 1048576);
        const void* Bf2 = useB ? (const void*)(ef216 + (long)i * 1048576)
                               : (const void*)(enc_ffn_w2 + (long)i * 1048576);

        if (useA) mgemm(xpb, 1, nullptr, 0, Bqk, useB, ib, QKVb, 1,
                        8192, 1024, 512, 512, 1536, 0);
        else      mgemm(x, 0, pos_embed, 1, Bqk, useB, ib, QKVb, 1,
                        8192, 1024, 512, 512, 1536, 0);
        mgemm64(useA ? (const void*)xb : (const void*)x, useA, nullptr, 0,
                Bv, useB, ib + 1024, QKVb + 1024, 1, 8192, 512, 512, 512, 1536, 0);
        fattn_mfma_kernel<<<dim3(16, 64), 256, 0, stream>>>(QKVb, E1b, 1024);
        mgemm64(E1b, 1, nullptr, 0, Bo, useB, enc_out_b + (long)i * 512,
                E2b, 1, 8192, 512, 512, 512, 512, 0);
        ln_kernel<<<8192, 256, 0, stream>>>(x, E2b, enc_ln_w + (long)i * 1024,
                                            enc_ln_b + (long)i * 1024, x,
                                            useA ? xb : nullptr, useA ? xpb : nullptr,
                                            pos_embed, 1);
        mgemm(useA ? (const void*)xb : (const void*)x, useA, nullptr, 0,
              Bf1, useB, enc_ffn_b1 + (long)i * 2048, Fb, 1,
              8192, 2048, 512, 512, 2048, 1);
        mgemm64(Fb, 1, nullptr, 0, Bf2, useB, enc_ffn_b2 + (long)i * 512,
                E1b, 1, 8192, 512, 2048, 2048, 512, 0);
        ln_kernel<<<8192, 256, 0, stream>>>(x, E1b, enc_ln_w + (long)i * 1024 + 512,
                                            enc_ln_b + (long)i * 1024 + 512, x,
                                            useA ? xb : nullptr, useA ? xpb : nullptr,
                                            pos_embed, 1);
    }
    // x = memory; xb = bf16(memory); xpb = bf16(memory + pos)

    // ---------------- decoder ----------------
    for (int i = 0; i < 6; i++) {
        const float* iw = dec_in_w + (long)i * 786432;
        const float* ib = dec_in_b + (long)i * 1536;
        const float* cw = dec_ca_w + (long)i * 1048576;
        const float* cb = dec_ca_b + (long)i * 2048;
        const void* Bqk = useB ? (const void*)(di16 + (long)i * 786432) : (const void*)iw;
        const void* Bv  = useB ? (const void*)(di16 + (long)i * 786432 + 524288)
                               : (const void*)(iw + 524288);
        const void* Bo  = useB ? (const void*)(do16 + (long)i * 262144)
                               : (const void*)(dec_out_w + (long)i * 262144);
        const void* Bcq = useB ? (const void*)(dca16 + (long)i * 1048576) : (const void*)cw;
        const void* Bck = useB ? (const void*)(dca16 + (long)i * 1048576 + 262144)
                               : (const void*)(cw + 262144);
        const void* Bcv = useB ? (const void*)(dca16 + (long)i * 1048576 + 524288)
                               : (const void*)(cw + 524288);
        const void* Bco = useB ? (const void*)(dca16 + (long)i * 1048576 + 786432)
                               : (const void*)(cw + 786432);
        const void* Bf1 = useB ? (const void*)(df116 + (long)i * 1048576)
                               : (const void*)(dec_ffn_w1 + (long)i * 1048576);
        const void* Bf2 = useB ? (const void*)(df216 + (long)i * 1048576)
                               : (const void*)(dec_ffn_w2 + (long)i * 1048576);

        if (useA) mgemm64(tqb, 1, nullptr, 0, Bqk, useB, ib, QKVb, 1,
                          2048, 1024, 512, 512, 1536, 0);
        else      mgemm64(tgt, 0, query_embed, 2, Bqk, useB, ib, QKVb, 1,
                          2048, 1024, 512, 512, 1536, 0);
        mgemm64(useA ? (const void*)tb : (const void*)tgt, useA, nullptr, 0,
                Bv, useB, ib + 1024, QKVb + 1024, 1, 2048, 512, 512, 512, 1536, 0);
        fattn_mfma_kernel<<<dim3(4, 64), 256, 0, stream>>>(QKVb, E1b, 256);
        mgemm64(E1b, 1, nullptr, 0, Bo, useB, dec_out_b + (long)i * 512,
                E2b, 1, 2048, 512, 512, 512, 512, 0);  // E2b = sa (keep)
        ln_kernel<<<2048, 256, 0, stream>>>(tgt, E2b, dec_ln_w + (long)i * 1536,
                                            dec_ln_b + (long)i * 1536, tgt,
                                            useA ? tb : nullptr, useA ? tqb : nullptr,
                                            query_embed, 2);

        // assign (cross) attention: q = sa + qpos, k = memory + pos, v = memory
        mgemm64(E2b, 1, query_embed, 2, Bcq, useB, cb, E1b, 1,
                2048, 512, 512, 512, 512, 0);                                        // qca
        if (useA) mgemm64(xpb, 1, nullptr, 0, Bck, useB, cb + 512, kca, 1,
                          8192, 512, 512, 512, 512, 0);                              // kca
        else      mgemm64(x, 0, pos_embed, 1, Bck, useB, cb + 512, kca, 1,
                          8192, 512, 512, 512, 512, 0);
        mgemm64(useA ? (const void*)xb : (const void*)x, useA, nullptr, 0,
                Bcv, useB, cb + 1024, vca, 1, 8192, 512, 512, 512, 512, 0);          // vca
        bgemm_mfma_kernel<<<dim3(8, 2, 64), 256, 0, stream>>>(
            E1b, 4096, 64, kca, 4096, 64, Fb, 1024, 262144, 64, 0.125f);
        if (i == 5) mean_h_kernel<<<8192, 256, 0, stream>>>(Fb, outS);
        col_softmax_kernel<<<dim3(4, 64), 256, 0, stream>>>(Fb);
        if (i == 5) mean_h_kernel<<<8192, 256, 0, stream>>>(Fb, outP);
        pv_mfma_kernel<<<dim3(4, 64), 256, 0, stream>>>(Fb, vca, E2b);
        mgemm64(E2b, 1, nullptr, 0, Bco, useB, cb + 1536, E1b, 1,
                2048, 512, 512, 512, 512, 0);
        ln_kernel<<<2048, 256, 0, stream>>>(tgt, E1b, dec_ln_w + (long)i * 1536 + 512,
                                            dec_ln_b + (long)i * 1536 + 512, tgt,
                                            useA ? tb : nullptr, useA ? tqb : nullptr,
                                            query_embed, 2);

        // FFN
        mgemm64(useA ? (const void*)tb : (const void*)tgt, useA, nullptr, 0,
                Bf1, useB, dec_ffn_b1 + (long)i * 2048, Fb, 1,
                2048, 2048, 512, 512, 2048, 1);
        mgemm64(Fb, 1, nullptr, 0, Bf2, useB, dec_ffn_b2 + (long)i * 512,
                E1b, 1, 2048, 512, 2048, 2048, 512, 0);
        ln_kernel<<<2048, 256, 0, stream>>>(tgt, E1b, dec_ln_w + (long)i * 1536 + 1024,
                                            dec_ln_b + (long)i * 1536 + 1024, tgt,
                                            useA ? tb : nullptr, useA ? tqb : nullptr,
                                            query_embed, 2);
    }

    // final LN -> fp32 output 0
    ln_kernel<<<2048, 256, 0, stream>>>(tgt, nullptr, final_ln_w, final_ln_b, out0,
                                        nullptr, nullptr, nullptr, 0);
}